// Round 2
// baseline (29708.698 us; speedup 1.0000x reference)
//
#include <hip/hip_runtime.h>
#include <hip/hip_bf16.h>

#define EPS 1e-5f

// ---------------- BN fold: scale[c], shift[c] ----------------
__global__ void prep_affine(const float* __restrict__ cb, const float* __restrict__ g,
                            const float* __restrict__ be, const float* __restrict__ m,
                            const float* __restrict__ v, float* __restrict__ scale,
                            float* __restrict__ shift, int C, int has_bn) {
    int c = blockIdx.x * blockDim.x + threadIdx.x;
    if (c >= C) return;
    if (has_bn) {
        float s = g[c] * rsqrtf(v[c] + EPS);
        scale[c] = s;
        shift[c] = (cb[c] - m[c]) * s + be[c];
    } else {
        scale[c] = 1.0f;
        shift[c] = cb[c];
    }
}

// ---------------- generic direct conv (NCHW / OIHW), single image ----------------
template <int KH, int KW, int S, int P, bool RELU>
__global__ void conv_direct(const float* __restrict__ x, const float* __restrict__ w,
                            const float* __restrict__ scale, const float* __restrict__ shift,
                            float* __restrict__ y,
                            int Cin, int Hin, int Win, int Cout, int Hout, int Wout) {
    int idx = blockIdx.x * blockDim.x + threadIdx.x;
    int total = Cout * Hout * Wout;
    if (idx >= total) return;
    int ow = idx % Wout;
    int oh = (idx / Wout) % Hout;
    int oc = idx / (Wout * Hout);

    float acc = 0.f;
    const float* wp = w + oc * Cin * KH * KW;
    for (int ic = 0; ic < Cin; ++ic) {
        const float* xp = x + ic * Hin * Win;
        const float* wpc = wp + ic * KH * KW;
#pragma unroll
        for (int kh = 0; kh < KH; ++kh) {
            int ih = oh * S - P + kh;
            if (ih < 0 || ih >= Hin) continue;
            const float* xr = xp + ih * Win;
#pragma unroll
            for (int kw = 0; kw < KW; ++kw) {
                int iw = ow * S - P + kw;
                if (iw < 0 || iw >= Win) continue;
                acc += xr[iw] * wpc[kh * KW + kw];
            }
        }
    }
    float r = acc * scale[oc] + shift[oc];
    if (RELU) r = fmaxf(r, 0.f);
    y[idx] = r;
}

// ---------------- 81-shift correlation, single image ----------------
// cf, pf: [256,64,64]; out: [81,64,64]
__global__ void correlation81(const float* __restrict__ cf, const float* __restrict__ pf,
                              float* __restrict__ out) {
    int idx = blockIdx.x * blockDim.x + threadIdx.x;
    const int total = 81 * 64 * 64;
    if (idx >= total) return;
    int w = idx & 63;
    int h = (idx >> 6) & 63;
    int s = idx >> 12;
    int di = s / 9 - 4;
    int dj = s % 9 - 4;
    int h2 = h + di;
    int w2 = w + dj;
    float acc = 0.f;
    if (h2 >= 0 && h2 < 64 && w2 >= 0 && w2 < 64) {
        const float* c0 = cf + h * 64 + w;
        const float* p0 = pf + h2 * 64 + w2;
        for (int c = 0; c < 256; ++c) {
            acc += c0[c * 4096] * p0[c * 4096];
        }
    }
    out[idx] = acc;
}

// ---------------- launch ----------------
extern "C" void kernel_launch(void* const* d_in, const int* in_sizes, int n_in,
                              void* d_out, int out_size, void* d_ws, size_t ws_size,
                              hipStream_t stream) {
    const float* cloth  = (const float*)d_in[0];
    const float* person = (const float*)d_in[1];
    const float* w1 = (const float*)d_in[2];
    const float* b1 = (const float*)d_in[3];
    const float* g1 = (const float*)d_in[4];
    const float* be1 = (const float*)d_in[5];
    const float* m1 = (const float*)d_in[6];
    const float* v1 = (const float*)d_in[7];
    const float* w2 = (const float*)d_in[8];
    const float* b2 = (const float*)d_in[9];
    const float* g2 = (const float*)d_in[10];
    const float* be2 = (const float*)d_in[11];
    const float* m2 = (const float*)d_in[12];
    const float* v2 = (const float*)d_in[13];
    const float* w3 = (const float*)d_in[14];
    const float* b3 = (const float*)d_in[15];
    const float* g3 = (const float*)d_in[16];
    const float* be3 = (const float*)d_in[17];
    const float* m3 = (const float*)d_in[18];
    const float* v3 = (const float*)d_in[19];
    const float* fw1 = (const float*)d_in[20];
    const float* fb1 = (const float*)d_in[21];
    const float* fw2 = (const float*)d_in[22];
    const float* fb2 = (const float*)d_in[23];
    const float* fw3 = (const float*)d_in[24];
    const float* fb3 = (const float*)d_in[25];

    char* ws = (char*)d_ws;
    // ---- per-image workspace layout (bytes), total < 39 MB ----
    float* cfb  = (float*)(ws + 0);          //  256*64*64*4  = 4,194,304
    float* pfb  = (float*)(ws + 4194304);    //  4,194,304
    float* t1   = (float*)(ws + 8388608);    //  64*256*256*4 = 16,777,216
    float* t2   = (float*)(ws + 25165824);   // 128*128*128*4 = 8,388,608
    float* corr = (float*)(ws + 33554432);   //  81*64*64*4   = 1,327,104
    float* f1   = (float*)(ws + 34881536);   // 128*64*64*4   = 2,097,152
    float* f2   = (float*)(ws + 36978688);   //  64*64*64*4   = 1,048,576
    float* aff  = (float*)(ws + 38027264);   // affine params
    float* s1 = aff;         float* sh1 = aff + 64;
    float* s2 = aff + 128;   float* sh2 = aff + 256;
    float* s3 = aff + 384;   float* sh3 = aff + 640;
    float* sf1 = aff + 896;  float* shf1 = aff + 1024;
    float* sf2 = aff + 1152; float* shf2 = aff + 1216;
    float* sf3 = aff + 1280; float* shf3 = aff + 1282;

    // fold BN / bias
    prep_affine<<<1, 64, 0, stream>>>(b1, g1, be1, m1, v1, s1, sh1, 64, 1);
    prep_affine<<<1, 128, 0, stream>>>(b2, g2, be2, m2, v2, s2, sh2, 128, 1);
    prep_affine<<<1, 256, 0, stream>>>(b3, g3, be3, m3, v3, s3, sh3, 256, 1);
    prep_affine<<<1, 128, 0, stream>>>(fb1, nullptr, nullptr, nullptr, nullptr, sf1, shf1, 128, 0);
    prep_affine<<<1, 64, 0, stream>>>(fb2, nullptr, nullptr, nullptr, nullptr, sf2, shf2, 64, 0);
    prep_affine<<<1, 2, 0, stream>>>(fb3, nullptr, nullptr, nullptr, nullptr, sf3, shf3, 2, 0);

    for (int b = 0; b < 8; ++b) {
        // ----- feature extraction for this image: cloth then person -----
        const float* imgs[2]  = {cloth + (size_t)b * 3 * 512 * 512,
                                 person + (size_t)b * 3 * 512 * 512};
        float* feats[2] = {cfb, pfb};
        for (int i = 0; i < 2; ++i) {
            // conv1: 3->64, 7x7 s2 p3, 512 -> 256
            {
                int total = 64 * 256 * 256;
                conv_direct<7, 7, 2, 3, true><<<total / 256, 256, 0, stream>>>(
                    imgs[i], w1, s1, sh1, t1, 3, 512, 512, 64, 256, 256);
            }
            // conv2: 64->128, 3x3 s2 p1, 256 -> 128
            {
                int total = 128 * 128 * 128;
                conv_direct<3, 3, 2, 1, true><<<total / 256, 256, 0, stream>>>(
                    t1, w2, s2, sh2, t2, 64, 256, 256, 128, 128, 128);
            }
            // conv3: 128->256, 3x3 s2 p1, 128 -> 64
            {
                int total = 256 * 64 * 64;
                conv_direct<3, 3, 2, 1, true><<<total / 256, 256, 0, stream>>>(
                    t2, w3, s3, sh3, feats[i], 128, 128, 128, 256, 64, 64);
            }
        }

        // ----- correlation: [81,64,64] -----
        {
            int total = 81 * 64 * 64;
            correlation81<<<(total + 255) / 256, 256, 0, stream>>>(cfb, pfb, corr);
        }

        // ----- regression head -----
        {
            int total = 128 * 64 * 64;
            conv_direct<3, 3, 1, 1, true><<<total / 256, 256, 0, stream>>>(
                corr, fw1, sf1, shf1, f1, 81, 64, 64, 128, 64, 64);
        }
        {
            int total = 64 * 64 * 64;
            conv_direct<3, 3, 1, 1, true><<<total / 256, 256, 0, stream>>>(
                f1, fw2, sf2, shf2, f2, 128, 64, 64, 64, 64, 64);
        }
        {
            int total = 2 * 64 * 64;
            conv_direct<3, 3, 1, 1, false><<<(total + 255) / 256, 256, 0, stream>>>(
                f2, fw3, sf3, shf3, (float*)d_out + (size_t)b * 2 * 64 * 64,
                64, 64, 64, 2, 64, 64);
        }
    }
}

// Round 3
// 2087.874 us; speedup vs baseline: 14.2292x; 14.2292x over previous
//
#include <hip/hip_runtime.h>

typedef __bf16 bf16x8_t __attribute__((ext_vector_type(8)));
typedef float f32x4 __attribute__((ext_vector_type(4)));
typedef unsigned short u16x8 __attribute__((ext_vector_type(8)));

#define EPS 1e-5f

__device__ __forceinline__ unsigned short f2bf(float f) {
    unsigned u = __builtin_bit_cast(unsigned, f);
    u += 0x7fff + ((u >> 16) & 1);          // RTNE
    return (unsigned short)(u >> 16);
}
__device__ __forceinline__ float bf2f(unsigned short h) {
    unsigned u = ((unsigned)h) << 16;
    return __builtin_bit_cast(float, u);
}

// ---------------- BN fold ----------------
__global__ void prep_affine(const float* __restrict__ cb, const float* __restrict__ g,
                            const float* __restrict__ be, const float* __restrict__ m,
                            const float* __restrict__ v, float* __restrict__ scale,
                            float* __restrict__ shift, int C, int has_bn) {
    int c = blockIdx.x * blockDim.x + threadIdx.x;
    if (c >= C) return;
    if (has_bn) {
        float s = g[c] * rsqrtf(v[c] + EPS);
        scale[c] = s;
        shift[c] = (cb[c] - m[c]) * s + be[c];
    } else {
        scale[c] = 1.0f;
        shift[c] = cb[c];
    }
}

// ------- weights OIHW fp32 -> [Sp][Kp] bf16, k = (kh*KHW+kw)*CIN + ic -------
template <int CIN, int KHW>
__global__ void conv_weights(const float* __restrict__ w, unsigned short* __restrict__ dst,
                             int Cout, int Sp, int Kp) {
    int idx = blockIdx.x * 256 + threadIdx.x;
    if (idx >= Sp * Kp) return;
    int m = idx / Kp, k = idx - m * Kp;
    const int K = KHW * KHW * CIN;
    unsigned short v = 0;
    if (m < Cout && k < K) {
        int q = k / CIN, ic = k - q * CIN;
        int kh = q / KHW, kw = q - kh * KHW;
        v = f2bf(w[((m * CIN + ic) * KHW + kh) * KHW + kw]);
    }
    dst[idx] = v;
}

// ------- materialized im2col -> [R][Kp] bf16 -------
template <int CIN, int KHW, bool NCHW_F32>
__global__ void im2col_k(const void* __restrict__ srcv, unsigned short* __restrict__ dst,
                         int R, int Kp, int Hin, int Win, int WoutShift, int stride, int pad) {
    int idx = blockIdx.x * 256 + threadIdx.x;
    if (idx >= R * Kp) return;
    int r = idx / Kp, k = idx - r * Kp;
    int oh = r >> WoutShift, ow = r & ((1 << WoutShift) - 1);
    const int K = KHW * KHW * CIN;
    unsigned short v = 0;
    if (k < K) {
        int q = k / CIN, ic = k - q * CIN;
        int kh = q / KHW, kw = q - kh * KHW;
        int ih = oh * stride - pad + kh, iw = ow * stride - pad + kw;
        if ((unsigned)ih < (unsigned)Hin && (unsigned)iw < (unsigned)Win) {
            if (NCHW_F32) v = f2bf(((const float*)srcv)[(ic * Hin + ih) * Win + iw]);
            else          v = ((const unsigned short*)srcv)[(ih * Win + iw) * CIN + ic];
        }
    }
    dst[idx] = v;
}

// ------- MFMA GEMM: C[R][Cout] = X[R][K] * W^T, fused scale/shift/relu -------
// X: either materialized [R][Kp] bf16 (IMPLICIT=0) or NHWC bf16 input of a
// 3x3 pad-1 conv (IMPLICIT=1, Cin % 32 == 0). Wave tile 64x64, block WRxWS waves.
template <int WR, int WS, bool IMPLICIT, bool RELU, bool OUT_NCHW>
__global__ __launch_bounds__(256)
void gemm_conv(const unsigned short* __restrict__ X, const unsigned short* __restrict__ Wmk,
               const float* __restrict__ scale, const float* __restrict__ shift,
               void* __restrict__ Yv, int Kp, int Cout,
               int Hin, int Win, int CinShift, int WoutShift, int stride) {
    constexpr int BR = WR * 64, BS = WS * 64, LDK = 40;  // 80B LDS row stride
    __shared__ unsigned short Xs[BR * LDK];
    __shared__ unsigned short Ws[BS * LDK];
    const int tid = threadIdx.x;
    const int lane = tid & 63, wid = tid >> 6;
    const int wr = wid % WR, wsx = wid / WR;
    const int r0 = blockIdx.x * BR, s0 = blockIdx.y * BS;
    const int lr = lane & 15, lk = lane >> 4;

    // K-invariant staging precompute
    int xrow[WR], xc[WR], xoh[WR], xow[WR];
    const unsigned short* xbase[WR];
    #pragma unroll
    for (int i = 0; i < WR; ++i) {
        int chunk = i * 256 + tid;
        xrow[i] = chunk >> 2; xc[i] = chunk & 3;
        if (IMPLICIT) {
            int r = r0 + xrow[i];
            xoh[i] = r >> WoutShift;
            xow[i] = r & ((1 << WoutShift) - 1);
            xbase[i] = X;
        } else {
            xbase[i] = X + (size_t)(r0 + xrow[i]) * Kp + xc[i] * 8;
        }
    }
    int wrow[WS], wc[WS];
    const unsigned short* wbase[WS];
    #pragma unroll
    for (int i = 0; i < WS; ++i) {
        int chunk = i * 256 + tid;
        wrow[i] = chunk >> 2; wc[i] = chunk & 3;
        wbase[i] = Wmk + (size_t)(s0 + wrow[i]) * Kp + wc[i] * 8;
    }

    const f32x4 fz = {0.f, 0.f, 0.f, 0.f};
    f32x4 acc[4][4];
    #pragma unroll
    for (int a = 0; a < 4; ++a)
        #pragma unroll
        for (int b = 0; b < 4; ++b) acc[a][b] = fz;

    const int nkt = Kp >> 5;
    for (int kt = 0; kt < nkt; ++kt) {
        const int k0 = kt << 5;
        u16x8 xv[WR], wv[WS];
        if (IMPLICIT) {
            int kq = k0 >> CinShift;
            int kh = kq / 3, kw = kq - kh * 3;
            int ic0 = k0 - (kq << CinShift);
            #pragma unroll
            for (int i = 0; i < WR; ++i) {
                int ih = xoh[i] * stride - 1 + kh;
                int iw = xow[i] * stride - 1 + kw;
                if ((unsigned)ih < (unsigned)Hin && (unsigned)iw < (unsigned)Win) {
                    xv[i] = *(const u16x8*)&X[(((ih * Win) + iw) << CinShift) + ic0 + xc[i] * 8];
                } else {
                    const u16x8 z = {0, 0, 0, 0, 0, 0, 0, 0};
                    xv[i] = z;
                }
            }
        } else {
            #pragma unroll
            for (int i = 0; i < WR; ++i) xv[i] = *(const u16x8*)(xbase[i] + k0);
        }
        #pragma unroll
        for (int i = 0; i < WS; ++i) wv[i] = *(const u16x8*)(wbase[i] + k0);

        __syncthreads();  // previous iteration's fragment reads done
        #pragma unroll
        for (int i = 0; i < WR; ++i) *(u16x8*)&Xs[xrow[i] * LDK + xc[i] * 8] = xv[i];
        #pragma unroll
        for (int i = 0; i < WS; ++i) *(u16x8*)&Ws[wrow[i] * LDK + wc[i] * 8] = wv[i];
        __syncthreads();

        u16x8 af[4], bfr[4];
        #pragma unroll
        for (int mi = 0; mi < 4; ++mi)
            af[mi] = *(const u16x8*)&Xs[(wr * 64 + mi * 16 + lr) * LDK + lk * 8];
        #pragma unroll
        for (int si = 0; si < 4; ++si)
            bfr[si] = *(const u16x8*)&Ws[(wsx * 64 + si * 16 + lr) * LDK + lk * 8];
        #pragma unroll
        for (int mi = 0; mi < 4; ++mi)
            #pragma unroll
            for (int si = 0; si < 4; ++si)
                acc[mi][si] = __builtin_amdgcn_mfma_f32_16x16x32_bf16(
                    __builtin_bit_cast(bf16x8_t, af[mi]),
                    __builtin_bit_cast(bf16x8_t, bfr[si]), acc[mi][si], 0, 0, 0);
    }

    // epilogue: D row=(lane>>4)*4+reg, col=lane&15 (per 16x16 fragment)
    #pragma unroll
    for (int si = 0; si < 4; ++si) {
        int col = s0 + wsx * 64 + si * 16 + lr;
        bool cok = col < Cout;
        float sc = cok ? scale[col] : 0.f;
        float sh = cok ? shift[col] : 0.f;
        #pragma unroll
        for (int mi = 0; mi < 4; ++mi) {
            int rbase = r0 + wr * 64 + mi * 16 + lk * 4;
            #pragma unroll
            for (int j = 0; j < 4; ++j) {
                float v = acc[mi][si][j] * sc + sh;
                if (RELU) v = fmaxf(v, 0.f);
                if (OUT_NCHW) {
                    if (cok) ((float*)Yv)[col * 4096 + rbase + j] = v;  // fconv3: HW=4096
                } else if (cok) {
                    ((unsigned short*)Yv)[(size_t)(rbase + j) * Cout + col] = f2bf(v);
                }
            }
        }
    }
}

// ------- 81-shift correlation, NHWC bf16 -------
__global__ void correlation81(const unsigned short* __restrict__ cf,
                              const unsigned short* __restrict__ pf,
                              unsigned short* __restrict__ out) {
    int idx = blockIdx.x * 256 + threadIdx.x;
    if (idx >= 4096 * 81) return;
    int n = idx / 81, s = idx - n * 81;
    int h = n >> 6, w = n & 63;
    int q = s / 9;
    int di = q - 4, dj = s - q * 9 - 4;
    int h2 = h + di, w2 = w + dj;
    float acc = 0.f;
    if ((unsigned)h2 < 64u && (unsigned)w2 < 64u) {
        const unsigned short* a = cf + n * 256;
        const unsigned short* b = pf + (h2 * 64 + w2) * 256;
        for (int c = 0; c < 256; c += 8) {
            u16x8 av = *(const u16x8*)&a[c];
            u16x8 bv = *(const u16x8*)&b[c];
            #pragma unroll
            for (int j = 0; j < 8; ++j) acc += bf2f(av[j]) * bf2f(bv[j]);
        }
    }
    out[idx] = f2bf(acc);
}

// ---------------- launch ----------------
extern "C" void kernel_launch(void* const* d_in, const int* in_sizes, int n_in,
                              void* d_out, int out_size, void* d_ws, size_t ws_size,
                              hipStream_t stream) {
    const float* cloth  = (const float*)d_in[0];
    const float* person = (const float*)d_in[1];
    const float* w1 = (const float*)d_in[2];  const float* b1 = (const float*)d_in[3];
    const float* g1 = (const float*)d_in[4];  const float* be1 = (const float*)d_in[5];
    const float* m1 = (const float*)d_in[6];  const float* v1 = (const float*)d_in[7];
    const float* w2 = (const float*)d_in[8];  const float* b2 = (const float*)d_in[9];
    const float* g2 = (const float*)d_in[10]; const float* be2 = (const float*)d_in[11];
    const float* m2 = (const float*)d_in[12]; const float* v2 = (const float*)d_in[13];
    const float* w3 = (const float*)d_in[14]; const float* b3 = (const float*)d_in[15];
    const float* g3 = (const float*)d_in[16]; const float* be3 = (const float*)d_in[17];
    const float* m3 = (const float*)d_in[18]; const float* v3 = (const float*)d_in[19];
    const float* fw1 = (const float*)d_in[20]; const float* fb1 = (const float*)d_in[21];
    const float* fw2 = (const float*)d_in[22]; const float* fb2 = (const float*)d_in[23];
    const float* fw3 = (const float*)d_in[24]; const float* fb3 = (const float*)d_in[25];

    char* ws = (char*)d_ws;
    auto U = [&](size_t off) { return (unsigned short*)(ws + off); };
    // layout (bytes), peak ~37.0 MB < proven 38.03 MB
    unsigned short* bufI  = U(0);          // conv1 im2col 20,971,520
    unsigned short* t2    = U(0);          // aliases bufI (4,194,304) after conv1 GEMM
    unsigned short* i2c2  = U(8388608);    // fconv1 im2col 6,029,312 (t2 dead by then)
    unsigned short* t1    = U(20971520);   // 8,388,608
    unsigned short* cfb   = U(29360128);   // 2,097,152
    unsigned short* pfb   = U(31457280);   // 2,097,152
    unsigned short* corr  = U(33554432);   //   663,552
    unsigned short* f1b   = U(34217984);   // 1,048,576
    unsigned short* f2b   = U(35266560);   //   524,288
    unsigned short* w1mk  = U(35790848);   //    20,480 (64x160)
    unsigned short* w2mk  = U(35811328);   //   147,456 (128x576)
    unsigned short* w3mk  = U(35958784);   //   589,824 (256x1152)
    unsigned short* fw1mk = U(36548608);   //   188,416 (128x736)
    unsigned short* fw2mk = U(36737024);   //   147,456 (64x1152)
    unsigned short* fw3mk = U(36884480);   //    73,728 (64x576)
    float* aff = (float*)(ws + 36958208);
    float *s1 = aff,        *sh1 = aff + 64,  *s2 = aff + 128, *sh2 = aff + 256;
    float *s3 = aff + 384,  *sh3 = aff + 640, *sf1 = aff + 896, *shf1 = aff + 1024;
    float *sf2 = aff + 1152, *shf2 = aff + 1216, *sf3 = aff + 1280, *shf3 = aff + 1288;

    prep_affine<<<1, 64, 0, stream>>>(b1, g1, be1, m1, v1, s1, sh1, 64, 1);
    prep_affine<<<1, 128, 0, stream>>>(b2, g2, be2, m2, v2, s2, sh2, 128, 1);
    prep_affine<<<1, 256, 0, stream>>>(b3, g3, be3, m3, v3, s3, sh3, 256, 1);
    prep_affine<<<1, 128, 0, stream>>>(fb1, nullptr, nullptr, nullptr, nullptr, sf1, shf1, 128, 0);
    prep_affine<<<1, 64, 0, stream>>>(fb2, nullptr, nullptr, nullptr, nullptr, sf2, shf2, 64, 0);
    prep_affine<<<1, 2, 0, stream>>>(fb3, nullptr, nullptr, nullptr, nullptr, sf3, shf3, 2, 0);

    conv_weights<3, 7><<<40, 256, 0, stream>>>(w1, w1mk, 64, 64, 160);
    conv_weights<64, 3><<<288, 256, 0, stream>>>(w2, w2mk, 128, 128, 576);
    conv_weights<128, 3><<<1152, 256, 0, stream>>>(w3, w3mk, 256, 256, 1152);
    conv_weights<81, 3><<<368, 256, 0, stream>>>(fw1, fw1mk, 128, 128, 736);
    conv_weights<128, 3><<<288, 256, 0, stream>>>(fw2, fw2mk, 64, 64, 1152);
    conv_weights<64, 3><<<144, 256, 0, stream>>>(fw3, fw3mk, 2, 64, 576);

    for (int b = 0; b < 8; ++b) {
        const float* imgs[2] = {cloth + (size_t)b * 786432, person + (size_t)b * 786432};
        unsigned short* feats[2] = {cfb, pfb};
        for (int i = 0; i < 2; ++i) {
            // conv1: im2col (K=147->160) + GEMM 64ch, R=65536
            im2col_k<3, 7, true><<<40960, 256, 0, stream>>>(imgs[i], bufI, 65536, 160, 512, 512, 8, 2, 3);
            gemm_conv<4, 1, false, true, false><<<dim3(256, 1), 256, 0, stream>>>(
                bufI, w1mk, s1, sh1, t1, 160, 64, 0, 0, 0, 0, 0);
            // conv2: implicit, t1[256x256x64] -> t2[128x128x128]
            gemm_conv<2, 2, true, true, false><<<dim3(128, 1), 256, 0, stream>>>(
                t1, w2mk, s2, sh2, t2, 576, 128, 256, 256, 6, 7, 2);
            // conv3: implicit, t2[128x128x128] -> feats[4096x256]
            gemm_conv<2, 2, true, true, false><<<dim3(32, 2), 256, 0, stream>>>(
                t2, w3mk, s3, sh3, feats[i], 1152, 256, 128, 128, 7, 6, 2);
        }
        correlation81<<<1296, 256, 0, stream>>>(cfb, pfb, corr);
        // fconv1: im2col (K=729->736) + GEMM 128ch
        im2col_k<81, 3, false><<<11776, 256, 0, stream>>>(corr, i2c2, 4096, 736, 64, 64, 6, 1, 1);
        gemm_conv<2, 2, false, true, false><<<dim3(32, 1), 256, 0, stream>>>(
            i2c2, fw1mk, sf1, shf1, f1b, 736, 128, 0, 0, 0, 0, 0);
        // fconv2: implicit, f1b[64x64x128] -> f2b[4096x64]
        gemm_conv<4, 1, true, true, false><<<dim3(16, 1), 256, 0, stream>>>(
            f1b, fw2mk, sf2, shf2, f2b, 1152, 64, 64, 64, 7, 6, 1);
        // fconv3: implicit, f2b[64x64x64] -> d_out NCHW fp32 [2][64][64]
        gemm_conv<4, 1, true, false, true><<<dim3(16, 1), 256, 0, stream>>>(
            f2b, fw3mk, sf3, shf3, (float*)d_out + (size_t)b * 8192, 576, 2, 64, 64, 6, 6, 1);
    }
}

// Round 5
// 537.091 us; speedup vs baseline: 55.3140x; 3.8874x over previous
//
#include <hip/hip_runtime.h>

typedef __bf16 bf16x8_t __attribute__((ext_vector_type(8)));
typedef float f32x4 __attribute__((ext_vector_type(4)));
typedef unsigned short u16x8 __attribute__((ext_vector_type(8)));
typedef unsigned short u16x4 __attribute__((ext_vector_type(4)));

#define EPS 1e-5f

__device__ __forceinline__ unsigned short f2bf(float f) {
    unsigned u = __builtin_bit_cast(unsigned, f);
    u += 0x7fff + ((u >> 16) & 1);          // RTNE
    return (unsigned short)(u >> 16);
}
__device__ __forceinline__ float bf2f(unsigned short h) {
    unsigned u = ((unsigned)h) << 16;
    return __builtin_bit_cast(float, u);
}

// ---------------- BN fold ----------------
__global__ void prep_affine(const float* __restrict__ cb, const float* __restrict__ g,
                            const float* __restrict__ be, const float* __restrict__ m,
                            const float* __restrict__ v, float* __restrict__ scale,
                            float* __restrict__ shift, int C, int has_bn) {
    int c = blockIdx.x * blockDim.x + threadIdx.x;
    if (c >= C) return;
    if (has_bn) {
        float s = g[c] * rsqrtf(v[c] + EPS);
        scale[c] = s;
        shift[c] = (cb[c] - m[c]) * s + be[c];
    } else {
        scale[c] = 1.0f;
        shift[c] = cb[c];
    }
}

// ------- weights OIHW fp32 -> [Sp][Kp] bf16, k = tap*CINP + ic -------
template <int CIN, int CINP, int KHW>
__global__ void conv_weights(const float* __restrict__ w, unsigned short* __restrict__ dst,
                             int Cout, int Sp, int Kp) {
    int idx = blockIdx.x * 256 + threadIdx.x;
    if (idx >= Sp * Kp) return;
    int m = idx / Kp, k = idx - m * Kp;
    int tap = k / CINP, ic = k - tap * CINP;
    unsigned short v = 0;
    if (m < Cout && tap < KHW * KHW && ic < CIN) {
        int kh = tap / KHW, kw = tap - kh * KHW;
        v = f2bf(w[((m * CIN + ic) * KHW + kh) * KHW + kw]);
    }
    dst[idx] = v;
}

// ------- input NCHW fp32 [3][512][512] -> NHWC4 bf16 [512][512][4], z = image -------
__global__ void to_nhwc4(const float* __restrict__ cloth, const float* __restrict__ person,
                         unsigned short* __restrict__ dst) {
    int z = blockIdx.z;
    const float* src = (z < 8) ? cloth + (size_t)z * 786432
                               : person + (size_t)(z - 8) * 786432;
    int p = blockIdx.x * 256 + threadIdx.x;  // pixel 0..262143
    u16x4 o;
    o[0] = f2bf(src[p]);
    o[1] = f2bf(src[262144 + p]);
    o[2] = f2bf(src[524288 + p]);
    o[3] = 0;
    *(u16x4*)&dst[(size_t)z * 1048576 + (size_t)p * 4] = o;
}

// ------- MFMA GEMM with implicit im2col, fused scale/shift/relu -------
// MODE 1: 3x3 pad-1 conv, X = NHWC bf16, Cin % 32 == 0 (K layout tap*Cin+ic)
// MODE 2: conv1 7x7 s2 p3, X = NHWC4 bf16 [512][512][4], K layout tap*4+ic, Kp=224
// Wave tile 64x64; block = WR x WS waves; grid (R/BR, ceil(Cout/BS), nimg).
template <int WR, int WS, int MODE, bool RELU, bool OUT_NCHW>
__global__ __launch_bounds__(WR * WS * 64)
void gemm_conv(const unsigned short* __restrict__ X, const unsigned short* __restrict__ Wmk,
               const float* __restrict__ scale, const float* __restrict__ shift,
               void* __restrict__ Yv, int Kp, int Cout,
               int Hin, int Win, int Cin, int WoutShift, int stride,
               int xImgStride, int yImgStride) {
    constexpr int BR = WR * 64, BS = WS * 64, LDK = 40, NT = WR * WS * 64;
    constexpr int SX = (BR * 4) / NT, SW = (BS * 4) / NT;
    __shared__ unsigned short Xs[BR * LDK];
    __shared__ unsigned short Ws[BS * LDK];
    const int tid = threadIdx.x;
    const int lane = tid & 63, wid = tid >> 6;
    const int wr = wid % WR, wsx = wid / WR;
    const int r0 = blockIdx.x * BR, s0 = blockIdx.y * BS;
    const int z = blockIdx.z;
    const int lr = lane & 15, lk = lane >> 4;
    const unsigned short* Ximg = X + (size_t)z * xImgStride;

    int xrow[SX], xc[SX], xoh[SX], xow[SX];
    #pragma unroll
    for (int i = 0; i < SX; ++i) {
        int c = i * NT + tid;
        xrow[i] = c >> 2; xc[i] = c & 3;
        int r = r0 + xrow[i];
        xoh[i] = r >> WoutShift;
        xow[i] = r & ((1 << WoutShift) - 1);
    }
    int wrow[SW], wc[SW];
    #pragma unroll
    for (int i = 0; i < SW; ++i) {
        int c = i * NT + tid;
        wrow[i] = c >> 2; wc[i] = c & 3;
    }

    const f32x4 fz = {0.f, 0.f, 0.f, 0.f};
    f32x4 acc[4][4];
    #pragma unroll
    for (int a = 0; a < 4; ++a)
        #pragma unroll
        for (int b = 0; b < 4; ++b) acc[a][b] = fz;

    int tap = 0, icb = 0;   // MODE 1 K-walk (Cin % 32 == 0)
    const int nkt = Kp >> 5;
    for (int kt = 0; kt < nkt; ++kt) {
        const int k0 = kt << 5;
        u16x8 xv[SX], wv[SW];
        if (MODE == 1) {
            int kh = tap / 3, kw = tap - kh * 3;
            #pragma unroll
            for (int i = 0; i < SX; ++i) {
                int ih = xoh[i] * stride - 1 + kh;
                int iw = xow[i] * stride - 1 + kw;
                u16x8 v = {0, 0, 0, 0, 0, 0, 0, 0};
                if ((unsigned)ih < (unsigned)Hin && (unsigned)iw < (unsigned)Win)
                    v = *(const u16x8*)&Ximg[(size_t)(ih * Win + iw) * Cin + icb + xc[i] * 8];
                xv[i] = v;
            }
        } else {  // MODE 2: two taps of 4 channels per 8-chunk
            #pragma unroll
            for (int i = 0; i < SX; ++i) {
                u16x4 half_[2];
                int t0 = (k0 >> 2) + xc[i] * 2;
                #pragma unroll
                for (int h = 0; h < 2; ++h) {
                    u16x4 v = {0, 0, 0, 0};
                    int t = t0 + h;
                    if (t < 49) {
                        int kh = t / 7, kw = t - kh * 7;
                        int ih = xoh[i] * 2 - 3 + kh;
                        int iw = xow[i] * 2 - 3 + kw;
                        if ((unsigned)ih < 512u && (unsigned)iw < 512u)
                            v = *(const u16x4*)&Ximg[((size_t)(ih * 512 + iw)) * 4];
                    }
                    half_[h] = v;
                }
                u16x8 full;
                #pragma unroll
                for (int j = 0; j < 4; ++j) { full[j] = half_[0][j]; full[4 + j] = half_[1][j]; }
                xv[i] = full;
            }
        }
        #pragma unroll
        for (int i = 0; i < SW; ++i)
            wv[i] = *(const u16x8*)&Wmk[(size_t)(s0 + wrow[i]) * Kp + wc[i] * 8 + k0];

        __syncthreads();  // previous iteration's fragment reads done
        #pragma unroll
        for (int i = 0; i < SX; ++i) *(u16x8*)&Xs[xrow[i] * LDK + xc[i] * 8] = xv[i];
        #pragma unroll
        for (int i = 0; i < SW; ++i) *(u16x8*)&Ws[wrow[i] * LDK + wc[i] * 8] = wv[i];
        __syncthreads();

        u16x8 af[4], bfr[4];
        #pragma unroll
        for (int mi = 0; mi < 4; ++mi)
            af[mi] = *(const u16x8*)&Xs[(wr * 64 + mi * 16 + lr) * LDK + lk * 8];
        #pragma unroll
        for (int si = 0; si < 4; ++si)
            bfr[si] = *(const u16x8*)&Ws[(wsx * 64 + si * 16 + lr) * LDK + lk * 8];
        #pragma unroll
        for (int mi = 0; mi < 4; ++mi)
            #pragma unroll
            for (int si = 0; si < 4; ++si)
                acc[mi][si] = __builtin_amdgcn_mfma_f32_16x16x32_bf16(
                    __builtin_bit_cast(bf16x8_t, af[mi]),
                    __builtin_bit_cast(bf16x8_t, bfr[si]), acc[mi][si], 0, 0, 0);

        if (MODE == 1) { icb += 32; if (icb >= Cin) { icb = 0; ++tap; } }
    }

    // epilogue: D row=(lane>>4)*4+reg, col=lane&15 (per 16x16 fragment)
    #pragma unroll
    for (int si = 0; si < 4; ++si) {
        int col = s0 + wsx * 64 + si * 16 + lr;
        bool cok = col < Cout;
        float sc = cok ? scale[col] : 0.f;
        float sh = cok ? shift[col] : 0.f;
        #pragma unroll
        for (int mi = 0; mi < 4; ++mi) {
            int rbase = r0 + wr * 64 + mi * 16 + lk * 4;
            #pragma unroll
            for (int j = 0; j < 4; ++j) {
                float v = acc[mi][si][j] * sc + sh;
                if (RELU) v = fmaxf(v, 0.f);
                if (OUT_NCHW) {
                    if (cok) ((float*)Yv)[(size_t)z * yImgStride + col * 4096 + rbase + j] = v;
                } else if (cok) {
                    ((unsigned short*)Yv)[(size_t)z * yImgStride + (size_t)(rbase + j) * Cout + col] = f2bf(v);
                }
            }
        }
    }
}

// ------- 81-shift correlation, NHWC bf16 [4096][256] -> padded [4096][96], z = image -------
__global__ void correlation81(const unsigned short* __restrict__ cf,
                              const unsigned short* __restrict__ pf,
                              unsigned short* __restrict__ out) {
    int z = blockIdx.z;
    int idx = blockIdx.x * 256 + threadIdx.x;
    if (idx >= 4096 * 96) return;
    int n = idx / 96, s = idx - n * 96;
    int h = n >> 6, w = n & 63;
    unsigned short r = 0;
    if (s < 81) {
        int q = s / 9;
        int di = q - 4, dj = s - q * 9 - 4;
        int h2 = h + di, w2 = w + dj;
        float acc = 0.f;
        if ((unsigned)h2 < 64u && (unsigned)w2 < 64u) {
            const unsigned short* a = cf + (size_t)z * 1048576 + n * 256;
            const unsigned short* b = pf + (size_t)z * 1048576 + (h2 * 64 + w2) * 256;
            for (int c = 0; c < 256; c += 8) {
                u16x8 av = *(const u16x8*)&a[c];
                u16x8 bv = *(const u16x8*)&b[c];
                #pragma unroll
                for (int j = 0; j < 8; ++j) acc += bf2f(av[j]) * bf2f(bv[j]);
            }
        }
        r = f2bf(acc);
    }
    out[(size_t)z * 393216 + idx] = r;
}

// ---------------- launch ----------------
extern "C" void kernel_launch(void* const* d_in, const int* in_sizes, int n_in,
                              void* d_out, int out_size, void* d_ws, size_t ws_size,
                              hipStream_t stream) {
    const float* cloth  = (const float*)d_in[0];
    const float* person = (const float*)d_in[1];
    const float* w1 = (const float*)d_in[2];  const float* b1 = (const float*)d_in[3];
    const float* g1 = (const float*)d_in[4];  const float* be1 = (const float*)d_in[5];
    const float* m1 = (const float*)d_in[6];  const float* v1 = (const float*)d_in[7];
    const float* w2 = (const float*)d_in[8];  const float* b2 = (const float*)d_in[9];
    const float* g2 = (const float*)d_in[10]; const float* be2 = (const float*)d_in[11];
    const float* m2 = (const float*)d_in[12]; const float* v2 = (const float*)d_in[13];
    const float* w3 = (const float*)d_in[14]; const float* b3 = (const float*)d_in[15];
    const float* g3 = (const float*)d_in[16]; const float* be3 = (const float*)d_in[17];
    const float* m3 = (const float*)d_in[18]; const float* v3 = (const float*)d_in[19];
    const float* fw1 = (const float*)d_in[20]; const float* fb1 = (const float*)d_in[21];
    const float* fw2 = (const float*)d_in[22]; const float* fb2 = (const float*)d_in[23];
    const float* fw3 = (const float*)d_in[24]; const float* fb3 = (const float*)d_in[25];

    char* ws = (char*)d_ws;
    auto U = [&](size_t off) { return (unsigned short*)(ws + off); };
    // ---- layout (bytes), ws_size = 256 MiB = 268,435,456 ----
    unsigned short* nhwc = U(0);            // 16 x 2,097,152  = 33,554,432
    unsigned short* t1   = U(33554432);     // 16 x 8,388,608  = 134,217,728
    unsigned short* cf   = U(33554432);     // alias t1 (dead after conv2): 16 x 2,097,152
    unsigned short* t2   = U(167772160);    // 16 x 4,194,304  = 67,108,864
    // tail region [234,881,024 .. 268,435,456)
    unsigned short* corr = U(234881024);    // 8 x 786,432   = 6,291,456
    unsigned short* f1b  = U(241172480);    // 8 x 1,048,576 = 8,388,608
    unsigned short* f2b  = U(249561088);    // 8 x 524,288   = 4,194,304
    unsigned short* w1mk  = U(253755392);   //  28,672 (64x224)
    unsigned short* w2mk  = U(253784064);   // 147,456 (128x576)
    unsigned short* w3mk  = U(253931520);   // 589,824 (256x1152)
    unsigned short* fw1mk = U(254521344);   // 221,184 (128x864)
    unsigned short* fw2mk = U(254742528);   // 147,456 (64x1152)
    unsigned short* fw3mk = U(254889984);   //  73,728 (64x576)
    float* aff = (float*)(ws + 254963712);
    float *s1 = aff,         *sh1 = aff + 64,   *s2 = aff + 128,  *sh2 = aff + 256;
    float *s3 = aff + 384,   *sh3 = aff + 640,  *sf1 = aff + 896, *shf1 = aff + 1024;
    float *sf2 = aff + 1152, *shf2 = aff + 1216, *sf3 = aff + 1280, *shf3 = aff + 1288;

    prep_affine<<<1, 64, 0, stream>>>(b1, g1, be1, m1, v1, s1, sh1, 64, 1);
    prep_affine<<<1, 128, 0, stream>>>(b2, g2, be2, m2, v2, s2, sh2, 128, 1);
    prep_affine<<<1, 256, 0, stream>>>(b3, g3, be3, m3, v3, s3, sh3, 256, 1);
    prep_affine<<<1, 128, 0, stream>>>(fb1, nullptr, nullptr, nullptr, nullptr, sf1, shf1, 128, 0);
    prep_affine<<<1, 64, 0, stream>>>(fb2, nullptr, nullptr, nullptr, nullptr, sf2, shf2, 64, 0);
    prep_affine<<<1, 2, 0, stream>>>(fb3, nullptr, nullptr, nullptr, nullptr, sf3, shf3, 2, 0);

    conv_weights<3, 4, 7><<<56, 256, 0, stream>>>(w1, w1mk, 64, 64, 224);
    conv_weights<64, 64, 3><<<288, 256, 0, stream>>>(w2, w2mk, 128, 128, 576);
    conv_weights<128, 128, 3><<<1152, 256, 0, stream>>>(w3, w3mk, 256, 256, 1152);
    conv_weights<81, 96, 3><<<432, 256, 0, stream>>>(fw1, fw1mk, 128, 128, 864);
    conv_weights<128, 128, 3><<<288, 256, 0, stream>>>(fw2, fw2mk, 64, 64, 1152);
    conv_weights<64, 64, 3><<<144, 256, 0, stream>>>(fw3, fw3mk, 2, 64, 576);

    // input -> NHWC4 bf16, all 16 images
    to_nhwc4<<<dim3(1024, 1, 16), 256, 0, stream>>>(cloth, person, nhwc);

    // conv1: 7x7 s2 p3, NHWC4 [512,512,4] -> t1 NHWC [256,256,64]  (R=65536/BR=256)
    gemm_conv<4, 1, 2, true, false><<<dim3(256, 1, 16), 256, 0, stream>>>(
        nhwc, w1mk, s1, sh1, t1, 224, 64, 512, 512, 4, 8, 2, 1048576, 4194304);
    // conv2: 3x3 s2 p1, t1 -> t2 NHWC [128,128,128]  (R=16384/BR=128 -> 128 blocks)
    gemm_conv<2, 2, 1, true, false><<<dim3(128, 1, 16), 256, 0, stream>>>(
        t1, w2mk, s2, sh2, t2, 576, 128, 256, 256, 64, 7, 2, 4194304, 2097152);
    // conv3: 3x3 s2 p1, t2 -> cf/pf NHWC [64,64,256]  (R=4096/BR=128 -> 32 blocks)
    gemm_conv<2, 2, 1, true, false><<<dim3(32, 2, 16), 256, 0, stream>>>(
        t2, w3mk, s3, sh3, cf, 1152, 256, 128, 128, 128, 6, 2, 2097152, 1048576);

    // correlation -> padded [4096][96]
    correlation81<<<dim3(1536, 1, 8), 256, 0, stream>>>(cf, cf + (size_t)8 * 1048576, corr);

    // fconv1: 3x3 p1, corr NHWC96 -> f1 NHWC [64,64,128]
    gemm_conv<2, 2, 1, true, false><<<dim3(32, 1, 8), 256, 0, stream>>>(
        corr, fw1mk, sf1, shf1, f1b, 864, 128, 64, 64, 96, 6, 1, 393216, 524288);
    // fconv2: 3x3 p1, f1 -> f2 NHWC [64,64,64]
    gemm_conv<2, 1, 1, true, false><<<dim3(32, 1, 8), 128, 0, stream>>>(
        f1b, fw2mk, sf2, shf2, f2b, 1152, 64, 64, 64, 128, 6, 1, 524288, 262144);
    // fconv3: 3x3 p1, f2 -> d_out NCHW fp32 [8][2][64][64]
    gemm_conv<2, 1, 1, false, true><<<dim3(32, 1, 8), 128, 0, stream>>>(
        f2b, fw3mk, sf3, shf3, (float*)d_out, 576, 2, 64, 64, 64, 6, 1, 262144, 8192);
}

// Round 6
// 380.176 us; speedup vs baseline: 78.1445x; 1.4127x over previous
//
#include <hip/hip_runtime.h>

typedef __bf16 bf16x8_t __attribute__((ext_vector_type(8)));
typedef float f32x4 __attribute__((ext_vector_type(4)));
typedef unsigned short u16x8 __attribute__((ext_vector_type(8)));
typedef unsigned short u16x4 __attribute__((ext_vector_type(4)));

#define EPS 1e-5f

__device__ __forceinline__ unsigned short f2bf(float f) {
    unsigned u = __builtin_bit_cast(unsigned, f);
    u += 0x7fff + ((u >> 16) & 1);          // RTNE
    return (unsigned short)(u >> 16);
}
__device__ __forceinline__ float bf2f(unsigned short h) {
    unsigned u = ((unsigned)h) << 16;
    return __builtin_bit_cast(float, u);
}

// ---------------- BN fold ----------------
__global__ void prep_affine(const float* __restrict__ cb, const float* __restrict__ g,
                            const float* __restrict__ be, const float* __restrict__ m,
                            const float* __restrict__ v, float* __restrict__ scale,
                            float* __restrict__ shift, int C, int has_bn) {
    int c = blockIdx.x * blockDim.x + threadIdx.x;
    if (c >= C) return;
    if (has_bn) {
        float s = g[c] * rsqrtf(v[c] + EPS);
        scale[c] = s;
        shift[c] = (cb[c] - m[c]) * s + be[c];
    } else {
        scale[c] = 1.0f;
        shift[c] = cb[c];
    }
}

// ------- weights OIHW fp32 -> [Sp][Kp] bf16, k = tap*CINP + ic -------
template <int CIN, int CINP, int KHW>
__global__ void conv_weights(const float* __restrict__ w, unsigned short* __restrict__ dst,
                             int Cout, int Sp, int Kp) {
    int idx = blockIdx.x * 256 + threadIdx.x;
    if (idx >= Sp * Kp) return;
    int m = idx / Kp, k = idx - m * Kp;
    int tap = k / CINP, ic = k - tap * CINP;
    unsigned short v = 0;
    if (m < Cout && tap < KHW * KHW && ic < CIN) {
        int kh = tap / KHW, kw = tap - kh * KHW;
        v = f2bf(w[((m * CIN + ic) * KHW + kh) * KHW + kw]);
    }
    dst[idx] = v;
}

// ------- input NCHW fp32 [3][512][512] -> NHWC4 bf16 [512][512][4], z = image -------
__global__ void to_nhwc4(const float* __restrict__ cloth, const float* __restrict__ person,
                         unsigned short* __restrict__ dst) {
    int z = blockIdx.z;
    const float* src = (z < 8) ? cloth + (size_t)z * 786432
                               : person + (size_t)(z - 8) * 786432;
    int p = blockIdx.x * 256 + threadIdx.x;  // pixel 0..262143
    u16x4 o;
    o[0] = f2bf(src[p]);
    o[1] = f2bf(src[262144 + p]);
    o[2] = f2bf(src[524288 + p]);
    o[3] = 0;
    *(u16x4*)&dst[(size_t)z * 1048576 + (size_t)p * 4] = o;
}

// ------- MFMA GEMM with implicit im2col, fused scale/shift/relu -------
// MODE 1: 3x3 pad-1 conv, X = NHWC bf16, Cin % 32 == 0 (K layout tap*Cin+ic)
// MODE 2: conv1 7x7 s2 p3, X = NHWC4 bf16 [512][512][4], K layout tap*4+ic, Kp=224
// Wave tile 64x64; block = WR x WS waves; grid (R/BR, ceil(Cout/BS), nimg).
template <int WR, int WS, int MODE, bool RELU, bool OUT_NCHW>
__global__ __launch_bounds__(WR * WS * 64)
void gemm_conv(const unsigned short* __restrict__ X, const unsigned short* __restrict__ Wmk,
               const float* __restrict__ scale, const float* __restrict__ shift,
               void* __restrict__ Yv, int Kp, int Cout,
               int Hin, int Win, int Cin, int WoutShift, int stride,
               int xImgStride, int yImgStride) {
    constexpr int BR = WR * 64, BS = WS * 64, LDK = 40, NT = WR * WS * 64;
    constexpr int SX = (BR * 4) / NT, SW = (BS * 4) / NT;
    __shared__ unsigned short Xs[BR * LDK];
    __shared__ unsigned short Ws[BS * LDK];
    const int tid = threadIdx.x;
    const int lane = tid & 63, wid = tid >> 6;
    const int wr = wid % WR, wsx = wid / WR;
    const int r0 = blockIdx.x * BR, s0 = blockIdx.y * BS;
    const int z = blockIdx.z;
    const int lr = lane & 15, lk = lane >> 4;
    const unsigned short* Ximg = X + (size_t)z * xImgStride;

    int xrow[SX], xc[SX], xoh[SX], xow[SX];
    #pragma unroll
    for (int i = 0; i < SX; ++i) {
        int c = i * NT + tid;
        xrow[i] = c >> 2; xc[i] = c & 3;
        int r = r0 + xrow[i];
        xoh[i] = r >> WoutShift;
        xow[i] = r & ((1 << WoutShift) - 1);
    }
    int wrow[SW], wc[SW];
    #pragma unroll
    for (int i = 0; i < SW; ++i) {
        int c = i * NT + tid;
        wrow[i] = c >> 2; wc[i] = c & 3;
    }

    const f32x4 fz = {0.f, 0.f, 0.f, 0.f};
    f32x4 acc[4][4];
    #pragma unroll
    for (int a = 0; a < 4; ++a)
        #pragma unroll
        for (int b = 0; b < 4; ++b) acc[a][b] = fz;

    int tap = 0, icb = 0;   // MODE 1 K-walk (Cin % 32 == 0)
    const int nkt = Kp >> 5;
    for (int kt = 0; kt < nkt; ++kt) {
        const int k0 = kt << 5;
        u16x8 xv[SX], wv[SW];
        if (MODE == 1) {
            int kh = tap / 3, kw = tap - kh * 3;
            #pragma unroll
            for (int i = 0; i < SX; ++i) {
                int ih = xoh[i] * stride - 1 + kh;
                int iw = xow[i] * stride - 1 + kw;
                u16x8 v = {0, 0, 0, 0, 0, 0, 0, 0};
                if ((unsigned)ih < (unsigned)Hin && (unsigned)iw < (unsigned)Win)
                    v = *(const u16x8*)&Ximg[(size_t)(ih * Win + iw) * Cin + icb + xc[i] * 8];
                xv[i] = v;
            }
        } else {  // MODE 2: two taps of 4 channels per 8-chunk
            #pragma unroll
            for (int i = 0; i < SX; ++i) {
                u16x4 half_[2];
                int t0 = (k0 >> 2) + xc[i] * 2;
                #pragma unroll
                for (int h = 0; h < 2; ++h) {
                    u16x4 v = {0, 0, 0, 0};
                    int t = t0 + h;
                    if (t < 49) {
                        int kh = t / 7, kw = t - kh * 7;
                        int ih = xoh[i] * 2 - 3 + kh;
                        int iw = xow[i] * 2 - 3 + kw;
                        if ((unsigned)ih < 512u && (unsigned)iw < 512u)
                            v = *(const u16x4*)&Ximg[((size_t)(ih * 512 + iw)) * 4];
                    }
                    half_[h] = v;
                }
                u16x8 full;
                #pragma unroll
                for (int j = 0; j < 4; ++j) { full[j] = half_[0][j]; full[4 + j] = half_[1][j]; }
                xv[i] = full;
            }
        }
        #pragma unroll
        for (int i = 0; i < SW; ++i)
            wv[i] = *(const u16x8*)&Wmk[(size_t)(s0 + wrow[i]) * Kp + wc[i] * 8 + k0];

        __syncthreads();  // previous iteration's fragment reads done
        #pragma unroll
        for (int i = 0; i < SX; ++i) *(u16x8*)&Xs[xrow[i] * LDK + xc[i] * 8] = xv[i];
        #pragma unroll
        for (int i = 0; i < SW; ++i) *(u16x8*)&Ws[wrow[i] * LDK + wc[i] * 8] = wv[i];
        __syncthreads();

        u16x8 af[4], bfr[4];
        #pragma unroll
        for (int mi = 0; mi < 4; ++mi)
            af[mi] = *(const u16x8*)&Xs[(wr * 64 + mi * 16 + lr) * LDK + lk * 8];
        #pragma unroll
        for (int si = 0; si < 4; ++si)
            bfr[si] = *(const u16x8*)&Ws[(wsx * 64 + si * 16 + lr) * LDK + lk * 8];
        #pragma unroll
        for (int mi = 0; mi < 4; ++mi)
            #pragma unroll
            for (int si = 0; si < 4; ++si)
                acc[mi][si] = __builtin_amdgcn_mfma_f32_16x16x32_bf16(
                    __builtin_bit_cast(bf16x8_t, af[mi]),
                    __builtin_bit_cast(bf16x8_t, bfr[si]), acc[mi][si], 0, 0, 0);

        if (MODE == 1) { icb += 32; if (icb >= Cin) { icb = 0; ++tap; } }
    }

    // epilogue: D row=(lane>>4)*4+reg, col=lane&15 (per 16x16 fragment)
    #pragma unroll
    for (int si = 0; si < 4; ++si) {
        int col = s0 + wsx * 64 + si * 16 + lr;
        bool cok = col < Cout;
        float sc = cok ? scale[col] : 0.f;
        float sh = cok ? shift[col] : 0.f;
        #pragma unroll
        for (int mi = 0; mi < 4; ++mi) {
            int rbase = r0 + wr * 64 + mi * 16 + lk * 4;
            #pragma unroll
            for (int j = 0; j < 4; ++j) {
                float v = acc[mi][si][j] * sc + sh;
                if (RELU) v = fmaxf(v, 0.f);
                if (OUT_NCHW) {
                    if (cok) ((float*)Yv)[(size_t)z * yImgStride + col * 4096 + rbase + j] = v;
                } else if (cok) {
                    ((unsigned short*)Yv)[(size_t)z * yImgStride + (size_t)(rbase + j) * Cout + col] = f2bf(v);
                }
            }
        }
    }
}

// ------- banded-MFMA 81-shift correlation -------
// cf, pf: NHWC bf16 [64][64][256] per image; out: padded [4096][96] bf16.
// Block = (h, z), 4 waves; wave t owns w-tile [16t, 16t+16).
// corr[(h,w)][(di+4)*9+dj+4] = QK^T band: Q = cf row h, K = pf row h+di.
__global__ __launch_bounds__(256)
void corr_mfma(const unsigned short* __restrict__ cf,
               const unsigned short* __restrict__ pf,
               unsigned short* __restrict__ out) {
    const int h = blockIdx.x;        // 0..63
    const int z = blockIdx.y;        // 0..7
    const int tid = threadIdx.x;
    const int lane = tid & 63, t = tid >> 6;
    const int lr = lane & 15, lk = lane >> 4;
    const unsigned short* cfi = cf + (size_t)z * 1048576;
    const unsigned short* pfi = pf + (size_t)z * 1048576;
    unsigned short* outp = out + (size_t)z * 393216;

    // A fragments: Q[w = 16t + lr][c], loaded once, reused for all 9 di
    u16x8 a[8];
    {
        const unsigned short* ap = cfi + ((size_t)(h * 64 + t * 16 + lr)) * 256 + lk * 8;
        #pragma unroll
        for (int ks = 0; ks < 8; ++ks) a[ks] = *(const u16x8*)(ap + ks * 32);
    }

    const u16x8 zz = {0, 0, 0, 0, 0, 0, 0, 0};
    for (int di = -4; di <= 4; ++di) {
        const int h2 = h + di;
        const bool hok = (unsigned)h2 < 64u;
        #pragma unroll
        for (int ct = 0; ct < 2; ++ct) {
            // B fragments: K[w' = 16t - 8 + 16ct + lr][c]; zero when OOB (zero-pad)
            const int wpg = t * 16 - 8 + ct * 16 + lr;
            u16x8 b[8];
            if (hok && (unsigned)wpg < 64u) {
                const unsigned short* bp = pfi + ((size_t)(h2 * 64 + wpg)) * 256 + lk * 8;
                #pragma unroll
                for (int ks = 0; ks < 8; ++ks) b[ks] = *(const u16x8*)(bp + ks * 32);
            } else {
                #pragma unroll
                for (int ks = 0; ks < 8; ++ks) b[ks] = zz;
            }
            // two accumulator chains to halve MFMA dependency latency
            f32x4 acc0 = {0.f, 0.f, 0.f, 0.f}, acc1 = {0.f, 0.f, 0.f, 0.f};
            #pragma unroll
            for (int ks = 0; ks < 8; ks += 2) {
                acc0 = __builtin_amdgcn_mfma_f32_16x16x32_bf16(
                    __builtin_bit_cast(bf16x8_t, a[ks]),
                    __builtin_bit_cast(bf16x8_t, b[ks]), acc0, 0, 0, 0);
                acc1 = __builtin_amdgcn_mfma_f32_16x16x32_bf16(
                    __builtin_bit_cast(bf16x8_t, a[ks + 1]),
                    __builtin_bit_cast(bf16x8_t, b[ks + 1]), acc1, 0, 0, 0);
            }
            // D: row (w_local) = lk*4 + j, col (w'_local) = lr
            const int wl = lk * 4;                 // + j
            const int wpl = ct * 16 - 8 + lr;      // w' - 16t
            #pragma unroll
            for (int j = 0; j < 4; ++j) {
                int dj = wpl - (wl + j);
                if (dj >= -4 && dj <= 4) {
                    int s = (di + 4) * 9 + dj + 4;
                    outp[(size_t)(h * 64 + t * 16 + wl + j) * 96 + s] =
                        f2bf(acc0[j] + acc1[j]);
                }
            }
        }
    }
}

// ---------------- launch ----------------
extern "C" void kernel_launch(void* const* d_in, const int* in_sizes, int n_in,
                              void* d_out, int out_size, void* d_ws, size_t ws_size,
                              hipStream_t stream) {
    const float* cloth  = (const float*)d_in[0];
    const float* person = (const float*)d_in[1];
    const float* w1 = (const float*)d_in[2];  const float* b1 = (const float*)d_in[3];
    const float* g1 = (const float*)d_in[4];  const float* be1 = (const float*)d_in[5];
    const float* m1 = (const float*)d_in[6];  const float* v1 = (const float*)d_in[7];
    const float* w2 = (const float*)d_in[8];  const float* b2 = (const float*)d_in[9];
    const float* g2 = (const float*)d_in[10]; const float* be2 = (const float*)d_in[11];
    const float* m2 = (const float*)d_in[12]; const float* v2 = (const float*)d_in[13];
    const float* w3 = (const float*)d_in[14]; const float* b3 = (const float*)d_in[15];
    const float* g3 = (const float*)d_in[16]; const float* be3 = (const float*)d_in[17];
    const float* m3 = (const float*)d_in[18]; const float* v3 = (const float*)d_in[19];
    const float* fw1 = (const float*)d_in[20]; const float* fb1 = (const float*)d_in[21];
    const float* fw2 = (const float*)d_in[22]; const float* fb2 = (const float*)d_in[23];
    const float* fw3 = (const float*)d_in[24]; const float* fb3 = (const float*)d_in[25];

    char* ws = (char*)d_ws;
    auto U = [&](size_t off) { return (unsigned short*)(ws + off); };
    // ---- layout (bytes), ws_size = 256 MiB = 268,435,456 ----
    unsigned short* nhwc = U(0);            // 16 x 2,097,152  = 33,554,432
    unsigned short* t1   = U(33554432);     // 16 x 8,388,608  = 134,217,728
    unsigned short* cf   = U(33554432);     // alias t1 (dead after conv2): 16 x 2,097,152
    unsigned short* t2   = U(167772160);    // 16 x 4,194,304  = 67,108,864
    // tail region [234,881,024 .. 268,435,456)
    unsigned short* corr = U(234881024);    // 8 x 786,432   = 6,291,456
    unsigned short* f1b  = U(241172480);    // 8 x 1,048,576 = 8,388,608
    unsigned short* f2b  = U(249561088);    // 8 x 524,288   = 4,194,304
    unsigned short* w1mk  = U(253755392);   //  28,672 (64x224)
    unsigned short* w2mk  = U(253784064);   // 147,456 (128x576)
    unsigned short* w3mk  = U(253931520);   // 589,824 (256x1152)
    unsigned short* fw1mk = U(254521344);   // 221,184 (128x864)
    unsigned short* fw2mk = U(254742528);   // 147,456 (64x1152)
    unsigned short* fw3mk = U(254889984);   //  73,728 (64x576)
    float* aff = (float*)(ws + 254963712);
    float *s1 = aff,         *sh1 = aff + 64,   *s2 = aff + 128,  *sh2 = aff + 256;
    float *s3 = aff + 384,   *sh3 = aff + 640,  *sf1 = aff + 896, *shf1 = aff + 1024;
    float *sf2 = aff + 1152, *shf2 = aff + 1216, *sf3 = aff + 1280, *shf3 = aff + 1288;

    prep_affine<<<1, 64, 0, stream>>>(b1, g1, be1, m1, v1, s1, sh1, 64, 1);
    prep_affine<<<1, 128, 0, stream>>>(b2, g2, be2, m2, v2, s2, sh2, 128, 1);
    prep_affine<<<1, 256, 0, stream>>>(b3, g3, be3, m3, v3, s3, sh3, 256, 1);
    prep_affine<<<1, 128, 0, stream>>>(fb1, nullptr, nullptr, nullptr, nullptr, sf1, shf1, 128, 0);
    prep_affine<<<1, 64, 0, stream>>>(fb2, nullptr, nullptr, nullptr, nullptr, sf2, shf2, 64, 0);
    prep_affine<<<1, 2, 0, stream>>>(fb3, nullptr, nullptr, nullptr, nullptr, sf3, shf3, 2, 0);

    conv_weights<3, 4, 7><<<56, 256, 0, stream>>>(w1, w1mk, 64, 64, 224);
    conv_weights<64, 64, 3><<<288, 256, 0, stream>>>(w2, w2mk, 128, 128, 576);
    conv_weights<128, 128, 3><<<1152, 256, 0, stream>>>(w3, w3mk, 256, 256, 1152);
    conv_weights<81, 96, 3><<<432, 256, 0, stream>>>(fw1, fw1mk, 128, 128, 864);
    conv_weights<128, 128, 3><<<288, 256, 0, stream>>>(fw2, fw2mk, 64, 64, 1152);
    conv_weights<64, 64, 3><<<144, 256, 0, stream>>>(fw3, fw3mk, 2, 64, 576);

    // input -> NHWC4 bf16, all 16 images
    to_nhwc4<<<dim3(1024, 1, 16), 256, 0, stream>>>(cloth, person, nhwc);

    // conv1: 7x7 s2 p3, NHWC4 [512,512,4] -> t1 NHWC [256,256,64]  (R=65536/BR=256)
    gemm_conv<4, 1, 2, true, false><<<dim3(256, 1, 16), 256, 0, stream>>>(
        nhwc, w1mk, s1, sh1, t1, 224, 64, 512, 512, 4, 8, 2, 1048576, 4194304);
    // conv2: 3x3 s2 p1, t1 -> t2 NHWC [128,128,128]  (R=16384/BR=128 -> 128 blocks)
    gemm_conv<2, 2, 1, true, false><<<dim3(128, 1, 16), 256, 0, stream>>>(
        t1, w2mk, s2, sh2, t2, 576, 128, 256, 256, 64, 7, 2, 4194304, 2097152);
    // conv3: 3x3 s2 p1, t2 -> cf/pf NHWC [64,64,256]  (R=4096/BR=128 -> 32 blocks)
    gemm_conv<2, 2, 1, true, false><<<dim3(32, 2, 16), 256, 0, stream>>>(
        t2, w3mk, s3, sh3, cf, 1152, 256, 128, 128, 128, 6, 2, 2097152, 1048576);

    // correlation (banded MFMA) -> padded [4096][96]
    corr_mfma<<<dim3(64, 8), 256, 0, stream>>>(cf, cf + (size_t)8 * 1048576, corr);

    // fconv1: 3x3 p1, corr NHWC96 -> f1 NHWC [64,64,128]
    gemm_conv<2, 2, 1, true, false><<<dim3(32, 1, 8), 256, 0, stream>>>(
        corr, fw1mk, sf1, shf1, f1b, 864, 128, 64, 64, 96, 6, 1, 393216, 524288);
    // fconv2: 3x3 p1, f1 -> f2 NHWC [64,64,64]
    gemm_conv<2, 1, 1, true, false><<<dim3(32, 1, 8), 128, 0, stream>>>(
        f1b, fw2mk, sf2, shf2, f2b, 1152, 64, 64, 64, 128, 6, 1, 524288, 262144);
    // fconv3: 3x3 p1, f2 -> d_out NCHW fp32 [8][2][64][64]
    gemm_conv<2, 1, 1, false, true><<<dim3(32, 1, 8), 128, 0, stream>>>(
        f2b, fw3mk, sf3, shf3, (float*)d_out, 576, 2, 64, 64, 64, 6, 1, 262144, 8192);
}

// Round 7
// 374.290 us; speedup vs baseline: 79.3735x; 1.0157x over previous
//
#include <hip/hip_runtime.h>

typedef __bf16 bf16x8_t __attribute__((ext_vector_type(8)));
typedef float f32x4 __attribute__((ext_vector_type(4)));
typedef unsigned short u16x8 __attribute__((ext_vector_type(8)));
typedef unsigned short u16x4 __attribute__((ext_vector_type(4)));

#define EPS 1e-5f

__device__ __forceinline__ unsigned short f2bf(float f) {
    unsigned u = __builtin_bit_cast(unsigned, f);
    u += 0x7fff + ((u >> 16) & 1);          // RTNE
    return (unsigned short)(u >> 16);
}

// ---------------- BN fold ----------------
__global__ void prep_affine(const float* __restrict__ cb, const float* __restrict__ g,
                            const float* __restrict__ be, const float* __restrict__ m,
                            const float* __restrict__ v, float* __restrict__ scale,
                            float* __restrict__ shift, int C, int has_bn) {
    int c = blockIdx.x * blockDim.x + threadIdx.x;
    if (c >= C) return;
    if (has_bn) {
        float s = g[c] * rsqrtf(v[c] + EPS);
        scale[c] = s;
        shift[c] = (cb[c] - m[c]) * s + be[c];
    } else {
        scale[c] = 1.0f;
        shift[c] = cb[c];
    }
}

// ------- 3x3 weights OIHW fp32 -> [Sp][Kp] bf16, k = tap*CINP + ic -------
template <int CIN, int CINP>
__global__ void conv_weights(const float* __restrict__ w, unsigned short* __restrict__ dst,
                             int Cout, int Sp, int Kp) {
    int idx = blockIdx.x * 256 + threadIdx.x;
    if (idx >= Sp * Kp) return;
    int m = idx / Kp, k = idx - m * Kp;
    int tap = k / CINP, ic = k - tap * CINP;
    unsigned short v = 0;
    if (m < Cout && tap < 9 && ic < CIN) {
        int kh = tap / 3, kw = tap - kh * 3;
        v = f2bf(w[((m * CIN + ic) * 3 + kh) * 3 + kw]);
    }
    dst[idx] = v;
}

// ------- conv1 weights [64,3,7,7] -> [64][224] bf16, k = kh*32 + kw*4 + ic -------
__global__ void conv_weights1(const float* __restrict__ w, unsigned short* __restrict__ dst) {
    int idx = blockIdx.x * 256 + threadIdx.x;
    if (idx >= 64 * 224) return;
    int m = idx / 224, k = idx - m * 224;
    int kh = k >> 5, r = k & 31, kw = r >> 2, ic = r & 3;
    unsigned short v = 0;
    if (kw < 7 && ic < 3) v = f2bf(w[((m * 3 + ic) * 7 + kh) * 7 + kw]);
    dst[idx] = v;
}

// ------- input NCHW fp32 [3][512][512] -> NHWC4 bf16 [512][512][4], z = image -------
__global__ void to_nhwc4(const float* __restrict__ cloth, const float* __restrict__ person,
                         unsigned short* __restrict__ dst) {
    int z = blockIdx.z;
    const float* src = (z < 8) ? cloth + (size_t)z * 786432
                               : person + (size_t)(z - 8) * 786432;
    int p = blockIdx.x * 256 + threadIdx.x;  // pixel 0..262143
    u16x4 o;
    o[0] = f2bf(src[p]);
    o[1] = f2bf(src[262144 + p]);
    o[2] = f2bf(src[524288 + p]);
    o[3] = 0;
    *(u16x4*)&dst[(size_t)z * 1048576 + (size_t)p * 4] = o;
}

// ------- MFMA GEMM with implicit im2col, fused scale/shift/relu -------
// MODE 1: 3x3 pad-1 conv, X = NHWC bf16, Cin = ICB*32, K layout tap*Cin+ic.
//         Static K-loop: 9 taps (addr/valid hoisted) x ICB chunks.
// MODE 2: conv1 7x7 s2 p3, X = NHWC4 bf16 [512][512][4], K layout kh*32+kw*4+ic.
//         One K-step = one input row; column validity K-invariant.
// Wave tile 64x64; block = WR x WS waves; grid (R/BR, ceil(Cout/BS), nimg).
template <int WR, int WS, int MODE, bool RELU, bool OUT_NCHW, int ICB>
__global__ __launch_bounds__(WR * WS * 64)
void gemm_conv(const unsigned short* __restrict__ X, const unsigned short* __restrict__ Wmk,
               const float* __restrict__ scale, const float* __restrict__ shift,
               void* __restrict__ Yv, int Cout,
               int Hin, int Win, int WoutShift, int stride,
               int xImgStride, int yImgStride) {
    constexpr int BR = WR * 64, BS = WS * 64, LDK = 40, NT = WR * WS * 64;
    constexpr int SX = (BR * 4) / NT, SW = (BS * 4) / NT;
    constexpr int CIN = ICB * 32;
    constexpr int KP = (MODE == 1) ? 9 * ICB * 32 : 224;
    __shared__ unsigned short Xs[BR * LDK];
    __shared__ unsigned short Ws[BS * LDK];
    const int tid = threadIdx.x;
    const int lane = tid & 63, wid = tid >> 6;
    const int wr = wid % WR, wsx = wid / WR;
    const int r0 = blockIdx.x * BR, s0 = blockIdx.y * BS;
    const int z = blockIdx.z;
    const int lr = lane & 15, lk = lane >> 4;
    const unsigned short* Ximg = X + (size_t)z * xImgStride;

    // K-invariant staging geometry
    int xrow[SX], xc[SX], xoh[SX], xow[SX];
    #pragma unroll
    for (int i = 0; i < SX; ++i) {
        int c = i * NT + tid;
        xrow[i] = c >> 2; xc[i] = c & 3;
        int r = r0 + xrow[i];
        xoh[i] = r >> WoutShift;
        xow[i] = r & ((1 << WoutShift) - 1);
    }
    const unsigned short* wbase[SW];
    int wrow[SW], wc[SW];
    #pragma unroll
    for (int i = 0; i < SW; ++i) {
        int c = i * NT + tid;
        wrow[i] = c >> 2; wc[i] = c & 3;
        wbase[i] = Wmk + (size_t)(s0 + wrow[i]) * KP + wc[i] * 8;
    }
    // hoisted LDS offsets
    int xs_off[SX], ws_off[SW];
    #pragma unroll
    for (int i = 0; i < SX; ++i) xs_off[i] = xrow[i] * LDK + xc[i] * 8;
    #pragma unroll
    for (int i = 0; i < SW; ++i) ws_off[i] = wrow[i] * LDK + wc[i] * 8;
    int af_off[4], bf_off[4];
    #pragma unroll
    for (int mi = 0; mi < 4; ++mi) af_off[mi] = (wr * 64 + mi * 16 + lr) * LDK + lk * 8;
    #pragma unroll
    for (int si = 0; si < 4; ++si) bf_off[si] = (wsx * 64 + si * 16 + lr) * LDK + lk * 8;

    const f32x4 fz = {0.f, 0.f, 0.f, 0.f};
    f32x4 acc[4][4];
    #pragma unroll
    for (int a = 0; a < 4; ++a)
        #pragma unroll
        for (int b = 0; b < 4; ++b) acc[a][b] = fz;

    // one BK=32 staging + MFMA round (xv/wv already in regs)
    auto round_ = [&](u16x8* xv, u16x8* wv) {
        __syncthreads();  // previous iteration's fragment reads done
        #pragma unroll
        for (int i = 0; i < SX; ++i) *(u16x8*)&Xs[xs_off[i]] = xv[i];
        #pragma unroll
        for (int i = 0; i < SW; ++i) *(u16x8*)&Ws[ws_off[i]] = wv[i];
        __syncthreads();
        u16x8 af[4], bfr[4];
        #pragma unroll
        for (int mi = 0; mi < 4; ++mi) af[mi] = *(const u16x8*)&Xs[af_off[mi]];
        #pragma unroll
        for (int si = 0; si < 4; ++si) bfr[si] = *(const u16x8*)&Ws[bf_off[si]];
        #pragma unroll
        for (int mi = 0; mi < 4; ++mi)
            #pragma unroll
            for (int si = 0; si < 4; ++si)
                acc[mi][si] = __builtin_amdgcn_mfma_f32_16x16x32_bf16(
                    __builtin_bit_cast(bf16x8_t, af[mi]),
                    __builtin_bit_cast(bf16x8_t, bfr[si]), acc[mi][si], 0, 0, 0);
    };

    if (MODE == 1) {
        #pragma unroll
        for (int tap = 0; tap < 9; ++tap) {
            const int kh = tap / 3, kw = tap - (tap / 3) * 3;  // compile-time
            const unsigned short* xptr[SX];
            bool xok[SX];
            #pragma unroll
            for (int i = 0; i < SX; ++i) {
                int ih = xoh[i] * stride - 1 + kh;
                int iw = xow[i] * stride - 1 + kw;
                xok[i] = ((unsigned)ih < (unsigned)Hin) & ((unsigned)iw < (unsigned)Win);
                xptr[i] = Ximg + (size_t)(ih * Win + iw) * CIN + xc[i] * 8;
            }
            #pragma unroll
            for (int ic = 0; ic < ICB; ++ic) {
                const int k0 = (tap * ICB + ic) * 32;
                u16x8 xv[SX], wv[SW];
                #pragma unroll
                for (int i = 0; i < SX; ++i) {
                    u16x8 v = {0, 0, 0, 0, 0, 0, 0, 0};
                    if (xok[i]) v = *(const u16x8*)(xptr[i] + ic * 32);
                    xv[i] = v;
                }
                #pragma unroll
                for (int i = 0; i < SW; ++i) wv[i] = *(const u16x8*)(wbase[i] + k0);
                round_(xv, wv);
            }
        }
    } else {
        // MODE 2: chunk xc covers kw = 2*xc + h (h=0,1), 4 ch each; kh = kt.
        int colb[SX], rowb[SX];
        bool cok0[SX], cok1[SX];
        #pragma unroll
        for (int i = 0; i < SX; ++i) {
            colb[i] = xow[i] * 2 - 3 + xc[i] * 2;
            cok0[i] = (unsigned)colb[i] < 512u;
            cok1[i] = (unsigned)(colb[i] + 1) < 512u;
            rowb[i] = xoh[i] * 2 - 3;
        }
        #pragma unroll
        for (int kt = 0; kt < 7; ++kt) {
            u16x8 xv[SX], wv[SW];
            #pragma unroll
            for (int i = 0; i < SX; ++i) {
                int ih = rowb[i] + kt;
                bool rok = (unsigned)ih < 512u;
                const unsigned short* rp = Ximg + (size_t)ih * 2048 + colb[i] * 4;
                u16x4 v0 = {0, 0, 0, 0}, v1 = {0, 0, 0, 0};
                if (rok & cok0[i]) v0 = *(const u16x4*)rp;
                if (rok & cok1[i]) v1 = *(const u16x4*)(rp + 4);
                u16x8 full;
                #pragma unroll
                for (int j = 0; j < 4; ++j) { full[j] = v0[j]; full[4 + j] = v1[j]; }
                xv[i] = full;
            }
            #pragma unroll
            for (int i = 0; i < SW; ++i) wv[i] = *(const u16x8*)(wbase[i] + kt * 32);
            round_(xv, wv);
        }
    }

    // epilogue: D row=(lane>>4)*4+reg, col=lane&15 (per 16x16 fragment)
    #pragma unroll
    for (int si = 0; si < 4; ++si) {
        int col = s0 + wsx * 64 + si * 16 + lr;
        bool cok = col < Cout;
        float sc = cok ? scale[col] : 0.f;
        float sh = cok ? shift[col] : 0.f;
        #pragma unroll
        for (int mi = 0; mi < 4; ++mi) {
            int rbase = r0 + wr * 64 + mi * 16 + lk * 4;
            #pragma unroll
            for (int j = 0; j < 4; ++j) {
                float v = acc[mi][si][j] * sc + sh;
                if (RELU) v = fmaxf(v, 0.f);
                if (OUT_NCHW) {
                    if (cok) ((float*)Yv)[(size_t)z * yImgStride + col * 4096 + rbase + j] = v;
                } else if (cok) {
                    ((unsigned short*)Yv)[(size_t)z * yImgStride + (size_t)(rbase + j) * Cout + col] = f2bf(v);
                }
            }
        }
    }
}

// ------- banded-MFMA 81-shift correlation -------
// cf, pf: NHWC bf16 [64][64][256] per image; out: padded [4096][96] bf16.
__global__ __launch_bounds__(256)
void corr_mfma(const unsigned short* __restrict__ cf,
               const unsigned short* __restrict__ pf,
               unsigned short* __restrict__ out) {
    const int h = blockIdx.x;        // 0..63
    const int z = blockIdx.y;        // 0..7
    const int tid = threadIdx.x;
    const int lane = tid & 63, t = tid >> 6;
    const int lr = lane & 15, lk = lane >> 4;
    const unsigned short* cfi = cf + (size_t)z * 1048576;
    const unsigned short* pfi = pf + (size_t)z * 1048576;
    unsigned short* outp = out + (size_t)z * 393216;

    u16x8 a[8];
    {
        const unsigned short* ap = cfi + ((size_t)(h * 64 + t * 16 + lr)) * 256 + lk * 8;
        #pragma unroll
        for (int ks = 0; ks < 8; ++ks) a[ks] = *(const u16x8*)(ap + ks * 32);
    }

    const u16x8 zz = {0, 0, 0, 0, 0, 0, 0, 0};
    for (int di = -4; di <= 4; ++di) {
        const int h2 = h + di;
        const bool hok = (unsigned)h2 < 64u;
        #pragma unroll
        for (int ct = 0; ct < 2; ++ct) {
            const int wpg = t * 16 - 8 + ct * 16 + lr;
            u16x8 b[8];
            if (hok && (unsigned)wpg < 64u) {
                const unsigned short* bp = pfi + ((size_t)(h2 * 64 + wpg)) * 256 + lk * 8;
                #pragma unroll
                for (int ks = 0; ks < 8; ++ks) b[ks] = *(const u16x8*)(bp + ks * 32);
            } else {
                #pragma unroll
                for (int ks = 0; ks < 8; ++ks) b[ks] = zz;
            }
            f32x4 acc0 = {0.f, 0.f, 0.f, 0.f}, acc1 = {0.f, 0.f, 0.f, 0.f};
            #pragma unroll
            for (int ks = 0; ks < 8; ks += 2) {
                acc0 = __builtin_amdgcn_mfma_f32_16x16x32_bf16(
                    __builtin_bit_cast(bf16x8_t, a[ks]),
                    __builtin_bit_cast(bf16x8_t, b[ks]), acc0, 0, 0, 0);
                acc1 = __builtin_amdgcn_mfma_f32_16x16x32_bf16(
                    __builtin_bit_cast(bf16x8_t, a[ks + 1]),
                    __builtin_bit_cast(bf16x8_t, b[ks + 1]), acc1, 0, 0, 0);
            }
            const int wl = lk * 4;
            const int wpl = ct * 16 - 8 + lr;
            #pragma unroll
            for (int j = 0; j < 4; ++j) {
                int dj = wpl - (wl + j);
                if (dj >= -4 && dj <= 4) {
                    int s = (di + 4) * 9 + dj + 4;
                    outp[(size_t)(h * 64 + t * 16 + wl + j) * 96 + s] =
                        f2bf(acc0[j] + acc1[j]);
                }
            }
        }
    }
}

// ---------------- launch ----------------
extern "C" void kernel_launch(void* const* d_in, const int* in_sizes, int n_in,
                              void* d_out, int out_size, void* d_ws, size_t ws_size,
                              hipStream_t stream) {
    const float* cloth  = (const float*)d_in[0];
    const float* person = (const float*)d_in[1];
    const float* w1 = (const float*)d_in[2];  const float* b1 = (const float*)d_in[3];
    const float* g1 = (const float*)d_in[4];  const float* be1 = (const float*)d_in[5];
    const float* m1 = (const float*)d_in[6];  const float* v1 = (const float*)d_in[7];
    const float* w2 = (const float*)d_in[8];  const float* b2 = (const float*)d_in[9];
    const float* g2 = (const float*)d_in[10]; const float* be2 = (const float*)d_in[11];
    const float* m2 = (const float*)d_in[12]; const float* v2 = (const float*)d_in[13];
    const float* w3 = (const float*)d_in[14]; const float* b3 = (const float*)d_in[15];
    const float* g3 = (const float*)d_in[16]; const float* be3 = (const float*)d_in[17];
    const float* m3 = (const float*)d_in[18]; const float* v3 = (const float*)d_in[19];
    const float* fw1 = (const float*)d_in[20]; const float* fb1 = (const float*)d_in[21];
    const float* fw2 = (const float*)d_in[22]; const float* fb2 = (const float*)d_in[23];
    const float* fw3 = (const float*)d_in[24]; const float* fb3 = (const float*)d_in[25];

    char* ws = (char*)d_ws;
    auto U = [&](size_t off) { return (unsigned short*)(ws + off); };
    // ---- layout (bytes), ws_size = 256 MiB ----
    unsigned short* nhwc = U(0);            // 16 x 2,097,152  = 33,554,432
    unsigned short* t1   = U(33554432);     // 16 x 8,388,608  = 134,217,728
    unsigned short* cf   = U(33554432);     // alias t1 (dead after conv2): 16 x 2,097,152
    unsigned short* t2   = U(167772160);    // 16 x 4,194,304  = 67,108,864
    unsigned short* corr = U(234881024);    // 8 x 786,432   = 6,291,456
    unsigned short* f1b  = U(241172480);    // 8 x 1,048,576 = 8,388,608
    unsigned short* f2b  = U(249561088);    // 8 x 524,288   = 4,194,304
    unsigned short* w1mk  = U(253755392);   //  28,672 (64x224)
    unsigned short* w2mk  = U(253784064);   // 147,456 (128x576)
    unsigned short* w3mk  = U(253931520);   // 589,824 (256x1152)
    unsigned short* fw1mk = U(254521344);   // 221,184 (128x864)
    unsigned short* fw2mk = U(254742528);   // 147,456 (64x1152)
    unsigned short* fw3mk = U(254889984);   //  73,728 (64x576)
    float* aff = (float*)(ws + 254963712);
    float *s1 = aff,         *sh1 = aff + 64,   *s2 = aff + 128,  *sh2 = aff + 256;
    float *s3 = aff + 384,   *sh3 = aff + 640,  *sf1 = aff + 896, *shf1 = aff + 1024;
    float *sf2 = aff + 1152, *shf2 = aff + 1216, *sf3 = aff + 1280, *shf3 = aff + 1288;

    prep_affine<<<1, 64, 0, stream>>>(b1, g1, be1, m1, v1, s1, sh1, 64, 1);
    prep_affine<<<1, 128, 0, stream>>>(b2, g2, be2, m2, v2, s2, sh2, 128, 1);
    prep_affine<<<1, 256, 0, stream>>>(b3, g3, be3, m3, v3, s3, sh3, 256, 1);
    prep_affine<<<1, 128, 0, stream>>>(fb1, nullptr, nullptr, nullptr, nullptr, sf1, shf1, 128, 0);
    prep_affine<<<1, 64, 0, stream>>>(fb2, nullptr, nullptr, nullptr, nullptr, sf2, shf2, 64, 0);
    prep_affine<<<1, 2, 0, stream>>>(fb3, nullptr, nullptr, nullptr, nullptr, sf3, shf3, 2, 0);

    conv_weights1<<<56, 256, 0, stream>>>(w1, w1mk);
    conv_weights<64, 64><<<288, 256, 0, stream>>>(w2, w2mk, 128, 128, 576);
    conv_weights<128, 128><<<1152, 256, 0, stream>>>(w3, w3mk, 256, 256, 1152);
    conv_weights<81, 96><<<432, 256, 0, stream>>>(fw1, fw1mk, 128, 128, 864);
    conv_weights<128, 128><<<288, 256, 0, stream>>>(fw2, fw2mk, 64, 64, 1152);
    conv_weights<64, 64><<<144, 256, 0, stream>>>(fw3, fw3mk, 2, 64, 576);

    // input -> NHWC4 bf16, all 16 images
    to_nhwc4<<<dim3(1024, 1, 16), 256, 0, stream>>>(cloth, person, nhwc);

    // conv1: 7x7 s2 p3, NHWC4 [512,512,4] -> t1 NHWC [256,256,64]
    gemm_conv<4, 1, 2, true, false, 1><<<dim3(256, 1, 16), 256, 0, stream>>>(
        nhwc, w1mk, s1, sh1, t1, 64, 512, 512, 8, 2, 1048576, 4194304);
    // conv2: 3x3 s2 p1, t1 -> t2 NHWC [128,128,128]
    gemm_conv<2, 2, 1, true, false, 2><<<dim3(128, 1, 16), 256, 0, stream>>>(
        t1, w2mk, s2, sh2, t2, 128, 256, 256, 7, 2, 4194304, 2097152);
    // conv3: 3x3 s2 p1, t2 -> cf/pf NHWC [64,64,256]
    gemm_conv<2, 2, 1, true, false, 4><<<dim3(32, 2, 16), 256, 0, stream>>>(
        t2, w3mk, s3, sh3, cf, 256, 128, 128, 6, 2, 2097152, 1048576);

    // correlation (banded MFMA) -> padded [4096][96]
    corr_mfma<<<dim3(64, 8), 256, 0, stream>>>(cf, cf + (size_t)8 * 1048576, corr);

    // fconv1: 3x3 p1, corr NHWC96 -> f1 NHWC [64,64,128]
    gemm_conv<2, 2, 1, true, false, 3><<<dim3(32, 1, 8), 256, 0, stream>>>(
        corr, fw1mk, sf1, shf1, f1b, 128, 64, 64, 6, 1, 393216, 524288);
    // fconv2: 3x3 p1, f1 -> f2 NHWC [64,64,64]
    gemm_conv<2, 1, 1, true, false, 4><<<dim3(32, 1, 8), 128, 0, stream>>>(
        f1b, fw2mk, sf2, shf2, f2b, 64, 64, 64, 6, 1, 524288, 262144);
    // fconv3: 3x3 p1, f2 -> d_out NCHW fp32 [8][2][64][64]
    gemm_conv<2, 1, 1, false, true, 2><<<dim3(32, 1, 8), 128, 0, stream>>>(
        f2b, fw3mk, sf3, shf3, (float*)d_out, 2, 64, 64, 6, 1, 262144, 8192);
}

// Round 8
// 365.664 us; speedup vs baseline: 81.2460x; 1.0236x over previous
//
#include <hip/hip_runtime.h>

typedef __bf16 bf16x8_t __attribute__((ext_vector_type(8)));
typedef float f32x4 __attribute__((ext_vector_type(4)));
typedef unsigned short u16x8 __attribute__((ext_vector_type(8)));
typedef unsigned short u16x4 __attribute__((ext_vector_type(4)));

#define EPS 1e-5f

__device__ __forceinline__ unsigned short f2bf(float f) {
    unsigned u = __builtin_bit_cast(unsigned, f);
    u += 0x7fff + ((u >> 16) & 1);          // RTNE
    return (unsigned short)(u >> 16);
}

// ---------------- BN fold ----------------
__global__ void prep_affine(const float* __restrict__ cb, const float* __restrict__ g,
                            const float* __restrict__ be, const float* __restrict__ m,
                            const float* __restrict__ v, float* __restrict__ scale,
                            float* __restrict__ shift, int C, int has_bn) {
    int c = blockIdx.x * blockDim.x + threadIdx.x;
    if (c >= C) return;
    if (has_bn) {
        float s = g[c] * rsqrtf(v[c] + EPS);
        scale[c] = s;
        shift[c] = (cb[c] - m[c]) * s + be[c];
    } else {
        scale[c] = 1.0f;
        shift[c] = cb[c];
    }
}

// ------- 3x3 weights OIHW fp32 -> [Sp][Kp] bf16, k = tap*CINP + ic -------
template <int CIN, int CINP>
__global__ void conv_weights(const float* __restrict__ w, unsigned short* __restrict__ dst,
                             int Cout, int Sp, int Kp) {
    int idx = blockIdx.x * 256 + threadIdx.x;
    if (idx >= Sp * Kp) return;
    int m = idx / Kp, k = idx - m * Kp;
    int tap = k / CINP, ic = k - tap * CINP;
    unsigned short v = 0;
    if (m < Cout && tap < 9 && ic < CIN) {
        int kh = tap / 3, kw = tap - kh * 3;
        v = f2bf(w[((m * CIN + ic) * 3 + kh) * 3 + kw]);
    }
    dst[idx] = v;
}

// ------- conv1 weights [64,3,7,7] -> [64][256] bf16, k = kh*32 + kw*4 + ic (kh<8, pad) -------
__global__ void conv_weights1(const float* __restrict__ w, unsigned short* __restrict__ dst) {
    int idx = blockIdx.x * 256 + threadIdx.x;
    if (idx >= 64 * 256) return;
    int m = idx >> 8, k = idx & 255;
    int kh = k >> 5, r = k & 31, kw = r >> 2, ic = r & 3;
    unsigned short v = 0;
    if (kh < 7 && kw < 7 && ic < 3) v = f2bf(w[((m * 3 + ic) * 7 + kh) * 7 + kw]);
    dst[idx] = v;
}

// ------- input NCHW fp32 [3][512][512] -> NHWC4 bf16 [512][512][4], z = image -------
__global__ void to_nhwc4(const float* __restrict__ cloth, const float* __restrict__ person,
                         unsigned short* __restrict__ dst) {
    int z = blockIdx.z;
    const float* src = (z < 8) ? cloth + (size_t)z * 786432
                               : person + (size_t)(z - 8) * 786432;
    int p = blockIdx.x * 256 + threadIdx.x;  // pixel 0..262143
    u16x4 o;
    o[0] = f2bf(src[p]);
    o[1] = f2bf(src[262144 + p]);
    o[2] = f2bf(src[524288 + p]);
    o[3] = 0;
    *(u16x4*)&dst[(size_t)z * 1048576 + (size_t)p * 4] = o;
}

// ------- MFMA GEMM with implicit im2col, BK=64, XOR-swizzled LDS -------
// MODE 1: 3x3 pad-1 conv, X = NHWC bf16, CIN in {64,128}, K layout tap*CIN+ic, K = NKT*64.
// MODE 2: conv1 7x7 s2 p3, X = NHWC4 bf16 [512][512][4], K layout kh*32+kw*4+ic, K=256 (kh 0..7, kh7 zero-wt).
// LDS rows = 64 bf16 (128 B, 8 slots of 16 B); slot ^= (row&7) both sides -> conflict-free reads.
// Wave tile 64x64; block = WR x WS waves; grid (R/BR, ceil(Cout/BS), nimg).
template <int WR, int WS, int MODE, bool RELU, bool OUT_NCHW, int CIN, int NKT>
__global__ __launch_bounds__(WR * WS * 64)
void gemm_conv(const unsigned short* __restrict__ X, const unsigned short* __restrict__ Wmk,
               const float* __restrict__ scale, const float* __restrict__ shift,
               void* __restrict__ Yv, int Cout,
               int Hin, int Win, int WoutShift, int stride,
               int xImgStride, int yImgStride) {
    constexpr int BR = WR * 64, BS = WS * 64, NT = WR * WS * 64;
    constexpr int SXC = BR * 8 / NT, SWC = BS * 8 / NT;   // 16B chunks per thread
    constexpr int KP = (MODE == 1) ? NKT * 64 : 256;
    __shared__ __align__(16) unsigned short Xs[BR * 64];
    __shared__ __align__(16) unsigned short Ws[BS * 64];
    const int tid = threadIdx.x;
    const int lane = tid & 63, wid = tid >> 6;
    const int wr = wid % WR, wsx = wid / WR;
    const int r0 = blockIdx.x * BR, s0 = blockIdx.y * BS;
    const int z = blockIdx.z;
    const int lr = lane & 15, lk = lane >> 4;
    const unsigned short* Ximg = X + (size_t)z * xImgStride;

    // ---- staging geometry (K-invariant) ----
    int xrow[SXC], xch[SXC], xs_off[SXC];
    int xoh[SXC], xow[SXC];          // MODE 1
    int rowb[SXC], colb[SXC];        // MODE 2
    bool cok0[SXC], cok1[SXC];
    #pragma unroll
    for (int i = 0; i < SXC; ++i) {
        int c = i * NT + tid;
        xrow[i] = c >> 3; xch[i] = c & 7;
        xs_off[i] = xrow[i] * 64 + ((xch[i] ^ (xrow[i] & 7)) * 8);
        int r = r0 + xrow[i];
        int oh = r >> WoutShift, ow = r & ((1 << WoutShift) - 1);
        xoh[i] = oh; xow[i] = ow;
        rowb[i] = oh * 2 - 3 + (xch[i] >> 2);
        colb[i] = ow * 2 - 3 + (xch[i] & 3) * 2;
        cok0[i] = (unsigned)colb[i] < 512u;
        cok1[i] = (unsigned)(colb[i] + 1) < 512u;
    }
    int ws_off[SWC];
    const unsigned short* wbase[SWC];
    #pragma unroll
    for (int i = 0; i < SWC; ++i) {
        int c = i * NT + tid;
        int row = c >> 3, ch = c & 7;
        ws_off[i] = row * 64 + ((ch ^ (row & 7)) * 8);
        wbase[i] = Wmk + (size_t)(s0 + row) * KP + ch * 8;
    }
    // fragment row bases
    int arow[4], brow[4];
    #pragma unroll
    for (int mi = 0; mi < 4; ++mi) arow[mi] = (wr * 64 + mi * 16 + lr) * 64;
    #pragma unroll
    for (int si = 0; si < 4; ++si) brow[si] = (wsx * 64 + si * 16 + lr) * 64;

    const f32x4 fz = {0.f, 0.f, 0.f, 0.f};
    f32x4 acc[4][4];
    #pragma unroll
    for (int a = 0; a < 4; ++a)
        #pragma unroll
        for (int b = 0; b < 4; ++b) acc[a][b] = fz;

    #pragma unroll
    for (int kt = 0; kt < NKT; ++kt) {
        u16x8 xv[SXC], wv[SWC];
        if (MODE == 1) {
            const int kk = kt * 64;
            const int tap = kk / CIN;                  // unroll-constant
            const int kh = tap / 3, kwv = tap - (tap / 3) * 3;
            const int icb0 = kk - tap * CIN;
            #pragma unroll
            for (int i = 0; i < SXC; ++i) {
                int ih = xoh[i] * stride - 1 + kh;
                int iw = xow[i] * stride - 1 + kwv;
                u16x8 v = {0, 0, 0, 0, 0, 0, 0, 0};
                if (((unsigned)ih < (unsigned)Hin) & ((unsigned)iw < (unsigned)Win))
                    v = *(const u16x8*)&Ximg[(size_t)(ih * Win + iw) * CIN + icb0 + xch[i] * 8];
                xv[i] = v;
            }
        } else {
            // MODE 2: round kt covers kh rows 2kt (chunks 0-3) and 2kt+1 (chunks 4-7)
            #pragma unroll
            for (int i = 0; i < SXC; ++i) {
                int ih = rowb[i] + 2 * kt;
                bool rok = (unsigned)ih < 512u;
                const unsigned short* rp = Ximg + (size_t)ih * 2048 + colb[i] * 4;
                u16x4 v0 = {0, 0, 0, 0}, v1 = {0, 0, 0, 0};
                if (rok & cok0[i]) v0 = *(const u16x4*)rp;
                if (rok & cok1[i]) v1 = *(const u16x4*)(rp + 4);
                u16x8 full;
                #pragma unroll
                for (int j = 0; j < 4; ++j) { full[j] = v0[j]; full[4 + j] = v1[j]; }
                xv[i] = full;
            }
        }
        #pragma unroll
        for (int i = 0; i < SWC; ++i) wv[i] = *(const u16x8*)(wbase[i] + kt * 64);

        __syncthreads();  // previous round's fragment reads done
        #pragma unroll
        for (int i = 0; i < SXC; ++i) *(u16x8*)&Xs[xs_off[i]] = xv[i];
        #pragma unroll
        for (int i = 0; i < SWC; ++i) *(u16x8*)&Ws[ws_off[i]] = wv[i];
        __syncthreads();

        #pragma unroll
        for (int hf = 0; hf < 2; ++hf) {
            const int cA = (((hf * 4 + lk) ^ (lr & 7)) * 8);
            u16x8 af[4], bfr[4];
            #pragma unroll
            for (int mi = 0; mi < 4; ++mi) af[mi] = *(const u16x8*)&Xs[arow[mi] + cA];
            #pragma unroll
            for (int si = 0; si < 4; ++si) bfr[si] = *(const u16x8*)&Ws[brow[si] + cA];
            #pragma unroll
            for (int mi = 0; mi < 4; ++mi)
                #pragma unroll
                for (int si = 0; si < 4; ++si)
                    acc[mi][si] = __builtin_amdgcn_mfma_f32_16x16x32_bf16(
                        __builtin_bit_cast(bf16x8_t, af[mi]),
                        __builtin_bit_cast(bf16x8_t, bfr[si]), acc[mi][si], 0, 0, 0);
        }
    }

    // epilogue: D row=(lane>>4)*4+reg, col=lane&15 (per 16x16 fragment)
    #pragma unroll
    for (int si = 0; si < 4; ++si) {
        int col = s0 + wsx * 64 + si * 16 + lr;
        bool cok = col < Cout;
        float sc = cok ? scale[col] : 0.f;
        float sh = cok ? shift[col] : 0.f;
        #pragma unroll
        for (int mi = 0; mi < 4; ++mi) {
            int rbase = r0 + wr * 64 + mi * 16 + lk * 4;
            #pragma unroll
            for (int j = 0; j < 4; ++j) {
                float v = acc[mi][si][j] * sc + sh;
                if (RELU) v = fmaxf(v, 0.f);
                if (OUT_NCHW) {
                    if (cok) ((float*)Yv)[(size_t)z * yImgStride + col * 4096 + rbase + j] = v;
                } else if (cok) {
                    ((unsigned short*)Yv)[(size_t)z * yImgStride + (size_t)(rbase + j) * Cout + col] = f2bf(v);
                }
            }
        }
    }
}

// ------- banded-MFMA 81-shift correlation -------
// cf, pf: NHWC bf16 [64][64][256] per image; out: padded [4096][128] bf16 (ch 81..127 never written).
__global__ __launch_bounds__(256)
void corr_mfma(const unsigned short* __restrict__ cf,
               const unsigned short* __restrict__ pf,
               unsigned short* __restrict__ out) {
    const int h = blockIdx.x;        // 0..63
    const int z = blockIdx.y;        // 0..7
    const int tid = threadIdx.x;
    const int lane = tid & 63, t = tid >> 6;
    const int lr = lane & 15, lk = lane >> 4;
    const unsigned short* cfi = cf + (size_t)z * 1048576;
    const unsigned short* pfi = pf + (size_t)z * 1048576;
    unsigned short* outp = out + (size_t)z * 524288;

    u16x8 a[8];
    {
        const unsigned short* ap = cfi + ((size_t)(h * 64 + t * 16 + lr)) * 256 + lk * 8;
        #pragma unroll
        for (int ks = 0; ks < 8; ++ks) a[ks] = *(const u16x8*)(ap + ks * 32);
    }

    const u16x8 zz = {0, 0, 0, 0, 0, 0, 0, 0};
    for (int di = -4; di <= 4; ++di) {
        const int h2 = h + di;
        const bool hok = (unsigned)h2 < 64u;
        #pragma unroll
        for (int ct = 0; ct < 2; ++ct) {
            const int wpg = t * 16 - 8 + ct * 16 + lr;
            u16x8 b[8];
            if (hok && (unsigned)wpg < 64u) {
                const unsigned short* bp = pfi + ((size_t)(h2 * 64 + wpg)) * 256 + lk * 8;
                #pragma unroll
                for (int ks = 0; ks < 8; ++ks) b[ks] = *(const u16x8*)(bp + ks * 32);
            } else {
                #pragma unroll
                for (int ks = 0; ks < 8; ++ks) b[ks] = zz;
            }
            f32x4 acc0 = {0.f, 0.f, 0.f, 0.f}, acc1 = {0.f, 0.f, 0.f, 0.f};
            #pragma unroll
            for (int ks = 0; ks < 8; ks += 2) {
                acc0 = __builtin_amdgcn_mfma_f32_16x16x32_bf16(
                    __builtin_bit_cast(bf16x8_t, a[ks]),
                    __builtin_bit_cast(bf16x8_t, b[ks]), acc0, 0, 0, 0);
                acc1 = __builtin_amdgcn_mfma_f32_16x16x32_bf16(
                    __builtin_bit_cast(bf16x8_t, a[ks + 1]),
                    __builtin_bit_cast(bf16x8_t, b[ks + 1]), acc1, 0, 0, 0);
            }
            const int wl = lk * 4;
            const int wpl = ct * 16 - 8 + lr;
            #pragma unroll
            for (int j = 0; j < 4; ++j) {
                int dj = wpl - (wl + j);
                if (dj >= -4 && dj <= 4) {
                    int s = (di + 4) * 9 + dj + 4;
                    outp[(size_t)(h * 64 + t * 16 + wl + j) * 128 + s] =
                        f2bf(acc0[j] + acc1[j]);
                }
            }
        }
    }
}

// ---------------- launch ----------------
extern "C" void kernel_launch(void* const* d_in, const int* in_sizes, int n_in,
                              void* d_out, int out_size, void* d_ws, size_t ws_size,
                              hipStream_t stream) {
    const float* cloth  = (const float*)d_in[0];
    const float* person = (const float*)d_in[1];
    const float* w1 = (const float*)d_in[2];  const float* b1 = (const float*)d_in[3];
    const float* g1 = (const float*)d_in[4];  const float* be1 = (const float*)d_in[5];
    const float* m1 = (const float*)d_in[6];  const float* v1 = (const float*)d_in[7];
    const float* w2 = (const float*)d_in[8];  const float* b2 = (const float*)d_in[9];
    const float* g2 = (const float*)d_in[10]; const float* be2 = (const float*)d_in[11];
    const float* m2 = (const float*)d_in[12]; const float* v2 = (const float*)d_in[13];
    const float* w3 = (const float*)d_in[14]; const float* b3 = (const float*)d_in[15];
    const float* g3 = (const float*)d_in[16]; const float* be3 = (const float*)d_in[17];
    const float* m3 = (const float*)d_in[18]; const float* v3 = (const float*)d_in[19];
    const float* fw1 = (const float*)d_in[20]; const float* fb1 = (const float*)d_in[21];
    const float* fw2 = (const float*)d_in[22]; const float* fb2 = (const float*)d_in[23];
    const float* fw3 = (const float*)d_in[24]; const float* fb3 = (const float*)d_in[25];

    char* ws = (char*)d_ws;
    auto U = [&](size_t off) { return (unsigned short*)(ws + off); };
    // ---- layout (bytes), ws_size = 256 MiB ----
    unsigned short* nhwc = U(0);            // 16 x 2,097,152  = 33,554,432
    unsigned short* t1   = U(33554432);     // 16 x 8,388,608  = 134,217,728
    unsigned short* cf   = U(33554432);     // alias t1 (dead after conv2): 16 x 2,097,152
    unsigned short* t2   = U(167772160);    // 16 x 4,194,304  = 67,108,864
    unsigned short* corr = U(234881024);    // 8 x 1,048,576 = 8,388,608  ([4096][128] padded)
    unsigned short* f1b  = U(243269632);    // 8 x 1,048,576 = 8,388,608
    unsigned short* f2b  = U(251658240);    // 8 x 524,288   = 4,194,304
    unsigned short* w1mk  = U(255852544);   //  32,768 (64x256)
    unsigned short* w2mk  = U(255885312);   // 147,456 (128x576)
    unsigned short* w3mk  = U(256032768);   // 589,824 (256x1152)
    unsigned short* fw1mk = U(256622592);   // 294,912 (128x1152)
    unsigned short* fw2mk = U(256917504);   // 147,456 (64x1152)
    unsigned short* fw3mk = U(257064960);   //  73,728 (64x576)
    float* aff = (float*)(ws + 257138688);
    float *s1 = aff,         *sh1 = aff + 64,   *s2 = aff + 128,  *sh2 = aff + 256;
    float *s3 = aff + 384,   *sh3 = aff + 640,  *sf1 = aff + 896, *shf1 = aff + 1024;
    float *sf2 = aff + 1152, *shf2 = aff + 1216, *sf3 = aff + 1280, *shf3 = aff + 1288;

    prep_affine<<<1, 64, 0, stream>>>(b1, g1, be1, m1, v1, s1, sh1, 64, 1);
    prep_affine<<<1, 128, 0, stream>>>(b2, g2, be2, m2, v2, s2, sh2, 128, 1);
    prep_affine<<<1, 256, 0, stream>>>(b3, g3, be3, m3, v3, s3, sh3, 256, 1);
    prep_affine<<<1, 128, 0, stream>>>(fb1, nullptr, nullptr, nullptr, nullptr, sf1, shf1, 128, 0);
    prep_affine<<<1, 64, 0, stream>>>(fb2, nullptr, nullptr, nullptr, nullptr, sf2, shf2, 64, 0);
    prep_affine<<<1, 2, 0, stream>>>(fb3, nullptr, nullptr, nullptr, nullptr, sf3, shf3, 2, 0);

    conv_weights1<<<64, 256, 0, stream>>>(w1, w1mk);
    conv_weights<64, 64><<<288, 256, 0, stream>>>(w2, w2mk, 128, 128, 576);
    conv_weights<128, 128><<<1152, 256, 0, stream>>>(w3, w3mk, 256, 256, 1152);
    conv_weights<81, 128><<<576, 256, 0, stream>>>(fw1, fw1mk, 128, 128, 1152);
    conv_weights<128, 128><<<288, 256, 0, stream>>>(fw2, fw2mk, 64, 64, 1152);
    conv_weights<64, 64><<<144, 256, 0, stream>>>(fw3, fw3mk, 2, 64, 576);

    // input -> NHWC4 bf16, all 16 images
    to_nhwc4<<<dim3(1024, 1, 16), 256, 0, stream>>>(cloth, person, nhwc);

    // conv1: 7x7 s2 p3, NHWC4 [512,512,4] -> t1 NHWC [256,256,64]   (R=65536/BR=256)
    gemm_conv<4, 1, 2, true, false, 4, 4><<<dim3(256, 1, 16), 256, 0, stream>>>(
        nhwc, w1mk, s1, sh1, t1, 64, 512, 512, 8, 2, 1048576, 4194304);
    // conv2: 3x3 s2 p1, t1 -> t2 NHWC [128,128,128]   (R=16384/BR=128)
    gemm_conv<2, 2, 1, true, false, 64, 9><<<dim3(128, 1, 16), 256, 0, stream>>>(
        t1, w2mk, s2, sh2, t2, 128, 256, 256, 7, 2, 4194304, 2097152);
    // conv3: 3x3 s2 p1, t2 -> cf/pf NHWC [64,64,256]   (R=4096/BR=128)
    gemm_conv<2, 2, 1, true, false, 128, 18><<<dim3(32, 2, 16), 256, 0, stream>>>(
        t2, w3mk, s3, sh3, cf, 256, 128, 128, 6, 2, 2097152, 1048576);

    // correlation (banded MFMA) -> padded [4096][128]
    corr_mfma<<<dim3(64, 8), 256, 0, stream>>>(cf, cf + (size_t)8 * 1048576, corr);

    // fconv1: 3x3 p1, corr NHWC128 -> f1 NHWC [64,64,128]
    gemm_conv<2, 2, 1, true, false, 128, 18><<<dim3(32, 1, 8), 256, 0, stream>>>(
        corr, fw1mk, sf1, shf1, f1b, 128, 64, 64, 6, 1, 524288, 524288);
    // fconv2: 3x3 p1, f1 -> f2 NHWC [64,64,64]
    gemm_conv<2, 1, 1, true, false, 128, 18><<<dim3(32, 1, 8), 128, 0, stream>>>(
        f1b, fw2mk, sf2, shf2, f2b, 64, 64, 64, 6, 1, 524288, 262144);
    // fconv3: 3x3 p1, f2 -> d_out NCHW fp32 [8][2][64][64]
    gemm_conv<2, 1, 1, false, true, 64, 9><<<dim3(32, 1, 8), 128, 0, stream>>>(
        f2b, fw3mk, sf3, shf3, (float*)d_out, 2, 64, 64, 6, 1, 262144, 8192);
}

// Round 10
// 357.339 us; speedup vs baseline: 83.1387x; 1.0233x over previous
//
#include <hip/hip_runtime.h>

typedef __bf16 bf16x8_t __attribute__((ext_vector_type(8)));
typedef float f32x4 __attribute__((ext_vector_type(4)));
typedef unsigned short u16x8 __attribute__((ext_vector_type(8)));
typedef unsigned short u16x4 __attribute__((ext_vector_type(4)));

#define EPS 1e-5f

__device__ __forceinline__ unsigned short f2bf(float f) {
    unsigned u = __builtin_bit_cast(unsigned, f);
    u += 0x7fff + ((u >> 16) & 1);          // RTNE
    return (unsigned short)(u >> 16);
}

// direct global->LDS 16B (dwordx4). LDS dest: wave-uniform base + lane*16.
__device__ __forceinline__ void gload16(const unsigned short* g, unsigned short* l) {
    __builtin_amdgcn_global_load_lds(
        (const __attribute__((address_space(1))) unsigned int*)g,
        (__attribute__((address_space(3))) unsigned int*)l,
        16, 0, 0);
}

// ---------------- BN fold ----------------
__global__ void prep_affine(const float* __restrict__ cb, const float* __restrict__ g,
                            const float* __restrict__ be, const float* __restrict__ m,
                            const float* __restrict__ v, float* __restrict__ scale,
                            float* __restrict__ shift, int C, int has_bn) {
    int c = blockIdx.x * blockDim.x + threadIdx.x;
    if (c >= C) return;
    if (has_bn) {
        float s = g[c] * rsqrtf(v[c] + EPS);
        scale[c] = s;
        shift[c] = (cb[c] - m[c]) * s + be[c];
    } else {
        scale[c] = 1.0f;
        shift[c] = cb[c];
    }
}

// ------- 3x3 weights OIHW fp32 -> [Sp][Kp] bf16, k = tap*CINP + ic -------
template <int CIN, int CINP>
__global__ void conv_weights(const float* __restrict__ w, unsigned short* __restrict__ dst,
                             int Cout, int Sp, int Kp) {
    int idx = blockIdx.x * 256 + threadIdx.x;
    if (idx >= Sp * Kp) return;
    int m = idx / Kp, k = idx - m * Kp;
    int tap = k / CINP, ic = k - tap * CINP;
    unsigned short v = 0;
    if (m < Cout && tap < 9 && ic < CIN) {
        int kh = tap / 3, kw = tap - kh * 3;
        v = f2bf(w[((m * CIN + ic) * 3 + kh) * 3 + kw]);
    }
    dst[idx] = v;
}

// ------- conv1 weights [64,3,7,7] -> [64][256] bf16, k = kh*32 + kw*4 + ic (kh<8) -------
__global__ void conv_weights1(const float* __restrict__ w, unsigned short* __restrict__ dst) {
    int idx = blockIdx.x * 256 + threadIdx.x;
    if (idx >= 64 * 256) return;
    int m = idx >> 8, k = idx & 255;
    int kh = k >> 5, r = k & 31, kw = r >> 2, ic = r & 3;
    unsigned short v = 0;
    if (kh < 7 && kw < 7 && ic < 3) v = f2bf(w[((m * 3 + ic) * 7 + kh) * 7 + kw]);
    dst[idx] = v;
}

// ------- input NCHW fp32 [3][512][512] -> padded NHWC4 bf16 [518][518][4] -------
__global__ void to_nhwc4(const float* __restrict__ cloth, const float* __restrict__ person,
                         unsigned short* __restrict__ dst) {
    int z = blockIdx.z;
    const float* src = (z < 8) ? cloth + (size_t)z * 786432
                               : person + (size_t)(z - 8) * 786432;
    int p = blockIdx.x * 256 + threadIdx.x;  // pixel 0..262143
    int row = p >> 9, col = p & 511;
    u16x4 o;
    o[0] = f2bf(src[p]);
    o[1] = f2bf(src[262144 + p]);
    o[2] = f2bf(src[524288 + p]);
    o[3] = 0;
    *(u16x4*)&dst[(size_t)z * 1073296 + ((size_t)(row + 3) * 518 + col + 3) * 4] = o;
}

// ------- zero the 1-ring border of padded NHWC [Hp][Wp][C8*8] for nimg images -------
__global__ void border_zero(unsigned short* __restrict__ buf, int Hp, int Wp, int C8,
                            int imgStrideElems, int nimg) {
    int idx = blockIdx.x * 256 + threadIdx.x;
    int nb = 2 * Wp + 2 * (Hp - 2);
    int per = nb * C8;
    if (idx >= per * nimg) return;
    int z = idx / per, q = idx - z * per;
    int p = q / C8, cc = q - p * C8;
    int row, col;
    if (p < Wp) { row = 0; col = p; }
    else if (p < 2 * Wp) { row = Hp - 1; col = p - Wp; }
    else { int e = p - 2 * Wp; row = 1 + (e >> 1); col = (e & 1) ? Wp - 1 : 0; }
    const u16x8 zv = {0, 0, 0, 0, 0, 0, 0, 0};
    *(u16x8*)&buf[(size_t)z * imgStrideElems + ((size_t)row * Wp + col) * (C8 * 8) + cc * 8] = zv;
}

// ------- MFMA GEMM, implicit im2col from PADDED inputs, global_load_lds staging -------
// MODE 1: 3x3 conv pad1, X = padded NHWC [HIN+2][HIN+2][CIN], K layout tap*CIN+ic.
// MODE 2: conv1 7x7 s2 p3, X = padded NHWC4 [518][518][4], K layout kh*32+kw*4+ic (kh<8).
// LDS [row][64] bf16 linear; XOR swizzle applied on the global SOURCE (slot s of row r
// holds K-chunk s^(r&7)); fragment reads use the same involution -> conflict-free.
// Wave tile 64x64; block = WR x WS waves; grid (R/BR, ceil(Cout/BS), nimg).
template <int WR, int WS, int MODE, bool RELU, bool OUT_NCHW, int CIN, int NKT,
          int HIN, int WOS, int STRIDE, int OPAD>
__global__ __launch_bounds__(WR * WS * 64)
void gemm_conv(const unsigned short* __restrict__ X, const unsigned short* __restrict__ Wmk,
               const float* __restrict__ scale, const float* __restrict__ shift,
               void* __restrict__ Yv, int Cout, int xImgStride, int yImgStride) {
    constexpr int BR = WR * 64, BS = WS * 64, NT = WR * WS * 64;
    constexpr int SXC = BR * 8 / NT, SWC = BS * 8 / NT;   // 16B chunks per thread
    constexpr int KP = (MODE == 1) ? NKT * 64 : 256;
    constexpr int WP = HIN + ((MODE == 2) ? 6 : 2);       // padded width
    constexpr int WOUT = 1 << WOS;
    constexpr int WOP = WOUT + 2 * OPAD;
    __shared__ __align__(16) unsigned short Xs[BR * 64];
    __shared__ __align__(16) unsigned short Ws[BS * 64];
    const int tid = threadIdx.x;
    const int lane = tid & 63, wid = tid >> 6;
    const int wr = wid % WR, wsx = wid / WR;
    const int r0 = blockIdx.x * BR, s0 = blockIdx.y * BS;
    const int z = blockIdx.z;
    const int lr = lane & 15, lk = lane >> 4;
    const unsigned short* Ximg = X + (size_t)z * xImgStride;

    // per-chunk global source base (kt=0), XOR-swizzled chunk select
    const unsigned short* xsrc[SXC];
    #pragma unroll
    for (int i = 0; i < SXC; ++i) {
        int c = i * NT + tid;
        int row = c >> 3, chs = (c & 7) ^ (row & 7);
        int r = r0 + row;
        int oh = r >> WOS, ow = r & (WOUT - 1);
        if (MODE == 1)
            xsrc[i] = Ximg + ((size_t)(oh * STRIDE) * WP + (size_t)(ow * STRIDE)) * CIN + chs * 8;
        else
            xsrc[i] = Ximg + ((size_t)(2 * oh + (chs >> 2)) * WP + 2 * ow + (chs & 3) * 2) * 4;
    }
    const unsigned short* wsrc[SWC];
    #pragma unroll
    for (int i = 0; i < SWC; ++i) {
        int c = i * NT + tid;
        int row = c >> 3, chs = (c & 7) ^ (row & 7);
        wsrc[i] = Wmk + (size_t)(s0 + row) * KP + chs * 8;
    }
    // wave-uniform LDS destinations (linear)
    unsigned short* xdst[SXC];
    #pragma unroll
    for (int i = 0; i < SXC; ++i) xdst[i] = &Xs[(i * NT + wid * 64) * 8];
    unsigned short* wdst[SWC];
    #pragma unroll
    for (int i = 0; i < SWC; ++i) wdst[i] = &Ws[(i * NT + wid * 64) * 8];

    // fragment row bases
    int arow[4], brow[4];
    #pragma unroll
    for (int mi = 0; mi < 4; ++mi) arow[mi] = (wr * 64 + mi * 16 + lr) * 64;
    #pragma unroll
    for (int si = 0; si < 4; ++si) brow[si] = (wsx * 64 + si * 16 + lr) * 64;

    const f32x4 fz = {0.f, 0.f, 0.f, 0.f};
    f32x4 acc[4][4];
    #pragma unroll
    for (int a = 0; a < 4; ++a)
        #pragma unroll
        for (int b = 0; b < 4; ++b) acc[a][b] = fz;

    #pragma unroll
    for (int kt = 0; kt < NKT; ++kt) {
        size_t koff;
        if (MODE == 1) {
            const int tap = (kt * 64) / CIN;
            const int kh = tap / 3, kw = tap - (tap / 3) * 3;
            const int icb0 = (kt * 64) % CIN;
            koff = ((size_t)kh * WP + kw) * CIN + icb0;
        } else {
            koff = (size_t)kt * 2 * WP * 4;
        }
        #pragma unroll
        for (int i = 0; i < SXC; ++i) gload16(xsrc[i] + koff, xdst[i]);
        #pragma unroll
        for (int i = 0; i < SWC; ++i) gload16(wsrc[i] + kt * 64, wdst[i]);
        __syncthreads();   // drains vmcnt: staged data visible

        #pragma unroll
        for (int hf = 0; hf < 2; ++hf) {
            const int cA = (((hf * 4 + lk) ^ (lr & 7)) * 8);
            u16x8 af[4], bfr[4];
            #pragma unroll
            for (int mi = 0; mi < 4; ++mi) af[mi] = *(const u16x8*)&Xs[arow[mi] + cA];
            #pragma unroll
            for (int si = 0; si < 4; ++si) bfr[si] = *(const u16x8*)&Ws[brow[si] + cA];
            #pragma unroll
            for (int mi = 0; mi < 4; ++mi)
                #pragma unroll
                for (int si = 0; si < 4; ++si)
                    acc[mi][si] = __builtin_amdgcn_mfma_f32_16x16x32_bf16(
                        __builtin_bit_cast(bf16x8_t, af[mi]),
                        __builtin_bit_cast(bf16x8_t, bfr[si]), acc[mi][si], 0, 0, 0);
        }
        __syncthreads();   // all reads done before next round's staging
    }

    // epilogue: D row=(lane>>4)*4+reg, col=lane&15 (per 16x16 fragment)
    #pragma unroll
    for (int si = 0; si < 4; ++si) {
        int col = s0 + wsx * 64 + si * 16 + lr;
        bool cok = col < Cout;
        float sc = cok ? scale[col] : 0.f;
        float sh = cok ? shift[col] : 0.f;
        #pragma unroll
        for (int mi = 0; mi < 4; ++mi) {
            int rbase = r0 + wr * 64 + mi * 16 + lk * 4;
            int oh = rbase >> WOS, ow = rbase & (WOUT - 1);
            #pragma unroll
            for (int j = 0; j < 4; ++j) {
                float v = acc[mi][si][j] * sc + sh;
                if (RELU) v = fmaxf(v, 0.f);
                if (OUT_NCHW) {
                    if (cok) ((float*)Yv)[(size_t)z * yImgStride + col * 4096 + rbase + j] = v;
                } else if (cok) {
                    size_t off = ((size_t)(oh + OPAD) * WOP + ow + OPAD + j) * Cout + col;
                    ((unsigned short*)Yv)[(size_t)z * yImgStride + off] = f2bf(v);
                }
            }
        }
    }
}

// ------- banded-MFMA 81-shift correlation -------
// cf, pf: NHWC bf16 [64][64][256]; out: padded [66][66][128] bf16 (ch>=81 stay 0).
__global__ __launch_bounds__(256)
void corr_mfma(const unsigned short* __restrict__ cf,
               const unsigned short* __restrict__ pf,
               unsigned short* __restrict__ out) {
    const int h = blockIdx.x;        // 0..63
    const int z = blockIdx.y;        // 0..7
    const int tid = threadIdx.x;
    const int lane = tid & 63, t = tid >> 6;
    const int lr = lane & 15, lk = lane >> 4;
    const unsigned short* cfi = cf + (size_t)z * 1048576;
    const unsigned short* pfi = pf + (size_t)z * 1048576;
    unsigned short* outp = out + (size_t)z * 557568;

    u16x8 a[8];
    {
        const unsigned short* ap = cfi + ((size_t)(h * 64 + t * 16 + lr)) * 256 + lk * 8;
        #pragma unroll
        for (int ks = 0; ks < 8; ++ks) a[ks] = *(const u16x8*)(ap + ks * 32);
    }

    const u16x8 zz = {0, 0, 0, 0, 0, 0, 0, 0};
    for (int di = -4; di <= 4; ++di) {
        const int h2 = h + di;
        const bool hok = (unsigned)h2 < 64u;
        #pragma unroll
        for (int ct = 0; ct < 2; ++ct) {
            const int wpg = t * 16 - 8 + ct * 16 + lr;
            u16x8 b[8];
            if (hok && (unsigned)wpg < 64u) {
                const unsigned short* bp = pfi + ((size_t)(h2 * 64 + wpg)) * 256 + lk * 8;
                #pragma unroll
                for (int ks = 0; ks < 8; ++ks) b[ks] = *(const u16x8*)(bp + ks * 32);
            } else {
                #pragma unroll
                for (int ks = 0; ks < 8; ++ks) b[ks] = zz;
            }
            f32x4 acc0 = {0.f, 0.f, 0.f, 0.f}, acc1 = {0.f, 0.f, 0.f, 0.f};
            #pragma unroll
            for (int ks = 0; ks < 8; ks += 2) {
                acc0 = __builtin_amdgcn_mfma_f32_16x16x32_bf16(
                    __builtin_bit_cast(bf16x8_t, a[ks]),
                    __builtin_bit_cast(bf16x8_t, b[ks]), acc0, 0, 0, 0);
                acc1 = __builtin_amdgcn_mfma_f32_16x16x32_bf16(
                    __builtin_bit_cast(bf16x8_t, a[ks + 1]),
                    __builtin_bit_cast(bf16x8_t, b[ks + 1]), acc1, 0, 0, 0);
            }
            const int wl = lk * 4;
            const int wpl = ct * 16 - 8 + lr;
            #pragma unroll
            for (int j = 0; j < 4; ++j) {
                int dj = wpl - (wl + j);
                if (dj >= -4 && dj <= 4) {
                    int s = (di + 4) * 9 + dj + 4;
                    int w = t * 16 + wl + j;
                    outp[((size_t)(h + 1) * 66 + w + 1) * 128 + s] =
                        f2bf(acc0[j] + acc1[j]);
                }
            }
        }
    }
}

// ---------------- launch ----------------
extern "C" void kernel_launch(void* const* d_in, const int* in_sizes, int n_in,
                              void* d_out, int out_size, void* d_ws, size_t ws_size,
                              hipStream_t stream) {
    const float* cloth  = (const float*)d_in[0];
    const float* person = (const float*)d_in[1];
    const float* w1 = (const float*)d_in[2];  const float* b1 = (const float*)d_in[3];
    const float* g1 = (const float*)d_in[4];  const float* be1 = (const float*)d_in[5];
    const float* m1 = (const float*)d_in[6];  const float* v1 = (const float*)d_in[7];
    const float* w2 = (const float*)d_in[8];  const float* b2 = (const float*)d_in[9];
    const float* g2 = (const float*)d_in[10]; const float* be2 = (const float*)d_in[11];
    const float* m2 = (const float*)d_in[12]; const float* v2 = (const float*)d_in[13];
    const float* w3 = (const float*)d_in[14]; const float* b3 = (const float*)d_in[15];
    const float* g3 = (const float*)d_in[16]; const float* be3 = (const float*)d_in[17];
    const float* m3 = (const float*)d_in[18]; const float* v3 = (const float*)d_in[19];
    const float* fw1 = (const float*)d_in[20]; const float* fb1 = (const float*)d_in[21];
    const float* fw2 = (const float*)d_in[22]; const float* fb2 = (const float*)d_in[23];
    const float* fw3 = (const float*)d_in[24]; const float* fb3 = (const float*)d_in[25];

    char* ws = (char*)d_ws;
    auto U = [&](size_t off) { return (unsigned short*)(ws + off); };
    // ---- layout (bytes), ws_size = 256 MiB = 268,435,456 ----
    unsigned short* nhwc = U(0);             // [518][518][4] x16 = 34,345,472
    unsigned short* t1   = U(34345472);      // [258][258][64] x16 = 136,323,072 -> ends 170,668,544
    unsigned short* cf   = U(34345472);      // alias t1 (dead after conv2): [64][64][256] x16
    unsigned short* t2   = U(170668544);     // [130][130][128] x16 = 69,222,400 -> ends 239,890,944
    unsigned short* w1mk  = U(239890944);    //  32,768 (64x256)
    unsigned short* w2mk  = U(239923712);    // 147,456 (128x576)
    unsigned short* w3mk  = U(240071168);    // 589,824 (256x1152)
    unsigned short* fw1mk = U(240660992);    // 294,912 (128x1152)
    unsigned short* fw2mk = U(240955904);    // 147,456 (64x1152)
    unsigned short* fw3mk = U(241103360);    //  73,728 (64x576) -> ends 241,177,088
    float* aff = (float*)(ws + 241177088);   // 8 KB
    // head buffers in DEDICATED tail region (never touched by nhwc/t1/t2 writes)
    unsigned short* corr = U(241185280);     // [66][66][128] x8 = 8,921,088 -> ends 250,106,368
    unsigned short* f1b  = U(250106368);     // [66][66][128] x8 = 8,921,088 -> ends 259,027,456
    unsigned short* f2b  = U(259027456);     // [66][66][64]  x8 = 4,460,544 -> ends 263,488,000
    float *s1 = aff,         *sh1 = aff + 64,   *s2 = aff + 128,  *sh2 = aff + 256;
    float *s3 = aff + 384,   *sh3 = aff + 640,  *sf1 = aff + 896, *shf1 = aff + 1024;
    float *sf2 = aff + 1152, *shf2 = aff + 1216, *sf3 = aff + 1280, *shf3 = aff + 1288;

    prep_affine<<<1, 64, 0, stream>>>(b1, g1, be1, m1, v1, s1, sh1, 64, 1);
    prep_affine<<<1, 128, 0, stream>>>(b2, g2, be2, m2, v2, s2, sh2, 128, 1);
    prep_affine<<<1, 256, 0, stream>>>(b3, g3, be3, m3, v3, s3, sh3, 256, 1);
    prep_affine<<<1, 128, 0, stream>>>(fb1, nullptr, nullptr, nullptr, nullptr, sf1, shf1, 128, 0);
    prep_affine<<<1, 64, 0, stream>>>(fb2, nullptr, nullptr, nullptr, nullptr, sf2, shf2, 64, 0);
    prep_affine<<<1, 2, 0, stream>>>(fb3, nullptr, nullptr, nullptr, nullptr, sf3, shf3, 2, 0);

    conv_weights1<<<64, 256, 0, stream>>>(w1, w1mk);
    conv_weights<64, 64><<<288, 256, 0, stream>>>(w2, w2mk, 128, 128, 576);
    conv_weights<128, 128><<<1152, 256, 0, stream>>>(w3, w3mk, 256, 256, 1152);
    conv_weights<81, 128><<<576, 256, 0, stream>>>(fw1, fw1mk, 128, 128, 1152);
    conv_weights<128, 128><<<288, 256, 0, stream>>>(fw2, fw2mk, 64, 64, 1152);
    conv_weights<64, 64><<<144, 256, 0, stream>>>(fw3, fw3mk, 2, 64, 576);

    // zero padded regions: nhwc (3-ring pad), head-buffer region (1-ring pads + dead chans),
    // t1/t2 rings
    hipMemsetAsync(ws, 0, 34345472, stream);
    hipMemsetAsync(ws + 241185280, 0, 22302720, stream);
    border_zero<<<514, 256, 0, stream>>>(t1, 258, 258, 8, 4260096, 16);
    border_zero<<<517, 256, 0, stream>>>(t2, 130, 130, 16, 2163200, 16);

    // input -> padded NHWC4 bf16, all 16 images
    to_nhwc4<<<dim3(1024, 1, 16), 256, 0, stream>>>(cloth, person, nhwc);

    // conv1: 7x7 s2 p3, nhwc[518,518,4] -> t1 pad[258,258,64]   (R=65536/BR=256)
    gemm_conv<4, 1, 2, true, false, 4, 4, 512, 8, 2, 1><<<dim3(256, 1, 16), 256, 0, stream>>>(
        nhwc, w1mk, s1, sh1, t1, 64, 1073296, 4260096);
    // conv2: 3x3 s2 p1, t1 -> t2 pad[130,130,128]   (R=16384/BR=128)
    gemm_conv<2, 2, 1, true, false, 64, 9, 256, 7, 2, 1><<<dim3(128, 1, 16), 256, 0, stream>>>(
        t1, w2mk, s2, sh2, t2, 128, 4260096, 2163200);
    // conv3: 3x3 s2 p1, t2 -> cf/pf unpadded [64,64,256]   (R=4096/BR=128)
    gemm_conv<2, 2, 1, true, false, 128, 18, 128, 6, 2, 0><<<dim3(32, 2, 16), 256, 0, stream>>>(
        t2, w3mk, s3, sh3, cf, 256, 2163200, 1048576);

    // correlation (banded MFMA) -> corr pad[66,66,128]
    corr_mfma<<<dim3(64, 8), 256, 0, stream>>>(cf, cf + (size_t)8 * 1048576, corr);

    // fconv1: 3x3 p1, corr -> f1b pad[66,66,128]
    gemm_conv<2, 2, 1, true, false, 128, 18, 64, 6, 1, 1><<<dim3(32, 1, 8), 256, 0, stream>>>(
        corr, fw1mk, sf1, shf1, f1b, 128, 557568, 557568);
    // fconv2: 3x3 p1, f1b -> f2b pad[66,66,64]
    gemm_conv<2, 1, 1, true, false, 128, 18, 64, 6, 1, 1><<<dim3(32, 1, 8), 128, 0, stream>>>(
        f1b, fw2mk, sf2, shf2, f2b, 64, 557568, 278784);
    // fconv3: 3x3 p1, f2b -> d_out NCHW fp32 [8][2][64][64]
    gemm_conv<2, 1, 1, false, true, 64, 9, 64, 6, 1, 0><<<dim3(32, 1, 8), 128, 0, stream>>>(
        f2b, fw3mk, sf3, shf3, (float*)d_out, 2, 278784, 8192);
}

// Round 11
// 347.217 us; speedup vs baseline: 85.5623x; 1.0292x over previous
//
#include <hip/hip_runtime.h>

typedef __bf16 bf16x8_t __attribute__((ext_vector_type(8)));
typedef float f32x4 __attribute__((ext_vector_type(4)));
typedef unsigned short u16x8 __attribute__((ext_vector_type(8)));
typedef unsigned short u16x4 __attribute__((ext_vector_type(4)));

#define EPS 1e-5f

__device__ __forceinline__ unsigned short f2bf(float f) {
    unsigned u = __builtin_bit_cast(unsigned, f);
    u += 0x7fff + ((u >> 16) & 1);          // RTNE
    return (unsigned short)(u >> 16);
}

// direct global->LDS 16B (dwordx4). LDS dest: wave-uniform base + lane*16.
__device__ __forceinline__ void gload16(const unsigned short* g, unsigned short* l) {
    __builtin_amdgcn_global_load_lds(
        (const __attribute__((address_space(1))) unsigned int*)g,
        (__attribute__((address_space(3))) unsigned int*)l,
        16, 0, 0);
}

// counted vmcnt wait (compile-time N)
template <int N> __device__ __forceinline__ void s_waitcnt_vm() {
    if constexpr (N == 0)       asm volatile("s_waitcnt vmcnt(0)" ::: "memory");
    else if constexpr (N == 8)  asm volatile("s_waitcnt vmcnt(8)" ::: "memory");
    else if constexpr (N == 10) asm volatile("s_waitcnt vmcnt(10)" ::: "memory");
    else if constexpr (N == 12) asm volatile("s_waitcnt vmcnt(12)" ::: "memory");
    else static_assert(N == 0, "unsupported vmcnt");
}

// ---------------- BN fold ----------------
__global__ void prep_affine(const float* __restrict__ cb, const float* __restrict__ g,
                            const float* __restrict__ be, const float* __restrict__ m,
                            const float* __restrict__ v, float* __restrict__ scale,
                            float* __restrict__ shift, int C, int has_bn) {
    int c = blockIdx.x * blockDim.x + threadIdx.x;
    if (c >= C) return;
    if (has_bn) {
        float s = g[c] * rsqrtf(v[c] + EPS);
        scale[c] = s;
        shift[c] = (cb[c] - m[c]) * s + be[c];
    } else {
        scale[c] = 1.0f;
        shift[c] = cb[c];
    }
}

// ------- 3x3 weights OIHW fp32 -> [Sp][Kp] bf16, k = tap*CINP + ic -------
template <int CIN, int CINP>
__global__ void conv_weights(const float* __restrict__ w, unsigned short* __restrict__ dst,
                             int Cout, int Sp, int Kp) {
    int idx = blockIdx.x * 256 + threadIdx.x;
    if (idx >= Sp * Kp) return;
    int m = idx / Kp, k = idx - m * Kp;
    int tap = k / CINP, ic = k - tap * CINP;
    unsigned short v = 0;
    if (m < Cout && tap < 9 && ic < CIN) {
        int kh = tap / 3, kw = tap - kh * 3;
        v = f2bf(w[((m * CIN + ic) * 3 + kh) * 3 + kw]);
    }
    dst[idx] = v;
}

// ------- conv1 weights [64,3,7,7] -> [64][256] bf16, k = kh*32 + kw*4 + ic (kh<8) -------
__global__ void conv_weights1(const float* __restrict__ w, unsigned short* __restrict__ dst) {
    int idx = blockIdx.x * 256 + threadIdx.x;
    if (idx >= 64 * 256) return;
    int m = idx >> 8, k = idx & 255;
    int kh = k >> 5, r = k & 31, kw = r >> 2, ic = r & 3;
    unsigned short v = 0;
    if (kh < 7 && kw < 7 && ic < 3) v = f2bf(w[((m * 3 + ic) * 7 + kh) * 7 + kw]);
    dst[idx] = v;
}

// ------- input NCHW fp32 [3][512][512] -> padded NHWC4 bf16 [518][518][4] -------
__global__ void to_nhwc4(const float* __restrict__ cloth, const float* __restrict__ person,
                         unsigned short* __restrict__ dst) {
    int z = blockIdx.z;
    const float* src = (z < 8) ? cloth + (size_t)z * 786432
                               : person + (size_t)(z - 8) * 786432;
    int p = blockIdx.x * 256 + threadIdx.x;  // pixel 0..262143
    int row = p >> 9, col = p & 511;
    u16x4 o;
    o[0] = f2bf(src[p]);
    o[1] = f2bf(src[262144 + p]);
    o[2] = f2bf(src[524288 + p]);
    o[3] = 0;
    *(u16x4*)&dst[(size_t)z * 1073296 + ((size_t)(row + 3) * 518 + col + 3) * 4] = o;
}

// ------- zero the 1-ring border of padded NHWC [Hp][Wp][C8*8] for nimg images -------
__global__ void border_zero(unsigned short* __restrict__ buf, int Hp, int Wp, int C8,
                            int imgStrideElems, int nimg) {
    int idx = blockIdx.x * 256 + threadIdx.x;
    int nb = 2 * Wp + 2 * (Hp - 2);
    int per = nb * C8;
    if (idx >= per * nimg) return;
    int z = idx / per, q = idx - z * per;
    int p = q / C8, cc = q - p * C8;
    int row, col;
    if (p < Wp) { row = 0; col = p; }
    else if (p < 2 * Wp) { row = Hp - 1; col = p - Wp; }
    else { int e = p - 2 * Wp; row = 1 + (e >> 1); col = (e & 1) ? Wp - 1 : 0; }
    const u16x8 zv = {0, 0, 0, 0, 0, 0, 0, 0};
    *(u16x8*)&buf[(size_t)z * imgStrideElems + ((size_t)row * Wp + col) * (C8 * 8) + cc * 8] = zv;
}

// ------- MFMA GEMM, implicit im2col, global_load_lds, 2-phase dbuf pipeline -------
// MODE 1: 3x3 conv pad1, X = padded NHWC [HIN+2][HIN+2][CIN], K layout tap*CIN+ic.
// MODE 2: conv1 7x7 s2 p3, X = padded NHWC4 [518][518][4], K layout kh*32+kw*4+ic (kh<8).
// LDS [row][64] bf16 linear; XOR swizzle on the global SOURCE; reads use same involution.
// Pipeline: stage(kt+1 -> buf^1) || wait prev loads (vmcnt(NLOAD)) -> barrier ->
//           compute buf -> barrier. Loads stay in flight across one full MFMA phase.
template <int WR, int WS, int MODE, bool RELU, bool OUT_NCHW, int CIN, int NKT,
          int HIN, int WOS, int STRIDE, int OPAD>
__global__ __launch_bounds__(WR * WS * 64)
void gemm_conv(const unsigned short* __restrict__ X, const unsigned short* __restrict__ Wmk,
               const float* __restrict__ scale, const float* __restrict__ shift,
               void* __restrict__ Yv, int Cout, int xImgStride, int yImgStride) {
    constexpr int BR = WR * 64, BS = WS * 64, NT = WR * WS * 64;
    constexpr int SXC = BR * 8 / NT, SWC = BS * 8 / NT;   // 16B chunks per thread
    constexpr int NLOAD = SXC + SWC;
    constexpr int KP = (MODE == 1) ? NKT * 64 : 256;
    constexpr int WP = HIN + ((MODE == 2) ? 6 : 2);       // padded width
    constexpr int WOUT = 1 << WOS;
    constexpr int WOP = WOUT + 2 * OPAD;
    __shared__ __align__(16) unsigned short Xs[2][BR * 64];
    __shared__ __align__(16) unsigned short Ws[2][BS * 64];
    const int tid = threadIdx.x;
    const int lane = tid & 63, wid = tid >> 6;
    const int wr = wid % WR, wsx = wid / WR;
    const int r0 = blockIdx.x * BR, s0 = blockIdx.y * BS;
    const int z = blockIdx.z;
    const int lr = lane & 15, lk = lane >> 4;
    const unsigned short* Ximg = X + (size_t)z * xImgStride;

    // per-chunk global source base (kt=0), XOR-swizzled chunk select
    const unsigned short* xsrc[SXC];
    #pragma unroll
    for (int i = 0; i < SXC; ++i) {
        int c = i * NT + tid;
        int row = c >> 3, chs = (c & 7) ^ (row & 7);
        int r = r0 + row;
        int oh = r >> WOS, ow = r & (WOUT - 1);
        if (MODE == 1)
            xsrc[i] = Ximg + ((size_t)(oh * STRIDE) * WP + (size_t)(ow * STRIDE)) * CIN + chs * 8;
        else
            xsrc[i] = Ximg + ((size_t)(2 * oh + (chs >> 2)) * WP + 2 * ow + (chs & 3) * 2) * 4;
    }
    const unsigned short* wsrc[SWC];
    #pragma unroll
    for (int i = 0; i < SWC; ++i) {
        int c = i * NT + tid;
        int row = c >> 3, chs = (c & 7) ^ (row & 7);
        wsrc[i] = Wmk + (size_t)(s0 + row) * KP + chs * 8;
    }

    // fragment row bases
    int arow[4], brow[4];
    #pragma unroll
    for (int mi = 0; mi < 4; ++mi) arow[mi] = (wr * 64 + mi * 16 + lr) * 64;
    #pragma unroll
    for (int si = 0; si < 4; ++si) brow[si] = (wsx * 64 + si * 16 + lr) * 64;

    const f32x4 fz = {0.f, 0.f, 0.f, 0.f};
    f32x4 acc[4][4];
    #pragma unroll
    for (int a = 0; a < 4; ++a)
        #pragma unroll
        for (int b = 0; b < 4; ++b) acc[a][b] = fz;

    // stage round kt into LDS buffer b
    auto stage = [&](int kt, int b) {
        size_t koff;
        if (MODE == 1) {
            const int tap = (kt * 64) / CIN;
            const int kh = tap / 3, kw = tap - (tap / 3) * 3;
            const int icb0 = (kt * 64) % CIN;
            koff = ((size_t)kh * WP + kw) * CIN + icb0;
        } else {
            koff = (size_t)kt * 2 * WP * 4;
        }
        #pragma unroll
        for (int i = 0; i < SXC; ++i) gload16(xsrc[i] + koff, &Xs[b][(i * NT + wid * 64) * 8]);
        #pragma unroll
        for (int i = 0; i < SWC; ++i) gload16(wsrc[i] + (size_t)kt * 64, &Ws[b][(i * NT + wid * 64) * 8]);
    };

    stage(0, 0);
    #pragma unroll
    for (int kt = 0; kt < NKT; ++kt) {
        const int cur = kt & 1;
        if (kt + 1 < NKT) {
            stage(kt + 1, cur ^ 1);
            s_waitcnt_vm<NLOAD>();   // prev round's loads landed; new ones in flight
        } else {
            s_waitcnt_vm<0>();
        }
        __builtin_amdgcn_sched_barrier(0);
        __builtin_amdgcn_s_barrier();
        __builtin_amdgcn_sched_barrier(0);

        #pragma unroll
        for (int hf = 0; hf < 2; ++hf) {
            const int cA = (((hf * 4 + lk) ^ (lr & 7)) * 8);
            u16x8 af[4], bfr[4];
            #pragma unroll
            for (int mi = 0; mi < 4; ++mi) af[mi] = *(const u16x8*)&Xs[cur][arow[mi] + cA];
            #pragma unroll
            for (int si = 0; si < 4; ++si) bfr[si] = *(const u16x8*)&Ws[cur][brow[si] + cA];
            #pragma unroll
            for (int mi = 0; mi < 4; ++mi)
                #pragma unroll
                for (int si = 0; si < 4; ++si)
                    acc[mi][si] = __builtin_amdgcn_mfma_f32_16x16x32_bf16(
                        __builtin_bit_cast(bf16x8_t, af[mi]),
                        __builtin_bit_cast(bf16x8_t, bfr[si]), acc[mi][si], 0, 0, 0);
        }
        __builtin_amdgcn_sched_barrier(0);
        __builtin_amdgcn_s_barrier();   // reads of buf[cur] done before it is re-staged
    }

    // epilogue: D row=(lane>>4)*4+reg, col=lane&15 (per 16x16 fragment)
    #pragma unroll
    for (int si = 0; si < 4; ++si) {
        int col = s0 + wsx * 64 + si * 16 + lr;
        bool cok = col < Cout;
        float sc = cok ? scale[col] : 0.f;
        float sh = cok ? shift[col] : 0.f;
        #pragma unroll
        for (int mi = 0; mi < 4; ++mi) {
            int rbase = r0 + wr * 64 + mi * 16 + lk * 4;
            int oh = rbase >> WOS, ow = rbase & (WOUT - 1);
            #pragma unroll
            for (int j = 0; j < 4; ++j) {
                float v = acc[mi][si][j] * sc + sh;
                if (RELU) v = fmaxf(v, 0.f);
                if (OUT_NCHW) {
                    if (cok) ((float*)Yv)[(size_t)z * yImgStride + col * 4096 + rbase + j] = v;
                } else if (cok) {
                    size_t off = ((size_t)(oh + OPAD) * WOP + ow + OPAD + j) * Cout + col;
                    ((unsigned short*)Yv)[(size_t)z * yImgStride + off] = f2bf(v);
                }
            }
        }
    }
}

// ------- banded-MFMA 81-shift correlation -------
// cf, pf: NHWC bf16 [64][64][256]; out: padded [66][66][128] bf16 (ch>=81 stay 0).
__global__ __launch_bounds__(256)
void corr_mfma(const unsigned short* __restrict__ cf,
               const unsigned short* __restrict__ pf,
               unsigned short* __restrict__ out) {
    const int h = blockIdx.x;        // 0..63
    const int z = blockIdx.y;        // 0..7
    const int tid = threadIdx.x;
    const int lane = tid & 63, t = tid >> 6;
    const int lr = lane & 15, lk = lane >> 4;
    const unsigned short* cfi = cf + (size_t)z * 1048576;
    const unsigned short* pfi = pf + (size_t)z * 1048576;
    unsigned short* outp = out + (size_t)z * 557568;

    u16x8 a[8];
    {
        const unsigned short* ap = cfi + ((size_t)(h * 64 + t * 16 + lr)) * 256 + lk * 8;
        #pragma unroll
        for (int ks = 0; ks < 8; ++ks) a[ks] = *(const u16x8*)(ap + ks * 32);
    }

    const u16x8 zz = {0, 0, 0, 0, 0, 0, 0, 0};
    for (int di = -4; di <= 4; ++di) {
        const int h2 = h + di;
        const bool hok = (unsigned)h2 < 64u;
        #pragma unroll
        for (int ct = 0; ct < 2; ++ct) {
            const int wpg = t * 16 - 8 + ct * 16 + lr;
            u16x8 b[8];
            if (hok && (unsigned)wpg < 64u) {
                const unsigned short* bp = pfi + ((size_t)(h2 * 64 + wpg)) * 256 + lk * 8;
                #pragma unroll
                for (int ks = 0; ks < 8; ++ks) b[ks] = *(const u16x8*)(bp + ks * 32);
            } else {
                #pragma unroll
                for (int ks = 0; ks < 8; ++ks) b[ks] = zz;
            }
            f32x4 acc0 = {0.f, 0.f, 0.f, 0.f}, acc1 = {0.f, 0.f, 0.f, 0.f};
            #pragma unroll
            for (int ks = 0; ks < 8; ks += 2) {
                acc0 = __builtin_amdgcn_mfma_f32_16x16x32_bf16(
                    __builtin_bit_cast(bf16x8_t, a[ks]),
                    __builtin_bit_cast(bf16x8_t, b[ks]), acc0, 0, 0, 0);
                acc1 = __builtin_amdgcn_mfma_f32_16x16x32_bf16(
                    __builtin_bit_cast(bf16x8_t, a[ks + 1]),
                    __builtin_bit_cast(bf16x8_t, b[ks + 1]), acc1, 0, 0, 0);
            }
            const int wl = lk * 4;
            const int wpl = ct * 16 - 8 + lr;
            #pragma unroll
            for (int j = 0; j < 4; ++j) {
                int dj = wpl - (wl + j);
                if (dj >= -4 && dj <= 4) {
                    int s = (di + 4) * 9 + dj + 4;
                    int w = t * 16 + wl + j;
                    outp[((size_t)(h + 1) * 66 + w + 1) * 128 + s] =
                        f2bf(acc0[j] + acc1[j]);
                }
            }
        }
    }
}

// ---------------- launch ----------------
extern "C" void kernel_launch(void* const* d_in, const int* in_sizes, int n_in,
                              void* d_out, int out_size, void* d_ws, size_t ws_size,
                              hipStream_t stream) {
    const float* cloth  = (const float*)d_in[0];
    const float* person = (const float*)d_in[1];
    const float* w1 = (const float*)d_in[2];  const float* b1 = (const float*)d_in[3];
    const float* g1 = (const float*)d_in[4];  const float* be1 = (const float*)d_in[5];
    const float* m1 = (const float*)d_in[6];  const float* v1 = (const float*)d_in[7];
    const float* w2 = (const float*)d_in[8];  const float* b2 = (const float*)d_in[9];
    const float* g2 = (const float*)d_in[10]; const float* be2 = (const float*)d_in[11];
    const float* m2 = (const float*)d_in[12]; const float* v2 = (const float*)d_in[13];
    const float* w3 = (const float*)d_in[14]; const float* b3 = (const float*)d_in[15];
    const float* g3 = (const float*)d_in[16]; const float* be3 = (const float*)d_in[17];
    const float* m3 = (const float*)d_in[18]; const float* v3 = (const float*)d_in[19];
    const float* fw1 = (const float*)d_in[20]; const float* fb1 = (const float*)d_in[21];
    const float* fw2 = (const float*)d_in[22]; const float* fb2 = (const float*)d_in[23];
    const float* fw3 = (const float*)d_in[24]; const float* fb3 = (const float*)d_in[25];

    char* ws = (char*)d_ws;
    auto U = [&](size_t off) { return (unsigned short*)(ws + off); };
    // ---- layout (bytes), ws_size = 256 MiB = 268,435,456 ----
    unsigned short* nhwc = U(0);             // [518][518][4] x16 = 34,345,472
    unsigned short* t1   = U(34345472);      // [258][258][64] x16 = 136,323,072 -> ends 170,668,544
    unsigned short* cf   = U(34345472);      // alias t1 (dead after conv2): [64][64][256] x16
    unsigned short* t2   = U(170668544);     // [130][130][128] x16 = 69,222,400 -> ends 239,890,944
    unsigned short* w1mk  = U(239890944);    //  32,768 (64x256)
    unsigned short* w2mk  = U(239923712);    // 147,456 (128x576)
    unsigned short* w3mk  = U(240071168);    // 589,824 (256x1152)
    unsigned short* fw1mk = U(240660992);    // 294,912 (128x1152)
    unsigned short* fw2mk = U(240955904);    // 147,456 (64x1152)
    unsigned short* fw3mk = U(241103360);    //  73,728 (64x576) -> ends 241,177,088
    float* aff = (float*)(ws + 241177088);   // 8 KB
    // head buffers in DEDICATED tail region (never touched by nhwc/t1/t2 writes)
    unsigned short* corr = U(241185280);     // [66][66][128] x8 = 8,921,088 -> ends 250,106,368
    unsigned short* f1b  = U(250106368);     // [66][66][128] x8 = 8,921,088 -> ends 259,027,456
    unsigned short* f2b  = U(259027456);     // [66][66][64]  x8 = 4,460,544 -> ends 263,488,000
    float *s1 = aff,         *sh1 = aff + 64,   *s2 = aff + 128,  *sh2 = aff + 256;
    float *s3 = aff + 384,   *sh3 = aff + 640,  *sf1 = aff + 896, *shf1 = aff + 1024;
    float *sf2 = aff + 1152, *shf2 = aff + 1216, *sf3 = aff + 1280, *shf3 = aff + 1288;

    prep_affine<<<1, 64, 0, stream>>>(b1, g1, be1, m1, v1, s1, sh1, 64, 1);
    prep_affine<<<1, 128, 0, stream>>>(b2, g2, be2, m2, v2, s2, sh2, 128, 1);
    prep_affine<<<1, 256, 0, stream>>>(b3, g3, be3, m3, v3, s3, sh3, 256, 1);
    prep_affine<<<1, 128, 0, stream>>>(fb1, nullptr, nullptr, nullptr, nullptr, sf1, shf1, 128, 0);
    prep_affine<<<1, 64, 0, stream>>>(fb2, nullptr, nullptr, nullptr, nullptr, sf2, shf2, 64, 0);
    prep_affine<<<1, 2, 0, stream>>>(fb3, nullptr, nullptr, nullptr, nullptr, sf3, shf3, 2, 0);

    conv_weights1<<<64, 256, 0, stream>>>(w1, w1mk);
    conv_weights<64, 64><<<288, 256, 0, stream>>>(w2, w2mk, 128, 128, 576);
    conv_weights<128, 128><<<1152, 256, 0, stream>>>(w3, w3mk, 256, 256, 1152);
    conv_weights<81, 128><<<576, 256, 0, stream>>>(fw1, fw1mk, 128, 128, 1152);
    conv_weights<128, 128><<<288, 256, 0, stream>>>(fw2, fw2mk, 64, 64, 1152);
    conv_weights<64, 64><<<144, 256, 0, stream>>>(fw3, fw3mk, 2, 64, 576);

    // zero padded regions: nhwc (3-ring pad), head-buffer region (1-ring pads + dead chans),
    // t1/t2 rings
    hipMemsetAsync(ws, 0, 34345472, stream);
    hipMemsetAsync(ws + 241185280, 0, 22302720, stream);
    border_zero<<<514, 256, 0, stream>>>(t1, 258, 258, 8, 4260096, 16);
    border_zero<<<517, 256, 0, stream>>>(t2, 130, 130, 16, 2163200, 16);

    // input -> padded NHWC4 bf16, all 16 images
    to_nhwc4<<<dim3(1024, 1, 16), 256, 0, stream>>>(cloth, person, nhwc);

    // conv1: 7x7 s2 p3, nhwc[518,518,4] -> t1 pad[258,258,64]   (R=65536/BR=256)
    gemm_conv<4, 1, 2, true, false, 4, 4, 512, 8, 2, 1><<<dim3(256, 1, 16), 256, 0, stream>>>(
        nhwc, w1mk, s1, sh1, t1, 64, 1073296, 4260096);
    // conv2: 3x3 s2 p1, t1 -> t2 pad[130,130,128]   (R=16384/BR=128)
    gemm_conv<2, 2, 1, true, false, 64, 9, 256, 7, 2, 1><<<dim3(128, 1, 16), 256, 0, stream>>>(
        t1, w2mk, s2, sh2, t2, 128, 4260096, 2163200);
    // conv3: 3x3 s2 p1, t2 -> cf/pf unpadded [64,64,256]   (R=4096/BR=128)
    gemm_conv<2, 2, 1, true, false, 128, 18, 128, 6, 2, 0><<<dim3(32, 2, 16), 256, 0, stream>>>(
        t2, w3mk, s3, sh3, cf, 256, 2163200, 1048576);

    // correlation (banded MFMA) -> corr pad[66,66,128]
    corr_mfma<<<dim3(64, 8), 256, 0, stream>>>(cf, cf + (size_t)8 * 1048576, corr);

    // fconv1: 3x3 p1, corr -> f1b pad[66,66,128]
    gemm_conv<2, 2, 1, true, false, 128, 18, 64, 6, 1, 1><<<dim3(32, 1, 8), 256, 0, stream>>>(
        corr, fw1mk, sf1, shf1, f1b, 128, 557568, 557568);
    // fconv2: 3x3 p1, f1b -> f2b pad[66,66,64]
    gemm_conv<2, 1, 1, true, false, 128, 18, 64, 6, 1, 1><<<dim3(32, 1, 8), 128, 0, stream>>>(
        f1b, fw2mk, sf2, shf2, f2b, 64, 557568, 278784);
    // fconv3: 3x3 p1, f2b -> d_out NCHW fp32 [8][2][64][64]
    gemm_conv<2, 1, 1, false, true, 64, 9, 64, 6, 1, 0><<<dim3(32, 1, 8), 128, 0, stream>>>(
        f2b, fw3mk, sf3, shf3, (float*)d_out, 2, 278784, 8192);
}

// Round 12
// 306.065 us; speedup vs baseline: 97.0667x; 1.1345x over previous
//
#include <hip/hip_runtime.h>

typedef __bf16 bf16x8_t __attribute__((ext_vector_type(8)));
typedef float f32x4 __attribute__((ext_vector_type(4)));
typedef unsigned short u16x8 __attribute__((ext_vector_type(8)));
typedef unsigned short u16x4 __attribute__((ext_vector_type(4)));

#define EPS 1e-5f

__device__ __forceinline__ unsigned short f2bf(float f) {
    unsigned u = __builtin_bit_cast(unsigned, f);
    u += 0x7fff + ((u >> 16) & 1);          // RTNE
    return (unsigned short)(u >> 16);
}

// direct global->LDS 16B (dwordx4). LDS dest: wave-uniform base + lane*16.
__device__ __forceinline__ void gload16(const unsigned short* g, unsigned short* l) {
    __builtin_amdgcn_global_load_lds(
        (const __attribute__((address_space(1))) unsigned int*)g,
        (__attribute__((address_space(3))) unsigned int*)l,
        16, 0, 0);
}

// counted vmcnt wait (compile-time N)
template <int N> __device__ __forceinline__ void s_waitcnt_vm() {
    if constexpr (N == 0)       asm volatile("s_waitcnt vmcnt(0)" ::: "memory");
    else if constexpr (N == 8)  asm volatile("s_waitcnt vmcnt(8)" ::: "memory");
    else if constexpr (N == 10) asm volatile("s_waitcnt vmcnt(10)" ::: "memory");
    else if constexpr (N == 12) asm volatile("s_waitcnt vmcnt(12)" ::: "memory");
    else static_assert(N == 0, "unsupported vmcnt");
}

// ---------------- fused BN fold (all 6 layers, 642 channels) ----------------
__global__ void prep_affine_all(const float* __restrict__ b1, const float* __restrict__ g1,
                                const float* __restrict__ be1, const float* __restrict__ m1,
                                const float* __restrict__ v1,
                                const float* __restrict__ b2, const float* __restrict__ g2,
                                const float* __restrict__ be2, const float* __restrict__ m2,
                                const float* __restrict__ v2,
                                const float* __restrict__ b3, const float* __restrict__ g3,
                                const float* __restrict__ be3, const float* __restrict__ m3,
                                const float* __restrict__ v3,
                                const float* __restrict__ fb1, const float* __restrict__ fb2,
                                const float* __restrict__ fb3, float* __restrict__ aff) {
    int i = blockIdx.x * 256 + threadIdx.x;
    if (i < 64) {
        float s = g1[i] * rsqrtf(v1[i] + EPS);
        aff[i] = s; aff[64 + i] = (b1[i] - m1[i]) * s + be1[i];
    } else if (i < 192) {
        int c = i - 64; float s = g2[c] * rsqrtf(v2[c] + EPS);
        aff[128 + c] = s; aff[256 + c] = (b2[c] - m2[c]) * s + be2[c];
    } else if (i < 448) {
        int c = i - 192; float s = g3[c] * rsqrtf(v3[c] + EPS);
        aff[384 + c] = s; aff[640 + c] = (b3[c] - m3[c]) * s + be3[c];
    } else if (i < 576) {
        int c = i - 448; aff[896 + c] = 1.f; aff[1024 + c] = fb1[c];
    } else if (i < 640) {
        int c = i - 576; aff[1152 + c] = 1.f; aff[1216 + c] = fb2[c];
    } else if (i < 642) {
        int c = i - 640; aff[1280 + c] = 1.f; aff[1288 + c] = fb3[c];
    }
}

// ------- fused weight repack: blockIdx.y selects layer -------
__device__ __forceinline__ void wconv3x3(const float* __restrict__ w, unsigned short* __restrict__ dst,
                                         int Cout, int Sp, int Kp, int CIN, int CINP, int idx) {
    if (idx >= Sp * Kp) return;
    int m = idx / Kp, k = idx - m * Kp;
    int tap = k / CINP, ic = k - tap * CINP;
    unsigned short v = 0;
    if (m < Cout && tap < 9 && ic < CIN) {
        int kh = tap / 3, kw = tap - kh * 3;
        v = f2bf(w[((m * CIN + ic) * 3 + kh) * 3 + kw]);
    }
    dst[idx] = v;
}

__global__ void conv_weights_all(const float* __restrict__ w1, const float* __restrict__ w2,
                                 const float* __restrict__ w3, const float* __restrict__ fw1,
                                 const float* __restrict__ fw2, const float* __restrict__ fw3,
                                 unsigned short* d1, unsigned short* d2, unsigned short* d3,
                                 unsigned short* d4, unsigned short* d5, unsigned short* d6) {
    int idx = blockIdx.x * 256 + threadIdx.x;
    switch (blockIdx.y) {
    case 0: {  // conv1: [64,3,7,7] -> [64][256], k = kh*32 + kw*4 + ic
        if (idx >= 64 * 256) return;
        int m = idx >> 8, k = idx & 255;
        int kh = k >> 5, r = k & 31, kw = r >> 2, ic = r & 3;
        unsigned short v = 0;
        if (kh < 7 && kw < 7 && ic < 3) v = f2bf(w1[((m * 3 + ic) * 7 + kh) * 7 + kw]);
        d1[idx] = v;
    } break;
    case 1: wconv3x3(w2, d2, 128, 128, 576, 64, 64, idx); break;
    case 2: wconv3x3(w3, d3, 256, 256, 1152, 128, 128, idx); break;
    case 3: wconv3x3(fw1, d4, 128, 128, 1152, 81, 128, idx); break;
    case 4: wconv3x3(fw2, d5, 64, 64, 1152, 128, 128, idx); break;
    case 5: wconv3x3(fw3, d6, 2, 64, 576, 64, 64, idx); break;
    }
}

// ------- input NCHW fp32 [3][512][512] -> padded NHWC4 bf16 [518][518][4] -------
__global__ void to_nhwc4(const float* __restrict__ cloth, const float* __restrict__ person,
                         unsigned short* __restrict__ dst) {
    int z = blockIdx.z;
    const float* src = (z < 8) ? cloth + (size_t)z * 786432
                               : person + (size_t)(z - 8) * 786432;
    int p = blockIdx.x * 256 + threadIdx.x;  // pixel 0..262143
    int row = p >> 9, col = p & 511;
    u16x4 o;
    o[0] = f2bf(src[p]);
    o[1] = f2bf(src[262144 + p]);
    o[2] = f2bf(src[524288 + p]);
    o[3] = 0;
    *(u16x4*)&dst[(size_t)z * 1073296 + ((size_t)(row + 3) * 518 + col + 3) * 4] = o;
}

// ------- zero the 1-ring border of padded NHWC [Hp][Wp][C8*8] for nimg images -------
__global__ void border_zero(unsigned short* __restrict__ buf, int Hp, int Wp, int C8,
                            int imgStrideElems, int nimg) {
    int idx = blockIdx.x * 256 + threadIdx.x;
    int nb = 2 * Wp + 2 * (Hp - 2);
    int per = nb * C8;
    if (idx >= per * nimg) return;
    int z = idx / per, q = idx - z * per;
    int p = q / C8, cc = q - p * C8;
    int row, col;
    if (p < Wp) { row = 0; col = p; }
    else if (p < 2 * Wp) { row = Hp - 1; col = p - Wp; }
    else { int e = p - 2 * Wp; row = 1 + (e >> 1); col = (e & 1) ? Wp - 1 : 0; }
    const u16x8 zv = {0, 0, 0, 0, 0, 0, 0, 0};
    *(u16x8*)&buf[(size_t)z * imgStrideElems + ((size_t)row * Wp + col) * (C8 * 8) + cc * 8] = zv;
}

// ------- MFMA GEMM, implicit im2col, global_load_lds, 2-phase dbuf pipeline -------
// MODE 1: 3x3 conv pad1, X = padded NHWC [HIN+2][HIN+2][CIN], K layout tap*CIN+ic.
// MODE 2: conv1 7x7 s2 p3, X = padded NHWC4 [518][518][4], K layout kh*32+kw*4+ic (kh<8).
// XCD-aware bx swizzle (gridDim.x % 8 == 0): adjacent-row blocks share an XCD's L2.
// Epilogue: bf16 tile staged to LDS (reusing Xs), then u16x8 coalesced stores.
template <int WR, int WS, int MODE, bool RELU, bool OUT_NCHW, int CIN, int NKT,
          int HIN, int WOS, int STRIDE, int OPAD>
__global__ __launch_bounds__(WR * WS * 64)
void gemm_conv(const unsigned short* __restrict__ X, const unsigned short* __restrict__ Wmk,
               const float* __restrict__ scale, const float* __restrict__ shift,
               void* __restrict__ Yv, int Cout, int xImgStride, int yImgStride) {
    constexpr int BR = WR * 64, BS = WS * 64, NT = WR * WS * 64;
    constexpr int SXC = BR * 8 / NT, SWC = BS * 8 / NT;   // 16B chunks per thread
    constexpr int NLOAD = SXC + SWC;
    constexpr int KP = (MODE == 1) ? NKT * 64 : 256;
    constexpr int WP = HIN + ((MODE == 2) ? 6 : 2);       // padded width
    constexpr int WOUT = 1 << WOS;
    constexpr int WOP = WOUT + 2 * OPAD;
    __shared__ __align__(16) unsigned short Xs[2][BR * 64];
    __shared__ __align__(16) unsigned short Ws[2][BS * 64];
    const int tid = threadIdx.x;
    const int lane = tid & 63, wid = tid >> 6;
    const int wr = wid % WR, wsx = wid / WR;
    int bx = blockIdx.x;
    { const int nx = gridDim.x; bx = (bx & 7) * (nx >> 3) + (bx >> 3); }  // XCD swizzle
    const int r0 = bx * BR, s0 = blockIdx.y * BS;
    const int z = blockIdx.z;
    const int lr = lane & 15, lk = lane >> 4;
    const unsigned short* Ximg = X + (size_t)z * xImgStride;

    // per-chunk global source base (kt=0), XOR-swizzled chunk select
    const unsigned short* xsrc[SXC];
    #pragma unroll
    for (int i = 0; i < SXC; ++i) {
        int c = i * NT + tid;
        int row = c >> 3, chs = (c & 7) ^ (row & 7);
        int r = r0 + row;
        int oh = r >> WOS, ow = r & (WOUT - 1);
        if (MODE == 1)
            xsrc[i] = Ximg + ((size_t)(oh * STRIDE) * WP + (size_t)(ow * STRIDE)) * CIN + chs * 8;
        else
            xsrc[i] = Ximg + ((size_t)(2 * oh + (chs >> 2)) * WP + 2 * ow + (chs & 3) * 2) * 4;
    }
    const unsigned short* wsrc[SWC];
    #pragma unroll
    for (int i = 0; i < SWC; ++i) {
        int c = i * NT + tid;
        int row = c >> 3, chs = (c & 7) ^ (row & 7);
        wsrc[i] = Wmk + (size_t)(s0 + row) * KP + chs * 8;
    }

    // fragment row bases
    int arow[4], brow[4];
    #pragma unroll
    for (int mi = 0; mi < 4; ++mi) arow[mi] = (wr * 64 + mi * 16 + lr) * 64;
    #pragma unroll
    for (int si = 0; si < 4; ++si) brow[si] = (wsx * 64 + si * 16 + lr) * 64;

    const f32x4 fz = {0.f, 0.f, 0.f, 0.f};
    f32x4 acc[4][4];
    #pragma unroll
    for (int a = 0; a < 4; ++a)
        #pragma unroll
        for (int b = 0; b < 4; ++b) acc[a][b] = fz;

    // stage round kt into LDS buffer b
    auto stage = [&](int kt, int b) {
        size_t koff;
        if (MODE == 1) {
            const int tap = (kt * 64) / CIN;
            const int kh = tap / 3, kw = tap - (tap / 3) * 3;
            const int icb0 = (kt * 64) % CIN;
            koff = ((size_t)kh * WP + kw) * CIN + icb0;
        } else {
            koff = (size_t)kt * 2 * WP * 4;
        }
        #pragma unroll
        for (int i = 0; i < SXC; ++i) gload16(xsrc[i] + koff, &Xs[b][(i * NT + wid * 64) * 8]);
        #pragma unroll
        for (int i = 0; i < SWC; ++i) gload16(wsrc[i] + (size_t)kt * 64, &Ws[b][(i * NT + wid * 64) * 8]);
    };

    stage(0, 0);
    #pragma unroll
    for (int kt = 0; kt < NKT; ++kt) {
        const int cur = kt & 1;
        if (kt + 1 < NKT) {
            stage(kt + 1, cur ^ 1);
            s_waitcnt_vm<NLOAD>();   // prev round's loads landed; new ones in flight
        } else {
            s_waitcnt_vm<0>();
        }
        __builtin_amdgcn_sched_barrier(0);
        __builtin_amdgcn_s_barrier();
        __builtin_amdgcn_sched_barrier(0);

        #pragma unroll
        for (int hf = 0; hf < 2; ++hf) {
            const int cA = (((hf * 4 + lk) ^ (lr & 7)) * 8);
            u16x8 af[4], bfr[4];
            #pragma unroll
            for (int mi = 0; mi < 4; ++mi) af[mi] = *(const u16x8*)&Xs[cur][arow[mi] + cA];
            #pragma unroll
            for (int si = 0; si < 4; ++si) bfr[si] = *(const u16x8*)&Ws[cur][brow[si] + cA];
            #pragma unroll
            for (int mi = 0; mi < 4; ++mi)
                #pragma unroll
                for (int si = 0; si < 4; ++si)
                    acc[mi][si] = __builtin_amdgcn_mfma_f32_16x16x32_bf16(
                        __builtin_bit_cast(bf16x8_t, af[mi]),
                        __builtin_bit_cast(bf16x8_t, bfr[si]), acc[mi][si], 0, 0, 0);
        }
        __builtin_amdgcn_sched_barrier(0);
        __builtin_amdgcn_s_barrier();   // reads of buf[cur] done before it is re-staged
    }

    // ---- epilogue ----
    if (OUT_NCHW) {
        // fconv3: scalar fp32 NCHW stores (tiny)
        #pragma unroll
        for (int si = 0; si < 4; ++si) {
            int col = s0 + wsx * 64 + si * 16 + lr;
            bool cok = col < Cout;
            float sc = cok ? scale[col] : 0.f;
            float sh = cok ? shift[col] : 0.f;
            #pragma unroll
            for (int mi = 0; mi < 4; ++mi) {
                int rbase = r0 + wr * 64 + mi * 16 + lk * 4;
                #pragma unroll
                for (int j = 0; j < 4; ++j) {
                    float v = acc[mi][si][j] * sc + sh;
                    if (RELU) v = fmaxf(v, 0.f);
                    if (cok) ((float*)Yv)[(size_t)z * yImgStride + col * 4096 + rbase + j] = v;
                }
            }
        }
    } else {
        // stage bf16 tile in LDS (reuse Xs: BR*BS <= 2*BR*64), then coalesced u16x8 stores
        unsigned short* epi = (unsigned short*)Xs;
        #pragma unroll
        for (int si = 0; si < 4; ++si) {
            int col = wsx * 64 + si * 16 + lr;       // block-local col; always < Cout here
            float sc = scale[s0 + col];
            float sh = shift[s0 + col];
            #pragma unroll
            for (int mi = 0; mi < 4; ++mi) {
                int rowl = wr * 64 + mi * 16 + lk * 4;
                #pragma unroll
                for (int j = 0; j < 4; ++j) {
                    float v = acc[mi][si][j] * sc + sh;
                    if (RELU) v = fmaxf(v, 0.f);
                    epi[(rowl + j) * BS + col] = f2bf(v);
                }
            }
        }
        __syncthreads();
        constexpr int NCH = BR * BS / 8 / NT;        // 8-col chunks per thread
        constexpr int CPR = BS / 8;                  // chunks per row
        #pragma unroll
        for (int i = 0; i < NCH; ++i) {
            int c = i * NT + tid;
            int row = c / CPR, colc = c - (c / CPR) * CPR;
            int r = r0 + row;
            int oh = r >> WOS, ow = r & (WOUT - 1);
            size_t off = ((size_t)(oh + OPAD) * WOP + ow + OPAD) * Cout + s0 + colc * 8;
            *(u16x8*)((unsigned short*)Yv + (size_t)z * yImgStride + off) =
                *(const u16x8*)&epi[row * BS + colc * 8];
        }
    }
}

// ------- banded-MFMA 81-shift correlation -------
// cf, pf: NHWC bf16 [64][64][256]; out: padded [66][66][128] bf16 (ch>=81 stay 0).
__global__ __launch_bounds__(256)
void corr_mfma(const unsigned short* __restrict__ cf,
               const unsigned short* __restrict__ pf,
               unsigned short* __restrict__ out) {
    const int h = blockIdx.x;        // 0..63
    const int z = blockIdx.y;        // 0..7
    const int tid = threadIdx.x;
    const int lane = tid & 63, t = tid >> 6;
    const int lr = lane & 15, lk = lane >> 4;
    const unsigned short* cfi = cf + (size_t)z * 1048576;
    const unsigned short* pfi = pf + (size_t)z * 1048576;
    unsigned short* outp = out + (size_t)z * 557568;

    u16x8 a[8];
    {
        const unsigned short* ap = cfi + ((size_t)(h * 64 + t * 16 + lr)) * 256 + lk * 8;
        #pragma unroll
        for (int ks = 0; ks < 8; ++ks) a[ks] = *(const u16x8*)(ap + ks * 32);
    }

    const u16x8 zz = {0, 0, 0, 0, 0, 0, 0, 0};
    for (int di = -4; di <= 4; ++di) {
        const int h2 = h + di;
        const bool hok = (unsigned)h2 < 64u;
        #pragma unroll
        for (int ct = 0; ct < 2; ++ct) {
            const int wpg = t * 16 - 8 + ct * 16 + lr;
            u16x8 b[8];
            if (hok && (unsigned)wpg < 64u) {
                const unsigned short* bp = pfi + ((size_t)(h2 * 64 + wpg)) * 256 + lk * 8;
                #pragma unroll
                for (int ks = 0; ks < 8; ++ks) b[ks] = *(const u16x8*)(bp + ks * 32);
            } else {
                #pragma unroll
                for (int ks = 0; ks < 8; ++ks) b[ks] = zz;
            }
            f32x4 acc0 = {0.f, 0.f, 0.f, 0.f}, acc1 = {0.f, 0.f, 0.f, 0.f};
            #pragma unroll
            for (int ks = 0; ks < 8; ks += 2) {
                acc0 = __builtin_amdgcn_mfma_f32_16x16x32_bf16(
                    __builtin_bit_cast(bf16x8_t, a[ks]),
                    __builtin_bit_cast(bf16x8_t, b[ks]), acc0, 0, 0, 0);
                acc1 = __builtin_amdgcn_mfma_f32_16x16x32_bf16(
                    __builtin_bit_cast(bf16x8_t, a[ks + 1]),
                    __builtin_bit_cast(bf16x8_t, b[ks + 1]), acc1, 0, 0, 0);
            }
            const int wl = lk * 4;
            const int wpl = ct * 16 - 8 + lr;
            #pragma unroll
            for (int j = 0; j < 4; ++j) {
                int dj = wpl - (wl + j);
                if (dj >= -4 && dj <= 4) {
                    int s = (di + 4) * 9 + dj + 4;
                    int w = t * 16 + wl + j;
                    outp[((size_t)(h + 1) * 66 + w + 1) * 128 + s] =
                        f2bf(acc0[j] + acc1[j]);
                }
            }
        }
    }
}

// ---------------- launch ----------------
extern "C" void kernel_launch(void* const* d_in, const int* in_sizes, int n_in,
                              void* d_out, int out_size, void* d_ws, size_t ws_size,
                              hipStream_t stream) {
    const float* cloth  = (const float*)d_in[0];
    const float* person = (const float*)d_in[1];
    const float* w1 = (const float*)d_in[2];  const float* b1 = (const float*)d_in[3];
    const float* g1 = (const float*)d_in[4];  const float* be1 = (const float*)d_in[5];
    const float* m1 = (const float*)d_in[6];  const float* v1 = (const float*)d_in[7];
    const float* w2 = (const float*)d_in[8];  const float* b2 = (const float*)d_in[9];
    const float* g2 = (const float*)d_in[10]; const float* be2 = (const float*)d_in[11];
    const float* m2 = (const float*)d_in[12]; const float* v2 = (const float*)d_in[13];
    const float* w3 = (const float*)d_in[14]; const float* b3 = (const float*)d_in[15];
    const float* g3 = (const float*)d_in[16]; const float* be3 = (const float*)d_in[17];
    const float* m3 = (const float*)d_in[18]; const float* v3 = (const float*)d_in[19];
    const float* fw1 = (const float*)d_in[20]; const float* fb1 = (const float*)d_in[21];
    const float* fw2 = (const float*)d_in[22]; const float* fb2 = (const float*)d_in[23];
    const float* fw3 = (const float*)d_in[24]; const float* fb3 = (const float*)d_in[25];

    char* ws = (char*)d_ws;
    auto U = [&](size_t off) { return (unsigned short*)(ws + off); };
    // ---- layout (bytes), ws_size = 256 MiB = 268,435,456 ----
    unsigned short* nhwc = U(0);             // [518][518][4] x16 = 34,345,472
    unsigned short* t1   = U(34345472);      // [258][258][64] x16 = 136,323,072 -> ends 170,668,544
    unsigned short* cf   = U(34345472);      // alias t1 (dead after conv2): [64][64][256] x16
    unsigned short* t2   = U(170668544);     // [130][130][128] x16 = 69,222,400 -> ends 239,890,944
    unsigned short* w1mk  = U(239890944);    //  32,768 (64x256)
    unsigned short* w2mk  = U(239923712);    // 147,456 (128x576)
    unsigned short* w3mk  = U(240071168);    // 589,824 (256x1152)
    unsigned short* fw1mk = U(240660992);    // 294,912 (128x1152)
    unsigned short* fw2mk = U(240955904);    // 147,456 (64x1152)
    unsigned short* fw3mk = U(241103360);    //  73,728 (64x576) -> ends 241,177,088
    float* aff = (float*)(ws + 241177088);   // 8 KB
    // head buffers in DEDICATED tail region (never touched by nhwc/t1/t2 writes)
    unsigned short* corr = U(241185280);     // [66][66][128] x8 = 8,921,088 -> ends 250,106,368
    unsigned short* f1b  = U(250106368);     // [66][66][128] x8 = 8,921,088 -> ends 259,027,456
    unsigned short* f2b  = U(259027456);     // [66][66][64]  x8 = 4,460,544 -> ends 263,488,000
    float *s1 = aff,         *sh1 = aff + 64,   *s2 = aff + 128,  *sh2 = aff + 256;
    float *s3 = aff + 384,   *sh3 = aff + 640,  *sf1 = aff + 896, *shf1 = aff + 1024;
    float *sf2 = aff + 1152, *shf2 = aff + 1216, *sf3 = aff + 1280, *shf3 = aff + 1288;

    prep_affine_all<<<3, 256, 0, stream>>>(b1, g1, be1, m1, v1, b2, g2, be2, m2, v2,
                                           b3, g3, be3, m3, v3, fb1, fb2, fb3, aff);
    conv_weights_all<<<dim3(1152, 6), 256, 0, stream>>>(w1, w2, w3, fw1, fw2, fw3,
                                                        w1mk, w2mk, w3mk, fw1mk, fw2mk, fw3mk);

    // zero padded regions: nhwc (3-ring pad), head-buffer region (1-ring pads + dead chans),
    // t1/t2 rings
    hipMemsetAsync(ws, 0, 34345472, stream);
    hipMemsetAsync(ws + 241185280, 0, 22302720, stream);
    border_zero<<<514, 256, 0, stream>>>(t1, 258, 258, 8, 4260096, 16);
    border_zero<<<517, 256, 0, stream>>>(t2, 130, 130, 16, 2163200, 16);

    // input -> padded NHWC4 bf16, all 16 images
    to_nhwc4<<<dim3(1024, 1, 16), 256, 0, stream>>>(cloth, person, nhwc);

    // conv1: 7x7 s2 p3, nhwc[518,518,4] -> t1 pad[258,258,64]   (R=65536/BR=256)
    gemm_conv<4, 1, 2, true, false, 4, 4, 512, 8, 2, 1><<<dim3(256, 1, 16), 256, 0, stream>>>(
        nhwc, w1mk, s1, sh1, t1, 64, 1073296, 4260096);
    // conv2: 3x3 s2 p1, t1 -> t2 pad[130,130,128]   (R=16384/BR=128)
    gemm_conv<2, 2, 1, true, false, 64, 9, 256, 7, 2, 1><<<dim3(128, 1, 16), 256, 0, stream>>>(
        t1, w2mk, s2, sh2, t2, 128, 4260096, 2163200);
    // conv3: 3x3 s2 p1, t2 -> cf/pf unpadded [64,64,256]   (R=4096/BR=128)
    gemm_conv<2, 2, 1, true, false, 128, 18, 128, 6, 2, 0><<<dim3(32, 2, 16), 256, 0, stream>>>(
        t2, w3mk, s3, sh3, cf, 256, 2163200, 1048576);

    // correlation (banded MFMA) -> corr pad[66,66,128]
    corr_mfma<<<dim3(64, 8), 256, 0, stream>>>(cf, cf + (size_t)8 * 1048576, corr);

    // fconv1: 3x3 p1, corr -> f1b pad[66,66,128]
    gemm_conv<2, 2, 1, true, false, 128, 18, 64, 6, 1, 1><<<dim3(32, 1, 8), 256, 0, stream>>>(
        corr, fw1mk, sf1, shf1, f1b, 128, 557568, 557568);
    // fconv2: 3x3 p1, f1b -> f2b pad[66,66,64]
    gemm_conv<2, 1, 1, true, false, 128, 18, 64, 6, 1, 1><<<dim3(32, 1, 8), 128, 0, stream>>>(
        f1b, fw2mk, sf2, shf2, f2b, 64, 557568, 278784);
    // fconv3: 3x3 p1, f2b -> d_out NCHW fp32 [8][2][64][64]
    gemm_conv<2, 1, 1, false, true, 64, 9, 64, 6, 1, 0><<<dim3(32, 1, 8), 128, 0, stream>>>(
        f2b, fw3mk, sf3, shf3, (float*)d_out, 2, 278784, 8192);
}

// Round 13
// 271.183 us; speedup vs baseline: 109.5521x; 1.1286x over previous
//
#include <hip/hip_runtime.h>

typedef __bf16 bf16x8_t __attribute__((ext_vector_type(8)));
typedef float f32x4 __attribute__((ext_vector_type(4)));
typedef unsigned short u16x8 __attribute__((ext_vector_type(8)));
typedef unsigned short u16x4 __attribute__((ext_vector_type(4)));

#define EPS 1e-5f

__device__ __forceinline__ unsigned short f2bf(float f) {
    unsigned u = __builtin_bit_cast(unsigned, f);
    u += 0x7fff + ((u >> 16) & 1);          // RTNE
    return (unsigned short)(u >> 16);
}

// direct global->LDS 16B (dwordx4). LDS dest: wave-uniform base + lane*16.
__device__ __forceinline__ void gload16(const unsigned short* g, unsigned short* l) {
    __builtin_amdgcn_global_load_lds(
        (const __attribute__((address_space(1))) unsigned int*)g,
        (__attribute__((address_space(3))) unsigned int*)l,
        16, 0, 0);
}

// counted vmcnt wait (compile-time N)
template <int N> __device__ __forceinline__ void s_waitcnt_vm() {
    if constexpr (N == 0)       asm volatile("s_waitcnt vmcnt(0)" ::: "memory");
    else if constexpr (N == 8)  asm volatile("s_waitcnt vmcnt(8)" ::: "memory");
    else if constexpr (N == 10) asm volatile("s_waitcnt vmcnt(10)" ::: "memory");
    else if constexpr (N == 12) asm volatile("s_waitcnt vmcnt(12)" ::: "memory");
    else static_assert(N == 0, "unsupported vmcnt");
}

// ---------------- fused BN fold (all 6 layers, 642 channels) ----------------
__global__ void prep_affine_all(const float* __restrict__ b1, const float* __restrict__ g1,
                                const float* __restrict__ be1, const float* __restrict__ m1,
                                const float* __restrict__ v1,
                                const float* __restrict__ b2, const float* __restrict__ g2,
                                const float* __restrict__ be2, const float* __restrict__ m2,
                                const float* __restrict__ v2,
                                const float* __restrict__ b3, const float* __restrict__ g3,
                                const float* __restrict__ be3, const float* __restrict__ m3,
                                const float* __restrict__ v3,
                                const float* __restrict__ fb1, const float* __restrict__ fb2,
                                const float* __restrict__ fb3, float* __restrict__ aff) {
    int i = blockIdx.x * 256 + threadIdx.x;
    if (i < 64) {
        float s = g1[i] * rsqrtf(v1[i] + EPS);
        aff[i] = s; aff[64 + i] = (b1[i] - m1[i]) * s + be1[i];
    } else if (i < 192) {
        int c = i - 64; float s = g2[c] * rsqrtf(v2[c] + EPS);
        aff[128 + c] = s; aff[256 + c] = (b2[c] - m2[c]) * s + be2[c];
    } else if (i < 448) {
        int c = i - 192; float s = g3[c] * rsqrtf(v3[c] + EPS);
        aff[384 + c] = s; aff[640 + c] = (b3[c] - m3[c]) * s + be3[c];
    } else if (i < 576) {
        int c = i - 448; aff[896 + c] = 1.f; aff[1024 + c] = fb1[c];
    } else if (i < 640) {
        int c = i - 576; aff[1152 + c] = 1.f; aff[1216 + c] = fb2[c];
    } else if (i < 642) {
        int c = i - 640; aff[1280 + c] = 1.f; aff[1288 + c] = fb3[c];
    }
}

// ------- fused weight repack: blockIdx.y selects layer -------
__device__ __forceinline__ void wconv3x3(const float* __restrict__ w, unsigned short* __restrict__ dst,
                                         int Cout, int Sp, int Kp, int CIN, int CINP, int idx) {
    if (idx >= Sp * Kp) return;
    int m = idx / Kp, k = idx - m * Kp;
    int tap = k / CINP, ic = k - tap * CINP;
    unsigned short v = 0;
    if (m < Cout && tap < 9 && ic < CIN) {
        int kh = tap / 3, kw = tap - kh * 3;
        v = f2bf(w[((m * CIN + ic) * 3 + kh) * 3 + kw]);
    }
    dst[idx] = v;
}

__global__ void conv_weights_all(const float* __restrict__ w1, const float* __restrict__ w2,
                                 const float* __restrict__ w3, const float* __restrict__ fw1,
                                 const float* __restrict__ fw2, const float* __restrict__ fw3,
                                 unsigned short* d1, unsigned short* d2, unsigned short* d3,
                                 unsigned short* d4, unsigned short* d5, unsigned short* d6) {
    int idx = blockIdx.x * 256 + threadIdx.x;
    switch (blockIdx.y) {
    case 0: {  // conv1: [64,3,7,7] -> [64][256], k = kh*32 + kw*4 + ic
        if (idx >= 64 * 256) return;
        int m = idx >> 8, k = idx & 255;
        int kh = k >> 5, r = k & 31, kw = r >> 2, ic = r & 3;
        unsigned short v = 0;
        if (kh < 7 && kw < 7 && ic < 3) v = f2bf(w1[((m * 3 + ic) * 7 + kh) * 7 + kw]);
        d1[idx] = v;
    } break;
    case 1: wconv3x3(w2, d2, 128, 128, 576, 64, 64, idx); break;
    case 2: wconv3x3(w3, d3, 256, 256, 1152, 128, 128, idx); break;
    case 3: wconv3x3(fw1, d4, 128, 128, 1152, 81, 128, idx); break;
    case 4: wconv3x3(fw2, d5, 64, 64, 1152, 128, 128, idx); break;
    case 5: wconv3x3(fw3, d6, 2, 64, 576, 64, 64, idx); break;
    }
}

// ------- input NCHW fp32 [3][512][512] -> padded NHWC4 bf16 [518][518][4] -------
__global__ void to_nhwc4(const float* __restrict__ cloth, const float* __restrict__ person,
                         unsigned short* __restrict__ dst) {
    int z = blockIdx.z;
    const float* src = (z < 8) ? cloth + (size_t)z * 786432
                               : person + (size_t)(z - 8) * 786432;
    int p = blockIdx.x * 256 + threadIdx.x;  // pixel 0..262143
    int row = p >> 9, col = p & 511;
    u16x4 o;
    o[0] = f2bf(src[p]);
    o[1] = f2bf(src[262144 + p]);
    o[2] = f2bf(src[524288 + p]);
    o[3] = 0;
    *(u16x4*)&dst[(size_t)z * 1073296 + ((size_t)(row + 3) * 518 + col + 3) * 4] = o;
}

// ------- zero the 3-ring border of padded NHWC4 [518][518][4], z = blockIdx.y -------
__global__ void ring3_zero(unsigned short* __restrict__ buf) {
    int z = blockIdx.y;
    int p = blockIdx.x * 256 + threadIdx.x;   // 0..6179 border pixels
    if (p >= 6180) return;
    int r, c;
    if (p < 1554) { r = p / 518; c = p - (p / 518) * 518; }
    else if (p < 3108) { int q = p - 1554; r = 515 + q / 518; c = q - (q / 518) * 518; }
    else { int q = p - 3108; r = 3 + q / 6; int k = q - (q / 6) * 6; c = (k < 3) ? k : 512 + k; }
    const u16x4 zv = {0, 0, 0, 0};
    *(u16x4*)&buf[(size_t)z * 1073296 + ((size_t)r * 518 + c) * 4] = zv;
}

// ------- zero the 1-ring border of padded NHWC [Hp][Wp][C8*8] for nimg images -------
__global__ void border_zero(unsigned short* __restrict__ buf, int Hp, int Wp, int C8,
                            int imgStrideElems, int nimg) {
    int idx = blockIdx.x * 256 + threadIdx.x;
    int nb = 2 * Wp + 2 * (Hp - 2);
    int per = nb * C8;
    if (idx >= per * nimg) return;
    int z = idx / per, q = idx - z * per;
    int p = q / C8, cc = q - p * C8;
    int row, col;
    if (p < Wp) { row = 0; col = p; }
    else if (p < 2 * Wp) { row = Hp - 1; col = p - Wp; }
    else { int e = p - 2 * Wp; row = 1 + (e >> 1); col = (e & 1) ? Wp - 1 : 0; }
    const u16x8 zv = {0, 0, 0, 0, 0, 0, 0, 0};
    *(u16x8*)&buf[(size_t)z * imgStrideElems + ((size_t)row * Wp + col) * (C8 * 8) + cc * 8] = zv;
}

// ------- MFMA GEMM, implicit im2col, global_load_lds staging -------
// MODE 1: 3x3 conv pad1, X = padded NHWC [HIN+2][HIN+2][CIN], K layout tap*CIN+ic.
// MODE 2: conv1 7x7 s2 p3, X = padded NHWC4 [518][518][4], K layout kh*32+kw*4+ic (kh<8).
// PIPE 0: single LDS buffer, drain per round (max occupancy — for small NKT).
// PIPE 1: double-buffered, counted vmcnt pipeline (for larger NKT).
// XCD-aware bx swizzle; epilogue staged in LDS (stride BS+8) + u16x8 coalesced stores.
template <int WR, int WS, int MODE, bool RELU, bool OUT_NCHW, int CIN, int NKT,
          int HIN, int WOS, int STRIDE, int OPAD, int PIPE>
__global__ __launch_bounds__(WR * WS * 64)
void gemm_conv(const unsigned short* __restrict__ X, const unsigned short* __restrict__ Wmk,
               const float* __restrict__ scale, const float* __restrict__ shift,
               void* __restrict__ Yv, int Cout, int xImgStride, int yImgStride) {
    constexpr int BR = WR * 64, BS = WS * 64, NT = WR * WS * 64;
    constexpr int SXC = BR * 8 / NT, SWC = BS * 8 / NT;   // 16B chunks per thread
    constexpr int NLOAD = SXC + SWC;
    constexpr int KP = (MODE == 1) ? NKT * 64 : 256;
    constexpr int WP = HIN + ((MODE == 2) ? 6 : 2);       // padded width
    constexpr int WOUT = 1 << WOS;
    constexpr int WOP = WOUT + 2 * OPAD;
    constexpr int NBUF = PIPE ? 2 : 1;
    constexpr int EPS_LDK = BS + 8;                        // epilogue row stride
    constexpr int GEMM_ELEMS = NBUF * (BR + BS) * 64;
    constexpr int EPI_ELEMS = BR * EPS_LDK;
    constexpr int LDS_ELEMS = GEMM_ELEMS > EPI_ELEMS ? GEMM_ELEMS : EPI_ELEMS;
    __shared__ __align__(16) unsigned short lds[LDS_ELEMS];
    unsigned short* XsB = lds;                      // [NBUF][BR*64]
    unsigned short* WsB = lds + NBUF * BR * 64;     // [NBUF][BS*64]
    const int tid = threadIdx.x;
    const int lane = tid & 63, wid = tid >> 6;
    const int wr = wid % WR, wsx = wid / WR;
    int bx = blockIdx.x;
    { const int nx = gridDim.x; bx = (bx & 7) * (nx >> 3) + (bx >> 3); }  // XCD swizzle
    const int r0 = bx * BR, s0 = blockIdx.y * BS;
    const int z = blockIdx.z;
    const int lr = lane & 15, lk = lane >> 4;
    const unsigned short* Ximg = X + (size_t)z * xImgStride;

    // per-chunk global source base (kt=0), XOR-swizzled chunk select
    const unsigned short* xsrc[SXC];
    #pragma unroll
    for (int i = 0; i < SXC; ++i) {
        int c = i * NT + tid;
        int row = c >> 3, chs = (c & 7) ^ (row & 7);
        int r = r0 + row;
        int oh = r >> WOS, ow = r & (WOUT - 1);
        if (MODE == 1)
            xsrc[i] = Ximg + ((size_t)(oh * STRIDE) * WP + (size_t)(ow * STRIDE)) * CIN + chs * 8;
        else
            xsrc[i] = Ximg + ((size_t)(2 * oh + (chs >> 2)) * WP + 2 * ow + (chs & 3) * 2) * 4;
    }
    const unsigned short* wsrc[SWC];
    #pragma unroll
    for (int i = 0; i < SWC; ++i) {
        int c = i * NT + tid;
        int row = c >> 3, chs = (c & 7) ^ (row & 7);
        wsrc[i] = Wmk + (size_t)(s0 + row) * KP + chs * 8;
    }

    // fragment row bases
    int arow[4], brow[4];
    #pragma unroll
    for (int mi = 0; mi < 4; ++mi) arow[mi] = (wr * 64 + mi * 16 + lr) * 64;
    #pragma unroll
    for (int si = 0; si < 4; ++si) brow[si] = (wsx * 64 + si * 16 + lr) * 64;

    const f32x4 fz = {0.f, 0.f, 0.f, 0.f};
    f32x4 acc[4][4];
    #pragma unroll
    for (int a = 0; a < 4; ++a)
        #pragma unroll
        for (int b = 0; b < 4; ++b) acc[a][b] = fz;

    // stage round kt into LDS buffer b
    auto stage = [&](int kt, int b) {
        size_t koff;
        if (MODE == 1) {
            const int tap = (kt * 64) / CIN;
            const int kh = tap / 3, kw = tap - (tap / 3) * 3;
            const int icb0 = (kt * 64) % CIN;
            koff = ((size_t)kh * WP + kw) * CIN + icb0;
        } else {
            koff = (size_t)kt * 2 * WP * 4;
        }
        #pragma unroll
        for (int i = 0; i < SXC; ++i)
            gload16(xsrc[i] + koff, &XsB[b * BR * 64 + (i * NT + wid * 64) * 8]);
        #pragma unroll
        for (int i = 0; i < SWC; ++i)
            gload16(wsrc[i] + (size_t)kt * 64, &WsB[b * BS * 64 + (i * NT + wid * 64) * 8]);
    };
    // MFMA over buffer b
    auto compute = [&](int b) {
        #pragma unroll
        for (int hf = 0; hf < 2; ++hf) {
            const int cA = (((hf * 4 + lk) ^ (lr & 7)) * 8);
            u16x8 af[4], bfr[4];
            #pragma unroll
            for (int mi = 0; mi < 4; ++mi) af[mi] = *(const u16x8*)&XsB[b * BR * 64 + arow[mi] + cA];
            #pragma unroll
            for (int si = 0; si < 4; ++si) bfr[si] = *(const u16x8*)&WsB[b * BS * 64 + brow[si] + cA];
            #pragma unroll
            for (int mi = 0; mi < 4; ++mi)
                #pragma unroll
                for (int si = 0; si < 4; ++si)
                    acc[mi][si] = __builtin_amdgcn_mfma_f32_16x16x32_bf16(
                        __builtin_bit_cast(bf16x8_t, af[mi]),
                        __builtin_bit_cast(bf16x8_t, bfr[si]), acc[mi][si], 0, 0, 0);
        }
    };

    if (PIPE == 0) {
        #pragma unroll
        for (int kt = 0; kt < NKT; ++kt) {
            stage(kt, 0);
            __syncthreads();
            compute(0);
            __syncthreads();
        }
    } else {
        stage(0, 0);
        #pragma unroll
        for (int kt = 0; kt < NKT; ++kt) {
            const int cur = kt & 1;
            if (kt + 1 < NKT) {
                stage(kt + 1, cur ^ 1);
                s_waitcnt_vm<NLOAD>();   // prev round's loads landed; new ones in flight
            } else {
                s_waitcnt_vm<0>();
            }
            __builtin_amdgcn_sched_barrier(0);
            __builtin_amdgcn_s_barrier();
            __builtin_amdgcn_sched_barrier(0);
            compute(cur);
            __builtin_amdgcn_sched_barrier(0);
            __builtin_amdgcn_s_barrier();   // reads of buf[cur] done before restage
        }
    }

    // ---- epilogue ----
    if (OUT_NCHW) {
        // fconv3: scalar fp32 NCHW stores (tiny)
        #pragma unroll
        for (int si = 0; si < 4; ++si) {
            int col = s0 + wsx * 64 + si * 16 + lr;
            bool cok = col < Cout;
            float sc = cok ? scale[col] : 0.f;
            float sh = cok ? shift[col] : 0.f;
            #pragma unroll
            for (int mi = 0; mi < 4; ++mi) {
                int rbase = r0 + wr * 64 + mi * 16 + lk * 4;
                #pragma unroll
                for (int j = 0; j < 4; ++j) {
                    float v = acc[mi][si][j] * sc + sh;
                    if (RELU) v = fmaxf(v, 0.f);
                    if (cok) ((float*)Yv)[(size_t)z * yImgStride + col * 4096 + rbase + j] = v;
                }
            }
        }
    } else {
        // stage bf16 tile in LDS (stride BS+8, conflict-light), then coalesced stores
        __syncthreads();
        unsigned short* epi = lds;
        #pragma unroll
        for (int si = 0; si < 4; ++si) {
            int col = wsx * 64 + si * 16 + lr;
            float sc = scale[s0 + col];
            float sh = shift[s0 + col];
            #pragma unroll
            for (int mi = 0; mi < 4; ++mi) {
                int rowl = wr * 64 + mi * 16 + lk * 4;
                #pragma unroll
                for (int j = 0; j < 4; ++j) {
                    float v = acc[mi][si][j] * sc + sh;
                    if (RELU) v = fmaxf(v, 0.f);
                    epi[(rowl + j) * EPS_LDK + col] = f2bf(v);
                }
            }
        }
        __syncthreads();
        constexpr int NCH = BR * BS / 8 / NT;        // 8-col chunks per thread
        constexpr int CPR = BS / 8;                  // chunks per row
        #pragma unroll
        for (int i = 0; i < NCH; ++i) {
            int c = i * NT + tid;
            int row = c / CPR, colc = c - (c / CPR) * CPR;
            int r = r0 + row;
            int oh = r >> WOS, ow = r & (WOUT - 1);
            size_t off = ((size_t)(oh + OPAD) * WOP + ow + OPAD) * Cout + s0 + colc * 8;
            *(u16x8*)((unsigned short*)Yv + (size_t)z * yImgStride + off) =
                *(const u16x8*)&epi[row * EPS_LDK + colc * 8];
        }
    }
}

// ------- banded-MFMA 81-shift correlation -------
// cf, pf: NHWC bf16 [64][64][256]; out: padded [66][66][128] bf16 (ch>=81 stay 0).
__global__ __launch_bounds__(256)
void corr_mfma(const unsigned short* __restrict__ cf,
               const unsigned short* __restrict__ pf,
               unsigned short* __restrict__ out) {
    const int h = blockIdx.x;        // 0..63
    const int z = blockIdx.y;        // 0..7
    const int tid = threadIdx.x;
    const int lane = tid & 63, t = tid >> 6;
    const int lr = lane & 15, lk = lane >> 4;
    const unsigned short* cfi = cf + (size_t)z * 1048576;
    const unsigned short* pfi = pf + (size_t)z * 1048576;
    unsigned short* outp = out + (size_t)z * 557568;

    u16x8 a[8];
    {
        const unsigned short* ap = cfi + ((size_t)(h * 64 + t * 16 + lr)) * 256 + lk * 8;
        #pragma unroll
        for (int ks = 0; ks < 8; ++ks) a[ks] = *(const u16x8*)(ap + ks * 32);
    }

    const u16x8 zz = {0, 0, 0, 0, 0, 0, 0, 0};
    for (int di = -4; di <= 4; ++di) {
        const int h2 = h + di;
        const bool hok = (unsigned)h2 < 64u;
        #pragma unroll
        for (int ct = 0; ct < 2; ++ct) {
            const int wpg = t * 16 - 8 + ct * 16 + lr;
            u16x8 b[8];
            if (hok && (unsigned)wpg < 64u) {
                const unsigned short* bp = pfi + ((size_t)(h2 * 64 + wpg)) * 256 + lk * 8;
                #pragma unroll
                for (int ks = 0; ks < 8; ++ks) b[ks] = *(const u16x8*)(bp + ks * 32);
            } else {
                #pragma unroll
                for (int ks = 0; ks < 8; ++ks) b[ks] = zz;
            }
            f32x4 acc0 = {0.f, 0.f, 0.f, 0.f}, acc1 = {0.f, 0.f, 0.f, 0.f};
            #pragma unroll
            for (int ks = 0; ks < 8; ks += 2) {
                acc0 = __builtin_amdgcn_mfma_f32_16x16x32_bf16(
                    __builtin_bit_cast(bf16x8_t, a[ks]),
                    __builtin_bit_cast(bf16x8_t, b[ks]), acc0, 0, 0, 0);
                acc1 = __builtin_amdgcn_mfma_f32_16x16x32_bf16(
                    __builtin_bit_cast(bf16x8_t, a[ks + 1]),
                    __builtin_bit_cast(bf16x8_t, b[ks + 1]), acc1, 0, 0, 0);
            }
            const int wl = lk * 4;
            const int wpl = ct * 16 - 8 + lr;
            #pragma unroll
            for (int j = 0; j < 4; ++j) {
                int dj = wpl - (wl + j);
                if (dj >= -4 && dj <= 4) {
                    int s = (di + 4) * 9 + dj + 4;
                    int w = t * 16 + wl + j;
                    outp[((size_t)(h + 1) * 66 + w + 1) * 128 + s] =
                        f2bf(acc0[j] + acc1[j]);
                }
            }
        }
    }
}

// ---------------- launch ----------------
extern "C" void kernel_launch(void* const* d_in, const int* in_sizes, int n_in,
                              void* d_out, int out_size, void* d_ws, size_t ws_size,
                              hipStream_t stream) {
    const float* cloth  = (const float*)d_in[0];
    const float* person = (const float*)d_in[1];
    const float* w1 = (const float*)d_in[2];  const float* b1 = (const float*)d_in[3];
    const float* g1 = (const float*)d_in[4];  const float* be1 = (const float*)d_in[5];
    const float* m1 = (const float*)d_in[6];  const float* v1 = (const float*)d_in[7];
    const float* w2 = (const float*)d_in[8];  const float* b2 = (const float*)d_in[9];
    const float* g2 = (const float*)d_in[10]; const float* be2 = (const float*)d_in[11];
    const float* m2 = (const float*)d_in[12]; const float* v2 = (const float*)d_in[13];
    const float* w3 = (const float*)d_in[14]; const float* b3 = (const float*)d_in[15];
    const float* g3 = (const float*)d_in[16]; const float* be3 = (const float*)d_in[17];
    const float* m3 = (const float*)d_in[18]; const float* v3 = (const float*)d_in[19];
    const float* fw1 = (const float*)d_in[20]; const float* fb1 = (const float*)d_in[21];
    const float* fw2 = (const float*)d_in[22]; const float* fb2 = (const float*)d_in[23];
    const float* fw3 = (const float*)d_in[24]; const float* fb3 = (const float*)d_in[25];

    char* ws = (char*)d_ws;
    auto U = [&](size_t off) { return (unsigned short*)(ws + off); };
    // ---- layout (bytes), ws_size = 256 MiB = 268,435,456 ----
    unsigned short* nhwc = U(0);             // [518][518][4] x16 = 34,345,472
    unsigned short* t1   = U(34345472);      // [258][258][64] x16 = 136,323,072 -> ends 170,668,544
    unsigned short* cf   = U(34345472);      // alias t1 (dead after conv2): [64][64][256] x16
    unsigned short* t2   = U(170668544);     // [130][130][128] x16 = 69,222,400 -> ends 239,890,944
    unsigned short* w1mk  = U(239890944);    //  32,768 (64x256)
    unsigned short* w2mk  = U(239923712);    // 147,456 (128x576)
    unsigned short* w3mk  = U(240071168);    // 589,824 (256x1152)
    unsigned short* fw1mk = U(240660992);    // 294,912 (128x1152)
    unsigned short* fw2mk = U(240955904);    // 147,456 (64x1152)
    unsigned short* fw3mk = U(241103360);    //  73,728 (64x576) -> ends 241,177,088
    float* aff = (float*)(ws + 241177088);   // 8 KB
    // head buffers in DEDICATED tail region (never touched by nhwc/t1/t2 writes)
    unsigned short* corr = U(241185280);     // [66][66][128] x8 = 8,921,088 -> ends 250,106,368
    unsigned short* f1b  = U(250106368);     // [66][66][128] x8 = 8,921,088 -> ends 259,027,456
    unsigned short* f2b  = U(259027456);     // [66][66][64]  x8 = 4,460,544 -> ends 263,488,000
    float *s1 = aff,         *sh1 = aff + 64,   *s2 = aff + 128,  *sh2 = aff + 256;
    float *s3 = aff + 384,   *sh3 = aff + 640,  *sf1 = aff + 896, *shf1 = aff + 1024;
    float *sf2 = aff + 1152, *shf2 = aff + 1216, *sf3 = aff + 1280, *shf3 = aff + 1288;

    prep_affine_all<<<3, 256, 0, stream>>>(b1, g1, be1, m1, v1, b2, g2, be2, m2, v2,
                                           b3, g3, be3, m3, v3, fb1, fb2, fb3, aff);
    conv_weights_all<<<dim3(1152, 6), 256, 0, stream>>>(w1, w2, w3, fw1, fw2, fw3,
                                                        w1mk, w2mk, w3mk, fw1mk, fw2mk, fw3mk);

    // zero padded regions: nhwc 3-ring, head-buffer region, t1/t2 rings
    ring3_zero<<<dim3(25, 16), 256, 0, stream>>>(nhwc);
    hipMemsetAsync(ws + 241185280, 0, 22302720, stream);
    border_zero<<<514, 256, 0, stream>>>(t1, 258, 258, 8, 4260096, 16);
    border_zero<<<517, 256, 0, stream>>>(t2, 130, 130, 16, 2163200, 16);

    // input -> padded NHWC4 bf16, all 16 images
    to_nhwc4<<<dim3(1024, 1, 16), 256, 0, stream>>>(cloth, person, nhwc);

    // conv1: 7x7 s2 p3, nhwc[518,518,4] -> t1 pad[258,258,64]  (single-buf, 4 blk/CU)
    gemm_conv<4, 1, 2, true, false, 4, 4, 512, 8, 2, 1, 0><<<dim3(256, 1, 16), 256, 0, stream>>>(
        nhwc, w1mk, s1, sh1, t1, 64, 1073296, 4260096);
    // conv2: 3x3 s2 p1, t1 -> t2 pad[130,130,128]   (dbuf pipeline)
    gemm_conv<2, 2, 1, true, false, 64, 9, 256, 7, 2, 1, 1><<<dim3(128, 1, 16), 256, 0, stream>>>(
        t1, w2mk, s2, sh2, t2, 128, 4260096, 2163200);
    // conv3: 3x3 s2 p1, t2 -> cf/pf unpadded [64,64,256]   (dbuf pipeline)
    gemm_conv<2, 2, 1, true, false, 128, 18, 128, 6, 2, 0, 1><<<dim3(32, 2, 16), 256, 0, stream>>>(
        t2, w3mk, s3, sh3, cf, 256, 2163200, 1048576);

    // correlation (banded MFMA) -> corr pad[66,66,128]
    corr_mfma<<<dim3(64, 8), 256, 0, stream>>>(cf, cf + (size_t)8 * 1048576, corr);

    // fconv1: 3x3 p1, corr -> f1b pad[66,66,128]
    gemm_conv<2, 2, 1, true, false, 128, 18, 64, 6, 1, 1, 1><<<dim3(32, 1, 8), 256, 0, stream>>>(
        corr, fw1mk, sf1, shf1, f1b, 128, 557568, 557568);
    // fconv2: 3x3 p1, f1b -> f2b pad[66,66,64]
    gemm_conv<2, 1, 1, true, false, 128, 18, 64, 6, 1, 1, 1><<<dim3(32, 1, 8), 128, 0, stream>>>(
        f1b, fw2mk, sf2, shf2, f2b, 64, 557568, 278784);
    // fconv3: 3x3 p1, f2b -> d_out NCHW fp32 [8][2][64][64]
    gemm_conv<2, 1, 1, false, true, 64, 9, 64, 6, 1, 0, 1><<<dim3(32, 1, 8), 128, 0, stream>>>(
        f2b, fw3mk, sf3, shf3, (float*)d_out, 2, 278784, 8192);
}